// Round 3
// baseline (2160.989 us; speedup 1.0000x reference)
//
#include <hip/hip_runtime.h>
#include <hip/hip_bf16.h>
#include <cstdint>

#define NN 50000
#define EE 800000
#define RR 8
#define GG 128
#define D0 384
#define DL 256

typedef __attribute__((ext_vector_type(8))) short bf16x8;
typedef __attribute__((ext_vector_type(4))) float f32x4;

__device__ __forceinline__ float sigmoidf_(float x) { return 1.0f / (1.0f + expf(-x)); }

// fp32 -> bf16 (round to nearest even)
__device__ __forceinline__ ushort f2bf(float f) {
    uint u = __float_as_uint(f);
    u += 0x7fffu + ((u >> 16) & 1u);
    return (ushort)(u >> 16);
}
__device__ __forceinline__ uint pack2bf(float lo, float hi) {
    return (uint)f2bf(lo) | ((uint)f2bf(hi) << 16);
}
__device__ __forceinline__ float bf2f(ushort u) {
    return __uint_as_float((uint)u << 16);
}

// accumulate 8 bf16 (packed in uint4) into fp32 accumulators
__device__ __forceinline__ void acc8(float* s, uint4 a) {
    s[0] += __uint_as_float(a.x << 16);
    s[1] += __uint_as_float(a.x & 0xffff0000u);
    s[2] += __uint_as_float(a.y << 16);
    s[3] += __uint_as_float(a.y & 0xffff0000u);
    s[4] += __uint_as_float(a.z << 16);
    s[5] += __uint_as_float(a.z & 0xffff0000u);
    s[6] += __uint_as_float(a.w << 16);
    s[7] += __uint_as_float(a.w & 0xffff0000u);
}

// order-preserving float->uint encoding for atomicMax
__device__ __forceinline__ unsigned fenc(float x) {
    unsigned u = __float_as_uint(x);
    return (u & 0x80000000u) ? ~u : (u | 0x80000000u);
}
__device__ __forceinline__ float fdec(unsigned u) {
    unsigned b = (u & 0x80000000u) ? (u & 0x7fffffffu) : ~u;
    return __uint_as_float(b);
}

// ---------------- embedding concat: h0[n, 0:384] (bf16) ----------------
__global__ __launch_bounds__(256) void embed_kernel(
    const int* __restrict__ x,
    const float* __restrict__ e0, const float* __restrict__ e1,
    const float* __restrict__ e2, const float* __restrict__ e3,
    const float* __restrict__ e4, const float* __restrict__ e5,
    ushort* __restrict__ h0)
{
    int idx = blockIdx.x * 256 + threadIdx.x;   // over NN*48 8-elem chunks
    if (idx >= NN * 48) return;
    int n = idx / 48;
    int q = idx - n * 48;
    int d = q * 8;
    int tbl = d >> 6;
    int w = d & 63;
    int row = x[n * 6 + tbl];
    const float* src;
    switch (tbl) {
        case 0: src = e0; break; case 1: src = e1; break; case 2: src = e2; break;
        case 3: src = e3; break; case 4: src = e4; break; default: src = e5; break;
    }
    float4 f0 = *(const float4*)&src[row * 64 + w];
    float4 f1 = *(const float4*)&src[row * 64 + w + 4];
    uint4 pk;
    pk.x = pack2bf(f0.x, f0.y);
    pk.y = pack2bf(f0.z, f0.w);
    pk.z = pack2bf(f1.x, f1.y);
    pk.w = pack2bf(f1.z, f1.w);
    *(uint4*)&h0[(size_t)n * D0 + d] = pk;
}

// ---------------- weight convert + transpose: WbT[r][n][k] = bf16(W[r][k][n]) ----------------
__global__ __launch_bounds__(256) void cvtT_kernel(
    const float* __restrict__ W, const float* __restrict__ root,
    ushort* __restrict__ WbT, int nrel, int IN)
{
    int idx = blockIdx.x * 256 + threadIdx.x;
    int tot = (nrel + 1) * DL * IN;
    if (idx >= tot) return;
    int k = idx % IN;
    int rn = idx / IN;
    int n = rn % DL;
    int r = rn / DL;
    float v = (r < nrel) ? W[((size_t)r * IN + k) * DL + n] : root[(size_t)k * DL + n];
    WbT[idx] = f2bf(v);
}

// ---------------- CSR build ----------------
__global__ __launch_bounds__(256) void count_kernel(
    const int* __restrict__ dst, const int* __restrict__ et, int* __restrict__ counts)
{
    int i = blockIdx.x * 256 + threadIdx.x;
    if (i < EE) atomicAdd(&counts[dst[i] * RR + et[i]], 1);
}

#define SCAN_CHUNK 4096
__global__ __launch_bounds__(256) void scanA_kernel(const int* __restrict__ cnt, int M, int* __restrict__ blkSums)
{
    __shared__ int s[256];
    int b = blockIdx.x, t = threadIdx.x;
    int base = b * SCAN_CHUNK + t * 16;
    int tot = 0;
    #pragma unroll
    for (int i = 0; i < 16; i++) { int idx = base + i; if (idx < M) tot += cnt[idx]; }
    s[t] = tot; __syncthreads();
    for (int off = 128; off > 0; off >>= 1) {
        if (t < off) s[t] += s[t + off];
        __syncthreads();
    }
    if (t == 0) blkSums[b] = s[0];
}

__global__ void scanB_kernel(const int* __restrict__ blkSums, int NB, int* __restrict__ blkOff)
{
    if (threadIdx.x == 0) {
        int run = 0;
        for (int i = 0; i < NB; i++) { blkOff[i] = run; run += blkSums[i]; }
    }
}

__global__ __launch_bounds__(256) void scanC_kernel(
    const int* __restrict__ cnt, int M, const int* __restrict__ blkOff,
    int* __restrict__ offs, int* __restrict__ curs)
{
    __shared__ int s[256];
    int b = blockIdx.x, t = threadIdx.x;
    int base = b * SCAN_CHUNK + t * 16;
    int loc[16];
    int tot = 0;
    #pragma unroll
    for (int i = 0; i < 16; i++) {
        int idx = base + i;
        int v = (idx < M) ? cnt[idx] : 0;
        loc[i] = tot; tot += v;
    }
    s[t] = tot; __syncthreads();
    for (int off = 1; off < 256; off <<= 1) {
        int v = (t >= off) ? s[t - off] : 0;
        __syncthreads();
        s[t] += v;
        __syncthreads();
    }
    int texc = s[t] - tot;           // exclusive prefix of this thread
    int bb = blkOff[b];
    #pragma unroll
    for (int i = 0; i < 16; i++) {
        int idx = base + i;
        if (idx < M) { int o = bb + texc + loc[i]; offs[idx] = o; curs[idx] = o; }
    }
}

__global__ __launch_bounds__(256) void scatter_kernel(
    const int* __restrict__ src, const int* __restrict__ dst, const int* __restrict__ et,
    int* __restrict__ cursors, int* __restrict__ esrc)
{
    int i = blockIdx.x * 256 + threadIdx.x;
    if (i < EE) {
        int pos = atomicAdd(&cursors[dst[i] * RR + et[i]], 1);
        esrc[pos] = src[i];
    }
}

// ---------------- fused aggregate + bf16-MFMA GEMM layer ----------------
// block = 256 threads (4 waves), 32-node tile, 256 output cols.
// Per relation: register-aggregate (fp32) bucket means from bf16 h rows,
// pack to bf16 LDS A[32][IN]; each wave computes a 32x64 output slice via
// v_mfma_f32_16x16x32_bf16. h stored bf16 throughout (halves gather bytes).
template<int IN, int ACT>
__global__ __launch_bounds__(256) void layer_mfma(
    const ushort* __restrict__ hin,
    const int* __restrict__ esrc,
    const int* __restrict__ offs,
    const int* __restrict__ cnts,
    const ushort* __restrict__ WbT,   // [(nrel+1)][DL][IN] bf16, n-major
    const float* __restrict__ bias,   // [DL]
    ushort* __restrict__ hout,        // [N, DL] bf16
    int nrel)
{
    constexpr int NC = IN / 32;       // MFMA K-steps
    constexpr int NU = IN / 64;       // uint4 (8 bf16) chunks per agg thread
    constexpr int LDA_ = IN + 8;      // keep rows 16B-aligned
    __shared__ ushort Ab[32][LDA_];

    const int t    = threadIdx.x;
    const int an   = t >> 3;          // agg node 0..31
    const int ac   = t & 7;           // agg chunk 0..7
    const int base = blockIdx.x * 32;
    const int node = base + an;
    const int lane = t & 63;
    const int wv   = t >> 6;          // wave 0..3
    const int l15  = lane & 15;
    const int kg   = lane >> 4;       // k-group 0..3
    const int wcol = wv * 64;

    f32x4 acc[2][4];
    #pragma unroll
    for (int mt = 0; mt < 2; mt++)
        #pragma unroll
        for (int nt = 0; nt < 4; nt++) acc[mt][nt] = (f32x4){0.f, 0.f, 0.f, 0.f};

    // B fragment base pointers (per n-tile), relation offset added in loop
    const ushort* bp[4];
    #pragma unroll
    for (int nt = 0; nt < 4; nt++)
        bp[nt] = WbT + (size_t)(wcol + nt * 16 + l15) * IN + kg * 4;

    union FR { bf16x8 v; uint u[4]; };

    for (int r = 0; r <= nrel; r++) {
        // ---- aggregation into fp32 registers ----
        float s[NU][8];
        #pragma unroll
        for (int j = 0; j < NU; j++)
            #pragma unroll
            for (int q = 0; q < 8; q++) s[j][q] = 0.f;
        if (node < NN) {
            if (r == nrel) {               // root: node's own features
                const ushort* hp = hin + (size_t)node * IN;
                #pragma unroll
                for (int j = 0; j < NU; j++)
                    acc8(s[j], *(const uint4*)(hp + j * 64 + ac * 8));
            } else {
                int bidx = node * RR + r;
                int st = offs[bidx], cn = cnts[bidx];
                int e = 0;
                for (; e + 1 < cn; e += 2) {   // pairwise: 2 latency chains in flight
                    const ushort* p0 = hin + (size_t)esrc[st + e] * IN;
                    const ushort* p1 = hin + (size_t)esrc[st + e + 1] * IN;
                    #pragma unroll
                    for (int j = 0; j < NU; j++) {
                        uint4 a = *(const uint4*)(p0 + j * 64 + ac * 8);
                        uint4 b = *(const uint4*)(p1 + j * 64 + ac * 8);
                        acc8(s[j], a);
                        acc8(s[j], b);
                    }
                }
                if (e < cn) {
                    const ushort* p0 = hin + (size_t)esrc[st + e] * IN;
                    #pragma unroll
                    for (int j = 0; j < NU; j++)
                        acc8(s[j], *(const uint4*)(p0 + j * 64 + ac * 8));
                }
                if (cn > 1) {
                    float nrm = 1.0f / (float)cn;   // mean aggregation
                    #pragma unroll
                    for (int j = 0; j < NU; j++)
                        #pragma unroll
                        for (int q = 0; q < 8; q++) s[j][q] *= nrm;
                }
            }
        }
        #pragma unroll
        for (int j = 0; j < NU; j++) {
            uint4 pk;
            pk.x = pack2bf(s[j][0], s[j][1]);
            pk.y = pack2bf(s[j][2], s[j][3]);
            pk.z = pack2bf(s[j][4], s[j][5]);
            pk.w = pack2bf(s[j][6], s[j][7]);
            *(uint4*)&Ab[an][j * 64 + ac * 8] = pk;
        }
        __syncthreads();

        // ---- MFMA over K = IN ----
        const size_t roff = (size_t)r * DL * IN;
        for (int ks = 0; ks < NC; ks++) {
            FR a0, a1, bb[4];
            const ushort* ap0 = &Ab[l15][ks * 32 + kg * 4];
            const ushort* ap1 = &Ab[16 + l15][ks * 32 + kg * 4];
            uint2 x0 = *(const uint2*)ap0;
            uint2 x1 = *(const uint2*)(ap0 + 16);
            a0.u[0] = x0.x; a0.u[1] = x0.y; a0.u[2] = x1.x; a0.u[3] = x1.y;
            uint2 y0 = *(const uint2*)ap1;
            uint2 y1 = *(const uint2*)(ap1 + 16);
            a1.u[0] = y0.x; a1.u[1] = y0.y; a1.u[2] = y1.x; a1.u[3] = y1.y;
            #pragma unroll
            for (int nt = 0; nt < 4; nt++) {
                const ushort* p = bp[nt] + roff + ks * 32;
                uint2 lo = *(const uint2*)p;
                uint2 hi = *(const uint2*)(p + 16);
                bb[nt].u[0] = lo.x; bb[nt].u[1] = lo.y; bb[nt].u[2] = hi.x; bb[nt].u[3] = hi.y;
            }
            #pragma unroll
            for (int nt = 0; nt < 4; nt++) {
                acc[0][nt] = __builtin_amdgcn_mfma_f32_16x16x32_bf16(a0.v, bb[nt].v, acc[0][nt], 0, 0, 0);
                acc[1][nt] = __builtin_amdgcn_mfma_f32_16x16x32_bf16(a1.v, bb[nt].v, acc[1][nt], 0, 0, 0);
            }
        }
        __syncthreads();
    }

    // ---- epilogue: bias + activation, C/D layout col=lane&15, row=(lane>>4)*4+i ----
    #pragma unroll
    for (int nt = 0; nt < 4; nt++) {
        int col = wcol + nt * 16 + l15;
        float bv = bias[col];
        #pragma unroll
        for (int mt = 0; mt < 2; mt++) {
            #pragma unroll
            for (int i = 0; i < 4; i++) {
                int n = base + mt * 16 + kg * 4 + i;
                if (n < NN) {
                    float v = acc[mt][nt][i] + bv;
                    hout[(size_t)n * DL + col] = f2bf(ACT ? sigmoidf_(v) : v);
                }
            }
        }
    }
}

// ---------------- BatchNorm stats over hg1 columns ----------------
__global__ __launch_bounds__(256) void bnstats_kernel(
    const ushort* __restrict__ hg1, float* __restrict__ colsum, float* __restrict__ colsum2)
{
    int col = threadIdx.x;            // 256 columns
    int row0 = blockIdx.x * 128;
    int rend = min(row0 + 128, NN);
    float s = 0.f, s2 = 0.f;
    for (int r = row0; r < rend; r++) {
        float v = bf2f(hg1[(size_t)r * DL + col]);
        s += v; s2 += v * v;
    }
    atomicAdd(&colsum[col], s);
    atomicAdd(&colsum2[col], s2);
}

__global__ void bnfinal_kernel(
    const float* __restrict__ colsum, const float* __restrict__ colsum2,
    const float* __restrict__ gamma, float* __restrict__ mu, float* __restrict__ aa)
{
    int c = threadIdx.x;
    if (c < DL) {
        float m = colsum[c] / (float)NN;
        float var = colsum2[c] / (float)NN - m * m;
        mu[c] = m;
        aa[c] = rsqrtf(var + 1e-5f) * gamma[c];
    }
}

// ---------------- gate = relu(BN(hg1)) @ Wg2 + bg2 ; segment max ----------------
__global__ __launch_bounds__(256) void gate_kernel(
    const ushort* __restrict__ hg1, const float* __restrict__ mu,
    const float* __restrict__ aa, const float* __restrict__ beta,
    const float* __restrict__ Wg2, const float* __restrict__ bg2,
    const int* __restrict__ batch,
    float* __restrict__ gate, unsigned* __restrict__ gmaxu)
{
    int lane = threadIdx.x & 63;
    int wid = (blockIdx.x * blockDim.x + threadIdx.x) >> 6;
    int nw = (gridDim.x * blockDim.x) >> 6;
    for (int n = wid; n < NN; n += nw) {
        float s = 0.f;
        #pragma unroll
        for (int c = 0; c < 4; c++) {
            int d = c * 64 + lane;
            float v = bf2f(hg1[(size_t)n * DL + d]);
            float xn = (v - mu[d]) * aa[d] + beta[d];
            xn = fmaxf(xn, 0.f);
            s += xn * Wg2[d];
        }
        #pragma unroll
        for (int o = 32; o > 0; o >>= 1) s += __shfl_down(s, o, 64);
        if (lane == 0) {
            float g = s + bg2[0];
            gate[n] = g;
            atomicMax(&gmaxu[batch[n]], fenc(g));
        }
    }
}

__global__ __launch_bounds__(256) void expdenom_kernel(
    const float* __restrict__ gate, const int* __restrict__ batch,
    const unsigned* __restrict__ gmaxu, float* __restrict__ ealpha, float* __restrict__ denom)
{
    int i = blockIdx.x * 256 + threadIdx.x;
    if (i < NN) {
        int b = batch[i];
        float ex = expf(gate[i] - fdec(gmaxu[b]));
        ealpha[i] = ex;
        atomicAdd(&denom[b], ex);
    }
}

// ---------------- pooled[g] = sum (e/denom) * h2[n] (batch sorted) ----------------
__global__ __launch_bounds__(256) void pool_kernel(
    const ushort* __restrict__ h2, const float* __restrict__ ealpha,
    const float* __restrict__ denom, const int* __restrict__ batch,
    float* __restrict__ pooled)
{
    int col = threadIdx.x;            // 256
    int row0 = blockIdx.x * 128;
    if (row0 >= NN) return;
    int rend = min(row0 + 128, NN);
    float accv = 0.f;
    int curg = batch[row0];
    for (int r = row0; r < rend; r++) {
        int g = batch[r];
        if (g != curg) {
            atomicAdd(&pooled[curg * DL + col], accv / denom[curg]);
            accv = 0.f; curg = g;
        }
        accv += ealpha[r] * bf2f(h2[(size_t)r * DL + col]);
    }
    atomicAdd(&pooled[curg * DL + col], accv / denom[curg]);
}

__global__ void head_kernel(
    const float* __restrict__ pooled, const float* __restrict__ Wgl,
    const float* __restrict__ bgl, float* __restrict__ out)
{
    int g = blockIdx.x;
    int lane = threadIdx.x;           // 64
    float s = 0.f;
    #pragma unroll
    for (int c = 0; c < 4; c++) {
        int d = c * 64 + lane;
        s += pooled[g * DL + d] * Wgl[d];
    }
    #pragma unroll
    for (int o = 32; o > 0; o >>= 1) s += __shfl_down(s, o, 64);
    if (lane == 0) out[g] = sigmoidf_(s + bgl[0]);
}

extern "C" void kernel_launch(void* const* d_in, const int* in_sizes, int n_in,
                              void* d_out, int out_size, void* d_ws, size_t ws_size,
                              hipStream_t stream)
{
    const int* x      = (const int*)d_in[0];
    const int* ei     = (const int*)d_in[1];
    const int* etype  = (const int*)d_in[2];
    const int* batch  = (const int*)d_in[3];
    const float* e0   = (const float*)d_in[4];
    const float* e1   = (const float*)d_in[5];
    const float* e2   = (const float*)d_in[6];
    const float* e3   = (const float*)d_in[7];
    const float* e4   = (const float*)d_in[8];
    const float* e5   = (const float*)d_in[9];
    const float* W1   = (const float*)d_in[10];
    const float* root1= (const float*)d_in[11];
    const float* b1   = (const float*)d_in[12];
    const float* W2   = (const float*)d_in[13];
    const float* root2= (const float*)d_in[14];
    const float* b2   = (const float*)d_in[15];
    const float* Wg1  = (const float*)d_in[16];
    const float* bg1  = (const float*)d_in[17];
    const float* gamma= (const float*)d_in[18];
    const float* beta = (const float*)d_in[19];
    const float* Wg2  = (const float*)d_in[20];
    const float* bg2  = (const float*)d_in[21];
    const float* Wgl  = (const float*)d_in[22];
    const float* bgl  = (const float*)d_in[23];
    float* out = (float*)d_out;

    const int* esrc_in = ei;          // edge_index[0]
    const int* edst_in = ei + EE;     // edge_index[1]

    char* ws = (char*)d_ws;
    size_t off = 0;
    auto alloc = [&](size_t b) -> char* {
        char* p = ws + off;
        off += (b + 255) & ~(size_t)255;
        return p;
    };
    ushort* h0     = (ushort*)alloc((size_t)NN * D0 * 2);  // 38.4 MB bf16 (reused as hg1)
    ushort* h1     = (ushort*)alloc((size_t)NN * DL * 2);  // 25.6 MB bf16
    ushort* h2     = (ushort*)alloc((size_t)NN * DL * 2);  // 25.6 MB bf16
    size_t zstart = off;                                   // ---- zeroed region ----
    int*      counts  = (int*)alloc((size_t)NN * RR * 4);
    float*    colsum  = (float*)alloc(DL * 4);
    float*    colsum2 = (float*)alloc(DL * 4);
    unsigned* gmaxu   = (unsigned*)alloc(GG * 4);
    float*    denom   = (float*)alloc(GG * 4);
    float*    pooled  = (float*)alloc((size_t)GG * DL * 4);
    size_t zbytes = off - zstart;                          // ---- end zeroed ----
    int*   offs    = (int*)alloc((size_t)NN * RR * 4);
    int*   cursors = (int*)alloc((size_t)NN * RR * 4);
    int*   esrc    = (int*)alloc((size_t)EE * 4);
    int*   blkSums = (int*)alloc(512);
    int*   blkOff  = (int*)alloc(512);
    float* mu      = (float*)alloc(DL * 4);
    float* aa      = (float*)alloc(DL * 4);
    float* gate    = (float*)alloc((size_t)NN * 4);
    float* ealpha  = (float*)alloc((size_t)NN * 4);
    ushort* WbT1   = (ushort*)alloc((size_t)9 * DL * D0 * 2);  // 1.77 MB
    ushort* WbT2   = (ushort*)alloc((size_t)9 * DL * DL * 2);  // 1.18 MB
    ushort* WbTg   = (ushort*)alloc((size_t)1 * DL * DL * 2);  // 131 KB
    ushort* hg1 = h0;   // reuse: h0 dead after layer1

    if (ws_size < off) return;   // fail loudly (wrong output) rather than corrupt

    hipMemsetAsync(ws + zstart, 0, zbytes, stream);

    embed_kernel<<<(NN * 48 + 255) / 256, 256, 0, stream>>>(x, e0, e1, e2, e3, e4, e5, h0);
    count_kernel<<<(EE + 255) / 256, 256, 0, stream>>>(edst_in, etype, counts);

    // weight bf16 transposes
    {
        int tot1 = 9 * DL * D0;
        cvtT_kernel<<<(tot1 + 255) / 256, 256, 0, stream>>>(W1, root1, WbT1, RR, D0);
        int tot2 = 9 * DL * DL;
        cvtT_kernel<<<(tot2 + 255) / 256, 256, 0, stream>>>(W2, root2, WbT2, RR, DL);
        int totg = 1 * DL * DL;
        cvtT_kernel<<<(totg + 255) / 256, 256, 0, stream>>>(nullptr, Wg1, WbTg, 0, DL);
    }

    const int M = NN * RR;
    const int NB = (M + SCAN_CHUNK - 1) / SCAN_CHUNK;   // 98
    scanA_kernel<<<NB, 256, 0, stream>>>(counts, M, blkSums);
    scanB_kernel<<<1, 64, 0, stream>>>(blkSums, NB, blkOff);
    scanC_kernel<<<NB, 256, 0, stream>>>(counts, M, blkOff, offs, cursors);
    scatter_kernel<<<(EE + 255) / 256, 256, 0, stream>>>(esrc_in, edst_in, etype, cursors, esrc);

    const int NBLK = (NN + 31) / 32;
    layer_mfma<D0, 1><<<NBLK, 256, 0, stream>>>(h0, esrc, offs, counts, WbT1, b1, h1, RR);
    layer_mfma<DL, 1><<<NBLK, 256, 0, stream>>>(h1, esrc, offs, counts, WbT2, b2, h2, RR);
    layer_mfma<DL, 0><<<NBLK, 256, 0, stream>>>(h2, esrc, offs, counts, WbTg, bg1, hg1, 0);

    bnstats_kernel<<<(NN + 127) / 128, 256, 0, stream>>>(hg1, colsum, colsum2);
    bnfinal_kernel<<<1, 256, 0, stream>>>(colsum, colsum2, gamma, mu, aa);
    gate_kernel<<<512, 256, 0, stream>>>(hg1, mu, aa, beta, Wg2, bg2, batch, gate, gmaxu);
    expdenom_kernel<<<(NN + 255) / 256, 256, 0, stream>>>(gate, batch, gmaxu, ealpha, denom);
    pool_kernel<<<(NN + 127) / 128, 256, 0, stream>>>(h2, ealpha, denom, batch, pooled);
    head_kernel<<<GG, 64, 0, stream>>>(pooled, Wgl, bgl, out);
}

// Round 5
// 1888.968 us; speedup vs baseline: 1.1440x; 1.1440x over previous
//
#include <hip/hip_runtime.h>
#include <hip/hip_bf16.h>
#include <cstdint>

#define NN 50000
#define EE 800000
#define RR 8
#define GG 128
#define D0 384
#define DL 256
#define CHC 512      // hrc columns: 2 relations * 256

typedef __attribute__((ext_vector_type(8))) short bf16x8;
typedef __attribute__((ext_vector_type(4))) float f32x4;

__device__ __forceinline__ float sigmoidf_(float x) { return 1.0f / (1.0f + expf(-x)); }

__device__ __forceinline__ ushort f2bf(float f) {
    uint u = __float_as_uint(f);
    u += 0x7fffu + ((u >> 16) & 1u);
    return (ushort)(u >> 16);
}
__device__ __forceinline__ uint pack2bf(float lo, float hi) {
    return (uint)f2bf(lo) | ((uint)f2bf(hi) << 16);
}
__device__ __forceinline__ float bf2f(ushort u) {
    return __uint_as_float((uint)u << 16);
}

// acc[0..7] += w * bf16x8(v)
__device__ __forceinline__ void accw8(float* s, uint4 a, float w) {
    s[0] += w * __uint_as_float(a.x << 16);
    s[1] += w * __uint_as_float(a.x & 0xffff0000u);
    s[2] += w * __uint_as_float(a.y << 16);
    s[3] += w * __uint_as_float(a.y & 0xffff0000u);
    s[4] += w * __uint_as_float(a.z << 16);
    s[5] += w * __uint_as_float(a.z & 0xffff0000u);
    s[6] += w * __uint_as_float(a.w << 16);
    s[7] += w * __uint_as_float(a.w & 0xffff0000u);
}

// order-preserving float->uint encoding for atomicMax
__device__ __forceinline__ unsigned fenc(float x) {
    unsigned u = __float_as_uint(x);
    return (u & 0x80000000u) ? ~u : (u | 0x80000000u);
}
__device__ __forceinline__ float fdec(unsigned u) {
    unsigned b = (u & 0x80000000u) ? (u & 0x7fffffffu) : ~u;
    return __uint_as_float(b);
}

// ---------------- embedding concat: h0[n, 0:384] (bf16) ----------------
__global__ __launch_bounds__(256) void embed_kernel(
    const int* __restrict__ x,
    const float* __restrict__ e0, const float* __restrict__ e1,
    const float* __restrict__ e2, const float* __restrict__ e3,
    const float* __restrict__ e4, const float* __restrict__ e5,
    ushort* __restrict__ h0)
{
    int idx = blockIdx.x * 256 + threadIdx.x;   // over NN*48 8-elem chunks
    if (idx >= NN * 48) return;
    int n = idx / 48;
    int q = idx - n * 48;
    int d = q * 8;
    int tbl = d >> 6;
    int w = d & 63;
    int row = x[n * 6 + tbl];
    const float* src;
    switch (tbl) {
        case 0: src = e0; break; case 1: src = e1; break; case 2: src = e2; break;
        case 3: src = e3; break; case 4: src = e4; break; default: src = e5; break;
    }
    float4 f0 = *(const float4*)&src[row * 64 + w];
    float4 f1 = *(const float4*)&src[row * 64 + w + 4];
    uint4 pk;
    pk.x = pack2bf(f0.x, f0.y);
    pk.y = pack2bf(f0.z, f0.w);
    pk.z = pack2bf(f1.x, f1.y);
    pk.w = pack2bf(f1.z, f1.w);
    *(uint4*)&h0[(size_t)n * D0 + d] = pk;
}

// ---------------- weight convert + transpose: WbT[r*256+n][k] = bf16(W[r][k][n]) ----------------
__global__ __launch_bounds__(256) void cvtT_kernel(
    const float* __restrict__ W, const float* __restrict__ root,
    ushort* __restrict__ WbT, int nrel, int IN)
{
    int idx = blockIdx.x * 256 + threadIdx.x;
    int tot = (nrel + 1) * DL * IN;
    if (idx >= tot) return;
    int k = idx % IN;
    int rn = idx / IN;
    int n = rn % DL;
    int r = rn / DL;
    float v = (r < nrel) ? W[((size_t)r * IN + k) * DL + n] : root[(size_t)k * DL + n];
    WbT[idx] = f2bf(v);
}

// ---------------- CSR build ----------------
__global__ __launch_bounds__(256) void count_kernel(
    const int* __restrict__ dst, const int* __restrict__ et, int* __restrict__ counts)
{
    int i = blockIdx.x * 256 + threadIdx.x;
    if (i < EE) atomicAdd(&counts[dst[i] * RR + et[i]], 1);
}

#define SCAN_CHUNK 4096
__global__ __launch_bounds__(256) void scanA_kernel(const int* __restrict__ cnt, int M, int* __restrict__ blkSums)
{
    __shared__ int s[256];
    int b = blockIdx.x, t = threadIdx.x;
    int base = b * SCAN_CHUNK + t * 16;
    int tot = 0;
    #pragma unroll
    for (int i = 0; i < 16; i++) { int idx = base + i; if (idx < M) tot += cnt[idx]; }
    s[t] = tot; __syncthreads();
    for (int off = 128; off > 0; off >>= 1) {
        if (t < off) s[t] += s[t + off];
        __syncthreads();
    }
    if (t == 0) blkSums[b] = s[0];
}

__global__ void scanB_kernel(const int* __restrict__ blkSums, int NB, int* __restrict__ blkOff)
{
    if (threadIdx.x == 0) {
        int run = 0;
        for (int i = 0; i < NB; i++) { blkOff[i] = run; run += blkSums[i]; }
    }
}

__global__ __launch_bounds__(256) void scanC_kernel(
    const int* __restrict__ cnt, int M, const int* __restrict__ blkOff,
    int* __restrict__ offs, int* __restrict__ curs)
{
    __shared__ int s[256];
    int b = blockIdx.x, t = threadIdx.x;
    int base = b * SCAN_CHUNK + t * 16;
    int loc[16];
    int tot = 0;
    #pragma unroll
    for (int i = 0; i < 16; i++) {
        int idx = base + i;
        int v = (idx < M) ? cnt[idx] : 0;
        loc[i] = tot; tot += v;
    }
    s[t] = tot; __syncthreads();
    for (int off = 1; off < 256; off <<= 1) {
        int v = (t >= off) ? s[t - off] : 0;
        __syncthreads();
        s[t] += v;
        __syncthreads();
    }
    int texc = s[t] - tot;           // exclusive prefix of this thread
    int bb = blkOff[b];
    #pragma unroll
    for (int i = 0; i < 16; i++) {
        int idx = base + i;
        if (idx < M) { int o = bb + texc + loc[i]; offs[idx] = o; curs[idx] = o; }
    }
}

// scatter: per-edge gather index into the 2-relation chunk (src*512 + (r&1)*256)
// and weight 1/cnt. CSR order is by (dst, rel) bucket.
__global__ __launch_bounds__(256) void scatter_kernel(
    const int* __restrict__ src, const int* __restrict__ dst, const int* __restrict__ et,
    const int* __restrict__ cnts, int* __restrict__ cursors,
    int* __restrict__ eidx, float* __restrict__ ew)
{
    int i = blockIdx.x * 256 + threadIdx.x;
    if (i < EE) {
        int r = et[i];
        int b = dst[i] * RR + r;
        int pos = atomicAdd(&cursors[b], 1);
        eidx[pos] = src[i] * CHC + (r & 1) * DL;
        ew[pos] = 1.0f / (float)cnts[b];
    }
}

// ---------------- dense bf16 MFMA GEMM: C[M][NCB*256] = A[M][K] @ Bt^T ----------------
// Bt rows are output columns: Bt[j][k], j = cb*256 + c. BM=64, 4 waves.
// MODE 0: write bf16. MODE 1: +bias, write bf16 (gate). MODE 2: +hacc+bias,
// sigmoid, write bf16 (fused root+aggregate finalize).
template<int K, int NCB, int MODE>
__global__ __launch_bounds__(256) void dense_gemm(
    const ushort* __restrict__ A,    // [M][K] bf16
    const ushort* __restrict__ Bt,   // [NCB*256][K] bf16
    const float* __restrict__ bias,  // [256] (MODE>=1)
    const float* __restrict__ hacc,  // [M][256] fp32 (MODE==2)
    ushort* __restrict__ C,          // [M][NCB*256] bf16
    int M)
{
    constexpr int NC = K / 32;
    constexpr int LDA_ = K + 8;      // +16B pad -> <=2-way LDS banks
    constexpr int NCOL = NCB * 256;
    __shared__ ushort Ab[64][LDA_];

    const int t    = threadIdx.x;
    const int base = blockIdx.x * 64;
    const int lane = t & 63;
    const int wv   = t >> 6;
    const int l15  = lane & 15;
    const int kg   = lane >> 4;
    const int wcol = wv * 64;

    // ---- stage A tile ----
    constexpr int CW = K / 8;        // uint4 chunks per row
    constexpr int NL = 64 * CW / 256;
    #pragma unroll
    for (int i = 0; i < NL; i++) {
        int idx = t + i * 256;
        int row = idx / CW, col = idx - row * CW;
        int gr = base + row; if (gr >= M) gr = M - 1;
        *(uint4*)&Ab[row][col * 8] = *(const uint4*)&A[(size_t)gr * K + col * 8];
    }
    __syncthreads();

    union FR { bf16x8 v; uint u[4]; };

    for (int cb = 0; cb < NCB; cb++) {
        f32x4 acc[4][4];
        #pragma unroll
        for (int mt = 0; mt < 4; mt++)
            #pragma unroll
            for (int nt = 0; nt < 4; nt++) acc[mt][nt] = (f32x4){0.f, 0.f, 0.f, 0.f};

        const ushort* bpb = Bt + (size_t)(cb * 256 + wcol + l15) * K + kg * 4;

        for (int ks = 0; ks < NC; ks++) {
            FR a[4], b[4];
            #pragma unroll
            for (int mt = 0; mt < 4; mt++) {
                const ushort* ap = &Ab[mt * 16 + l15][ks * 32 + kg * 4];
                uint2 x0 = *(const uint2*)ap;
                uint2 x1 = *(const uint2*)(ap + 16);
                a[mt].u[0] = x0.x; a[mt].u[1] = x0.y; a[mt].u[2] = x1.x; a[mt].u[3] = x1.y;
            }
            #pragma unroll
            for (int nt = 0; nt < 4; nt++) {
                const ushort* p = bpb + (size_t)nt * 16 * K + ks * 32;
                uint2 lo = *(const uint2*)p;
                uint2 hi = *(const uint2*)(p + 16);
                b[nt].u[0] = lo.x; b[nt].u[1] = lo.y; b[nt].u[2] = hi.x; b[nt].u[3] = hi.y;
            }
            #pragma unroll
            for (int nt = 0; nt < 4; nt++)
                #pragma unroll
                for (int mt = 0; mt < 4; mt++)
                    acc[mt][nt] = __builtin_amdgcn_mfma_f32_16x16x32_bf16(a[mt].v, b[nt].v, acc[mt][nt], 0, 0, 0);
        }

        // epilogue: C/D layout col=lane&15, row=(lane>>4)*4+i
        #pragma unroll
        for (int nt = 0; nt < 4; nt++) {
            int ccol = wcol + nt * 16 + l15;
            float bv = (MODE >= 1) ? bias[ccol] : 0.f;
            #pragma unroll
            for (int mt = 0; mt < 4; mt++) {
                #pragma unroll
                for (int i = 0; i < 4; i++) {
                    int row = base + mt * 16 + kg * 4 + i;
                    if (row < M) {
                        float v = acc[mt][nt][i] + bv;
                        if (MODE == 2) {
                            v += hacc[(size_t)row * DL + ccol];
                            v = sigmoidf_(v);
                        }
                        C[(size_t)row * NCOL + cb * 256 + ccol] = f2bf(v);
                    }
                }
            }
        }
    }
}

// ---------------- chunked flat CSR gather-accumulate ----------------
// Pass P covers relations {2P, 2P+1}: CSR buckets (n,2P),(n,2P+1) are
// contiguous. half-wave per node, 8 cols (16B) per lane, 4-deep unroll.
// P==0 initializes hacc, else accumulates.
template<int P>
__global__ __launch_bounds__(256) void gather_acc(
    const ushort* __restrict__ hrc,  // [N][512] bf16
    const int* __restrict__ eidx,
    const float* __restrict__ ew,
    const int* __restrict__ offs,    // [N*8]
    float* __restrict__ hacc)        // [N][256] fp32
{
    int t = threadIdx.x;
    int slot = t >> 5;               // 0..7
    int l = t & 31;
    int n = blockIdx.x * 8 + slot;
    if (n >= NN) return;
    int e    = offs[n * 8 + 2 * P];
    int endE = (P == 3) ? ((n == NN - 1) ? EE : offs[n * 8 + 8])
                        : offs[n * 8 + 2 * P + 2];
    int c = l * 8;

    float acc[8];
    if (P == 0) {
        #pragma unroll
        for (int q = 0; q < 8; q++) acc[q] = 0.f;
    } else {
        float4 a0 = *(const float4*)&hacc[(size_t)n * DL + c];
        float4 a1 = *(const float4*)&hacc[(size_t)n * DL + c + 4];
        acc[0] = a0.x; acc[1] = a0.y; acc[2] = a0.z; acc[3] = a0.w;
        acc[4] = a1.x; acc[5] = a1.y; acc[6] = a1.z; acc[7] = a1.w;
    }

    for (; e + 4 <= endE; e += 4) {
        int i0 = eidx[e], i1 = eidx[e + 1], i2 = eidx[e + 2], i3 = eidx[e + 3];
        float w0 = ew[e], w1 = ew[e + 1], w2 = ew[e + 2], w3 = ew[e + 3];
        uint4 v0 = *(const uint4*)&hrc[(size_t)i0 + c];
        uint4 v1 = *(const uint4*)&hrc[(size_t)i1 + c];
        uint4 v2 = *(const uint4*)&hrc[(size_t)i2 + c];
        uint4 v3 = *(const uint4*)&hrc[(size_t)i3 + c];
        accw8(acc, v0, w0); accw8(acc, v1, w1);
        accw8(acc, v2, w2); accw8(acc, v3, w3);
    }
    for (; e < endE; e++) {
        uint4 v = *(const uint4*)&hrc[(size_t)eidx[e] + c];
        accw8(acc, v, ew[e]);
    }

    *(float4*)&hacc[(size_t)n * DL + c]     = make_float4(acc[0], acc[1], acc[2], acc[3]);
    *(float4*)&hacc[(size_t)n * DL + c + 4] = make_float4(acc[4], acc[5], acc[6], acc[7]);
}

// ---------------- BatchNorm stats over hg1 columns ----------------
__global__ __launch_bounds__(256) void bnstats_kernel(
    const ushort* __restrict__ hg1, float* __restrict__ colsum, float* __restrict__ colsum2)
{
    int col = threadIdx.x;            // 256 columns
    int row0 = blockIdx.x * 128;
    int rend = min(row0 + 128, NN);
    float s = 0.f, s2 = 0.f;
    for (int r = row0; r < rend; r++) {
        float v = bf2f(hg1[(size_t)r * DL + col]);
        s += v; s2 += v * v;
    }
    atomicAdd(&colsum[col], s);
    atomicAdd(&colsum2[col], s2);
}

__global__ void bnfinal_kernel(
    const float* __restrict__ colsum, const float* __restrict__ colsum2,
    const float* __restrict__ gamma, float* __restrict__ mu, float* __restrict__ aa)
{
    int c = threadIdx.x;
    if (c < DL) {
        float m = colsum[c] / (float)NN;
        float var = colsum2[c] / (float)NN - m * m;
        mu[c] = m;
        aa[c] = rsqrtf(var + 1e-5f) * gamma[c];
    }
}

// ---------------- gate = relu(BN(hg1)) @ Wg2 + bg2 ; segment max ----------------
__global__ __launch_bounds__(256) void gate_kernel(
    const ushort* __restrict__ hg1, const float* __restrict__ mu,
    const float* __restrict__ aa, const float* __restrict__ beta,
    const float* __restrict__ Wg2, const float* __restrict__ bg2,
    const int* __restrict__ batch,
    float* __restrict__ gate, unsigned* __restrict__ gmaxu)
{
    int lane = threadIdx.x & 63;
    int wid = (blockIdx.x * blockDim.x + threadIdx.x) >> 6;
    int nw = (gridDim.x * blockDim.x) >> 6;
    for (int n = wid; n < NN; n += nw) {
        float s = 0.f;
        #pragma unroll
        for (int c = 0; c < 4; c++) {
            int d = c * 64 + lane;
            float v = bf2f(hg1[(size_t)n * DL + d]);
            float xn = (v - mu[d]) * aa[d] + beta[d];
            xn = fmaxf(xn, 0.f);
            s += xn * Wg2[d];
        }
        #pragma unroll
        for (int o = 32; o > 0; o >>= 1) s += __shfl_down(s, o, 64);
        if (lane == 0) {
            float g = s + bg2[0];
            gate[n] = g;
            atomicMax(&gmaxu[batch[n]], fenc(g));
        }
    }
}

__global__ __launch_bounds__(256) void expdenom_kernel(
    const float* __restrict__ gate, const int* __restrict__ batch,
    const unsigned* __restrict__ gmaxu, float* __restrict__ ealpha, float* __restrict__ denom)
{
    int i = blockIdx.x * 256 + threadIdx.x;
    if (i < NN) {
        int b = batch[i];
        float ex = expf(gate[i] - fdec(gmaxu[b]));
        ealpha[i] = ex;
        atomicAdd(&denom[b], ex);
    }
}

// ---------------- pooled[g] = sum (e/denom) * h2[n] (batch sorted) ----------------
__global__ __launch_bounds__(256) void pool_kernel(
    const ushort* __restrict__ h2, const float* __restrict__ ealpha,
    const float* __restrict__ denom, const int* __restrict__ batch,
    float* __restrict__ pooled)
{
    int col = threadIdx.x;            // 256
    int row0 = blockIdx.x * 128;
    if (row0 >= NN) return;
    int rend = min(row0 + 128, NN);
    float accv = 0.f;
    int curg = batch[row0];
    for (int r = row0; r < rend; r++) {
        int g = batch[r];
        if (g != curg) {
            atomicAdd(&pooled[curg * DL + col], accv / denom[curg]);
            accv = 0.f; curg = g;
        }
        accv += ealpha[r] * bf2f(h2[(size_t)r * DL + col]);
    }
    atomicAdd(&pooled[curg * DL + col], accv / denom[curg]);
}

__global__ void head_kernel(
    const float* __restrict__ pooled, const float* __restrict__ Wgl,
    const float* __restrict__ bgl, float* __restrict__ out)
{
    int g = blockIdx.x;
    int lane = threadIdx.x;           // 64
    float s = 0.f;
    #pragma unroll
    for (int c = 0; c < 4; c++) {
        int d = c * 64 + lane;
        s += pooled[g * DL + d] * Wgl[d];
    }
    #pragma unroll
    for (int o = 32; o > 0; o >>= 1) s += __shfl_down(s, o, 64);
    if (lane == 0) out[g] = sigmoidf_(s + bgl[0]);
}

extern "C" void kernel_launch(void* const* d_in, const int* in_sizes, int n_in,
                              void* d_out, int out_size, void* d_ws, size_t ws_size,
                              hipStream_t stream)
{
    const int* x      = (const int*)d_in[0];
    const int* ei     = (const int*)d_in[1];
    const int* etype  = (const int*)d_in[2];
    const int* batch  = (const int*)d_in[3];
    const float* e0   = (const float*)d_in[4];
    const float* e1   = (const float*)d_in[5];
    const float* e2   = (const float*)d_in[6];
    const float* e3   = (const float*)d_in[7];
    const float* e4   = (const float*)d_in[8];
    const float* e5   = (const float*)d_in[9];
    const float* W1   = (const float*)d_in[10];
    const float* root1= (const float*)d_in[11];
    const float* b1   = (const float*)d_in[12];
    const float* W2   = (const float*)d_in[13];
    const float* root2= (const float*)d_in[14];
    const float* b2   = (const float*)d_in[15];
    const float* Wg1  = (const float*)d_in[16];
    const float* bg1  = (const float*)d_in[17];
    const float* gamma= (const float*)d_in[18];
    const float* beta = (const float*)d_in[19];
    const float* Wg2  = (const float*)d_in[20];
    const float* bg2  = (const float*)d_in[21];
    const float* Wgl  = (const float*)d_in[22];
    const float* bgl  = (const float*)d_in[23];
    float* out = (float*)d_out;

    const int* esrc_in = ei;          // edge_index[0]
    const int* edst_in = ei + EE;     // edge_index[1]

    char* ws = (char*)d_ws;
    size_t off = 0;
    auto alloc = [&](size_t b) -> char* {
        char* p = ws + off;
        off += (b + 255) & ~(size_t)255;
        return p;
    };
    // Peak ws ~181 MB (R1's 188 MB is known to fit; R4's 281 MB did not).
    ushort* hbuf   = (ushort*)alloc((size_t)NN * D0 * 2);    // 38.4 MB: h0, later h2
    ushort* h1     = (ushort*)alloc((size_t)NN * DL * 2);    // 25.6 MB
    float*  hacc   = (float*)alloc((size_t)NN * DL * 4);     // 51.2 MB fp32
    ushort* hrc    = (ushort*)alloc((size_t)NN * CHC * 2);   // 51.2 MB (later hg1)
    size_t zstart = off;                                     // ---- zeroed region ----
    int*      counts  = (int*)alloc((size_t)NN * RR * 4);
    float*    colsum  = (float*)alloc(DL * 4);
    float*    colsum2 = (float*)alloc(DL * 4);
    unsigned* gmaxu   = (unsigned*)alloc(GG * 4);
    float*    denom   = (float*)alloc(GG * 4);
    float*    pooled  = (float*)alloc((size_t)GG * DL * 4);
    size_t zbytes = off - zstart;                            // ---- end zeroed ----
    int*   offs    = (int*)alloc((size_t)NN * RR * 4);
    int*   cursors = (int*)alloc((size_t)NN * RR * 4);
    int*   eidx    = (int*)alloc((size_t)EE * 4);
    float* ew      = (float*)alloc((size_t)EE * 4);
    int*   blkSums = (int*)alloc(512);
    int*   blkOff  = (int*)alloc(512);
    float* mu      = (float*)alloc(DL * 4);
    float* aa      = (float*)alloc(DL * 4);
    float* gate    = (float*)alloc((size_t)NN * 4);
    float* ealpha  = (float*)alloc((size_t)NN * 4);
    ushort* WbT1   = (ushort*)alloc((size_t)9 * DL * D0 * 2);  // 1.77 MB
    ushort* WbT2   = (ushort*)alloc((size_t)9 * DL * DL * 2);  // 1.18 MB
    ushort* WbTg   = (ushort*)alloc((size_t)1 * DL * DL * 2);  // 131 KB

    ushort* h0  = hbuf;
    ushort* h2  = hbuf;   // h0 dead after layer1's final GEMM
    ushort* hg1 = hrc;    // hrc dead after layer2's last gather

    if (ws_size < off) return;   // fail loudly (wrong output) rather than corrupt

    hipMemsetAsync(ws + zstart, 0, zbytes, stream);

    embed_kernel<<<(NN * 48 + 255) / 256, 256, 0, stream>>>(x, e0, e1, e2, e3, e4, e5, h0);
    count_kernel<<<(EE + 255) / 256, 256, 0, stream>>>(edst_in, etype, counts);

    // weight bf16 transposes
    {
        int tot1 = 9 * DL * D0;
        cvtT_kernel<<<(tot1 + 255) / 256, 256, 0, stream>>>(W1, root1, WbT1, RR, D0);
        int tot2 = 9 * DL * DL;
        cvtT_kernel<<<(tot2 + 255) / 256, 256, 0, stream>>>(W2, root2, WbT2, RR, DL);
        int totg = 1 * DL * DL;
        cvtT_kernel<<<(totg + 255) / 256, 256, 0, stream>>>(nullptr, Wg1, WbTg, 0, DL);
    }

    const int M = NN * RR;
    const int NB = (M + SCAN_CHUNK - 1) / SCAN_CHUNK;   // 98
    scanA_kernel<<<NB, 256, 0, stream>>>(counts, M, blkSums);
    scanB_kernel<<<1, 64, 0, stream>>>(blkSums, NB, blkOff);
    scanC_kernel<<<NB, 256, 0, stream>>>(counts, M, blkOff, offs, cursors);
    scatter_kernel<<<(EE + 255) / 256, 256, 0, stream>>>(esrc_in, edst_in, etype, counts, cursors, eidx, ew);

    const int GBLK = (NN + 63) / 64;   // GEMM M-blocks
    const int ABLK = (NN + 7) / 8;     // gather blocks

    // ---- layer 1 (IN=384): 4 chunks of 2 relations, then fused root ----
    dense_gemm<D0, 2, 0><<<GBLK, 256, 0, stream>>>(h0, WbT1 + (size_t)0 * DL * D0, nullptr, nullptr, hrc, NN);
    gather_acc<0><<<ABLK, 256, 0, stream>>>(hrc, eidx, ew, offs, hacc);
    dense_gemm<D0, 2, 0><<<GBLK, 256, 0, stream>>>(h0, WbT1 + (size_t)2 * DL * D0, nullptr, nullptr, hrc, NN);
    gather_acc<1><<<ABLK, 256, 0, stream>>>(hrc, eidx, ew, offs, hacc);
    dense_gemm<D0, 2, 0><<<GBLK, 256, 0, stream>>>(h0, WbT1 + (size_t)4 * DL * D0, nullptr, nullptr, hrc, NN);
    gather_acc<2><<<ABLK, 256, 0, stream>>>(hrc, eidx, ew, offs, hacc);
    dense_gemm<D0, 2, 0><<<GBLK, 256, 0, stream>>>(h0, WbT1 + (size_t)6 * DL * D0, nullptr, nullptr, hrc, NN);
    gather_acc<3><<<ABLK, 256, 0, stream>>>(hrc, eidx, ew, offs, hacc);
    dense_gemm<D0, 1, 2><<<GBLK, 256, 0, stream>>>(h0, WbT1 + (size_t)8 * DL * D0, b1, hacc, h1, NN);

    // ---- layer 2 (IN=256) ----
    dense_gemm<DL, 2, 0><<<GBLK, 256, 0, stream>>>(h1, WbT2 + (size_t)0 * DL * DL, nullptr, nullptr, hrc, NN);
    gather_acc<0><<<ABLK, 256, 0, stream>>>(hrc, eidx, ew, offs, hacc);
    dense_gemm<DL, 2, 0><<<GBLK, 256, 0, stream>>>(h1, WbT2 + (size_t)2 * DL * DL, nullptr, nullptr, hrc, NN);
    gather_acc<1><<<ABLK, 256, 0, stream>>>(hrc, eidx, ew, offs, hacc);
    dense_gemm<DL, 2, 0><<<GBLK, 256, 0, stream>>>(h1, WbT2 + (size_t)4 * DL * DL, nullptr, nullptr, hrc, NN);
    gather_acc<2><<<ABLK, 256, 0, stream>>>(hrc, eidx, ew, offs, hacc);
    dense_gemm<DL, 2, 0><<<GBLK, 256, 0, stream>>>(h1, WbT2 + (size_t)6 * DL * DL, nullptr, nullptr, hrc, NN);
    gather_acc<3><<<ABLK, 256, 0, stream>>>(hrc, eidx, ew, offs, hacc);
    dense_gemm<DL, 1, 2><<<GBLK, 256, 0, stream>>>(h1, WbT2 + (size_t)8 * DL * DL, b2, hacc, h2, NN);

    // ---- gate linear (no act; BN follows) ----
    dense_gemm<DL, 1, 1><<<GBLK, 256, 0, stream>>>(h2, WbTg, bg1, nullptr, hg1, NN);

    bnstats_kernel<<<(NN + 127) / 128, 256, 0, stream>>>(hg1, colsum, colsum2);
    bnfinal_kernel<<<1, 256, 0, stream>>>(colsum, colsum2, gamma, mu, aa);
    gate_kernel<<<512, 256, 0, stream>>>(hg1, mu, aa, beta, Wg2, bg2, batch, gate, gmaxu);
    expdenom_kernel<<<(NN + 255) / 256, 256, 0, stream>>>(gate, batch, gmaxu, ealpha, denom);
    pool_kernel<<<(NN + 127) / 128, 256, 0, stream>>>(h2, ealpha, denom, batch, pooled);
    head_kernel<<<GG, 64, 0, stream>>>(pooled, Wgl, bgl, out);
}

// Round 6
// 1604.259 us; speedup vs baseline: 1.3470x; 1.1775x over previous
//
#include <hip/hip_runtime.h>
#include <hip/hip_bf16.h>
#include <cstdint>

#define NN 50000
#define EE 800000
#define RR 8
#define GG 128
#define D0 384
#define DL 256
#define CHC 512      // hrc columns: 2 relations * 256

typedef __attribute__((ext_vector_type(8))) short bf16x8;
typedef __attribute__((ext_vector_type(4))) float f32x4;

__device__ __forceinline__ float sigmoidf_(float x) { return 1.0f / (1.0f + expf(-x)); }

__device__ __forceinline__ ushort f2bf(float f) {
    uint u = __float_as_uint(f);
    u += 0x7fffu + ((u >> 16) & 1u);
    return (ushort)(u >> 16);
}
__device__ __forceinline__ uint pack2bf(float lo, float hi) {
    return (uint)f2bf(lo) | ((uint)f2bf(hi) << 16);
}
__device__ __forceinline__ float bf2f(ushort u) {
    return __uint_as_float((uint)u << 16);
}

// acc[0..7] += w * bf16x8(v)
__device__ __forceinline__ void accw8(float* s, uint4 a, float w) {
    s[0] += w * __uint_as_float(a.x << 16);
    s[1] += w * __uint_as_float(a.x & 0xffff0000u);
    s[2] += w * __uint_as_float(a.y << 16);
    s[3] += w * __uint_as_float(a.y & 0xffff0000u);
    s[4] += w * __uint_as_float(a.z << 16);
    s[5] += w * __uint_as_float(a.z & 0xffff0000u);
    s[6] += w * __uint_as_float(a.w << 16);
    s[7] += w * __uint_as_float(a.w & 0xffff0000u);
}

// order-preserving float->uint encoding for atomicMax
__device__ __forceinline__ unsigned fenc(float x) {
    unsigned u = __float_as_uint(x);
    return (u & 0x80000000u) ? ~u : (u | 0x80000000u);
}
__device__ __forceinline__ float fdec(unsigned u) {
    unsigned b = (u & 0x80000000u) ? (u & 0x7fffffffu) : ~u;
    return __uint_as_float(b);
}

// ---------------- embedding concat: h0[n, 0:384] (bf16) ----------------
__global__ __launch_bounds__(256) void embed_kernel(
    const int* __restrict__ x,
    const float* __restrict__ e0, const float* __restrict__ e1,
    const float* __restrict__ e2, const float* __restrict__ e3,
    const float* __restrict__ e4, const float* __restrict__ e5,
    ushort* __restrict__ h0)
{
    int idx = blockIdx.x * 256 + threadIdx.x;   // over NN*48 8-elem chunks
    if (idx >= NN * 48) return;
    int n = idx / 48;
    int q = idx - n * 48;
    int d = q * 8;
    int tbl = d >> 6;
    int w = d & 63;
    int row = x[n * 6 + tbl];
    const float* src;
    switch (tbl) {
        case 0: src = e0; break; case 1: src = e1; break; case 2: src = e2; break;
        case 3: src = e3; break; case 4: src = e4; break; default: src = e5; break;
    }
    float4 f0 = *(const float4*)&src[row * 64 + w];
    float4 f1 = *(const float4*)&src[row * 64 + w + 4];
    uint4 pk;
    pk.x = pack2bf(f0.x, f0.y);
    pk.y = pack2bf(f0.z, f0.w);
    pk.z = pack2bf(f1.x, f1.y);
    pk.w = pack2bf(f1.z, f1.w);
    *(uint4*)&h0[(size_t)n * D0 + d] = pk;
}

// ---------------- weight convert + transpose: WbT[r*256+n][k] = bf16(W[r][k][n]) ----------------
__global__ __launch_bounds__(256) void cvtT_kernel(
    const float* __restrict__ W, const float* __restrict__ root,
    ushort* __restrict__ WbT, int nrel, int IN)
{
    int idx = blockIdx.x * 256 + threadIdx.x;
    int tot = (nrel + 1) * DL * IN;
    if (idx >= tot) return;
    int k = idx % IN;
    int rn = idx / IN;
    int n = rn % DL;
    int r = rn / DL;
    float v = (r < nrel) ? W[((size_t)r * IN + k) * DL + n] : root[(size_t)k * DL + n];
    WbT[idx] = f2bf(v);
}

// ---------------- CSR build ----------------
__global__ __launch_bounds__(256) void count_kernel(
    const int* __restrict__ dst, const int* __restrict__ et, int* __restrict__ counts)
{
    int i = blockIdx.x * 256 + threadIdx.x;
    if (i < EE) atomicAdd(&counts[dst[i] * RR + et[i]], 1);
}

#define SCAN_CHUNK 4096
__global__ __launch_bounds__(256) void scanA_kernel(const int* __restrict__ cnt, int M, int* __restrict__ blkSums)
{
    __shared__ int s[256];
    int b = blockIdx.x, t = threadIdx.x;
    int base = b * SCAN_CHUNK + t * 16;
    int tot = 0;
    #pragma unroll
    for (int i = 0; i < 16; i++) { int idx = base + i; if (idx < M) tot += cnt[idx]; }
    s[t] = tot; __syncthreads();
    for (int off = 128; off > 0; off >>= 1) {
        if (t < off) s[t] += s[t + off];
        __syncthreads();
    }
    if (t == 0) blkSums[b] = s[0];
}

__global__ void scanB_kernel(const int* __restrict__ blkSums, int NB, int* __restrict__ blkOff)
{
    if (threadIdx.x == 0) {
        int run = 0;
        for (int i = 0; i < NB; i++) { blkOff[i] = run; run += blkSums[i]; }
    }
}

__global__ __launch_bounds__(256) void scanC_kernel(
    const int* __restrict__ cnt, int M, const int* __restrict__ blkOff,
    int* __restrict__ offs, int* __restrict__ curs)
{
    __shared__ int s[256];
    int b = blockIdx.x, t = threadIdx.x;
    int base = b * SCAN_CHUNK + t * 16;
    int loc[16];
    int tot = 0;
    #pragma unroll
    for (int i = 0; i < 16; i++) {
        int idx = base + i;
        int v = (idx < M) ? cnt[idx] : 0;
        loc[i] = tot; tot += v;
    }
    s[t] = tot; __syncthreads();
    for (int off = 1; off < 256; off <<= 1) {
        int v = (t >= off) ? s[t - off] : 0;
        __syncthreads();
        s[t] += v;
        __syncthreads();
    }
    int texc = s[t] - tot;           // exclusive prefix of this thread
    int bb = blkOff[b];
    #pragma unroll
    for (int i = 0; i < 16; i++) {
        int idx = base + i;
        if (idx < M) { int o = bb + texc + loc[i]; offs[idx] = o; curs[idx] = o; }
    }
}

// scatter: per-edge gather index into the 2-relation chunk (src*512 + (r&1)*256)
// and weight 1/cnt. CSR order is by (dst, rel) bucket.
__global__ __launch_bounds__(256) void scatter_kernel(
    const int* __restrict__ src, const int* __restrict__ dst, const int* __restrict__ et,
    const int* __restrict__ cnts, int* __restrict__ cursors,
    int* __restrict__ eidx, float* __restrict__ ew)
{
    int i = blockIdx.x * 256 + threadIdx.x;
    if (i < EE) {
        int r = et[i];
        int b = dst[i] * RR + r;
        int pos = atomicAdd(&cursors[b], 1);
        eidx[pos] = src[i] * CHC + (r & 1) * DL;
        ew[pos] = 1.0f / (float)cnts[b];
    }
}

// ---------------- dense bf16 MFMA GEMM: C[M][NCB*256] = A[M][K] @ Bt^T ----------------
// Bt rows are output columns: Bt[j][k], j = cb*256 + c. BM=64, 4 waves.
// MODE 0: write bf16. MODE 1: +bias, write bf16 (gate). MODE 2: +hacc+bias,
// sigmoid, write bf16 (fused root+aggregate finalize).
template<int K, int NCB, int MODE>
__global__ __launch_bounds__(256) void dense_gemm(
    const ushort* __restrict__ A,    // [M][K] bf16
    const ushort* __restrict__ Bt,   // [NCB*256][K] bf16
    const float* __restrict__ bias,  // [256] (MODE>=1)
    const float* __restrict__ hacc,  // [M][256] fp32 (MODE==2)
    ushort* __restrict__ C,          // [M][NCB*256] bf16
    int M)
{
    constexpr int NC = K / 32;
    constexpr int LDA_ = K + 8;      // +16B pad -> <=2-way LDS banks
    constexpr int NCOL = NCB * 256;
    __shared__ ushort Ab[64][LDA_];

    const int t    = threadIdx.x;
    const int base = blockIdx.x * 64;
    const int lane = t & 63;
    const int wv   = t >> 6;
    const int l15  = lane & 15;
    const int kg   = lane >> 4;
    const int wcol = wv * 64;

    // ---- stage A tile ----
    constexpr int CW = K / 8;        // uint4 chunks per row
    constexpr int NL = 64 * CW / 256;
    #pragma unroll
    for (int i = 0; i < NL; i++) {
        int idx = t + i * 256;
        int row = idx / CW, col = idx - row * CW;
        int gr = base + row; if (gr >= M) gr = M - 1;
        *(uint4*)&Ab[row][col * 8] = *(const uint4*)&A[(size_t)gr * K + col * 8];
    }
    __syncthreads();

    union FR { bf16x8 v; uint u[4]; };

    for (int cb = 0; cb < NCB; cb++) {
        f32x4 acc[4][4];
        #pragma unroll
        for (int mt = 0; mt < 4; mt++)
            #pragma unroll
            for (int nt = 0; nt < 4; nt++) acc[mt][nt] = (f32x4){0.f, 0.f, 0.f, 0.f};

        const ushort* bpb = Bt + (size_t)(cb * 256 + wcol + l15) * K + kg * 4;

        for (int ks = 0; ks < NC; ks++) {
            FR a[4], b[4];
            #pragma unroll
            for (int mt = 0; mt < 4; mt++) {
                const ushort* ap = &Ab[mt * 16 + l15][ks * 32 + kg * 4];
                uint2 x0 = *(const uint2*)ap;
                uint2 x1 = *(const uint2*)(ap + 16);
                a[mt].u[0] = x0.x; a[mt].u[1] = x0.y; a[mt].u[2] = x1.x; a[mt].u[3] = x1.y;
            }
            #pragma unroll
            for (int nt = 0; nt < 4; nt++) {
                const ushort* p = bpb + (size_t)nt * 16 * K + ks * 32;
                uint2 lo = *(const uint2*)p;
                uint2 hi = *(const uint2*)(p + 16);
                b[nt].u[0] = lo.x; b[nt].u[1] = lo.y; b[nt].u[2] = hi.x; b[nt].u[3] = hi.y;
            }
            #pragma unroll
            for (int nt = 0; nt < 4; nt++)
                #pragma unroll
                for (int mt = 0; mt < 4; mt++)
                    acc[mt][nt] = __builtin_amdgcn_mfma_f32_16x16x32_bf16(a[mt].v, b[nt].v, acc[mt][nt], 0, 0, 0);
        }

        // epilogue: C/D layout col=lane&15, row=(lane>>4)*4+i
        #pragma unroll
        for (int nt = 0; nt < 4; nt++) {
            int ccol = wcol + nt * 16 + l15;
            float bv = (MODE >= 1) ? bias[ccol] : 0.f;
            #pragma unroll
            for (int mt = 0; mt < 4; mt++) {
                #pragma unroll
                for (int i = 0; i < 4; i++) {
                    int row = base + mt * 16 + kg * 4 + i;
                    if (row < M) {
                        float v = acc[mt][nt][i] + bv;
                        if (MODE == 2) {
                            v += hacc[(size_t)row * DL + ccol];
                            v = sigmoidf_(v);
                        }
                        C[(size_t)row * NCOL + cb * 256 + ccol] = f2bf(v);
                    }
                }
            }
        }
    }
}

// ---------------- chunked flat CSR gather-accumulate ----------------
// Pass P covers relations {2P, 2P+1}: CSR buckets (n,2P),(n,2P+1) are
// contiguous. half-wave per node, 8 cols (16B) per lane, 4-deep unroll.
// P==0 initializes hacc, else accumulates.
template<int P>
__global__ __launch_bounds__(256) void gather_acc(
    const ushort* __restrict__ hrc,  // [N][512] bf16
    const int* __restrict__ eidx,
    const float* __restrict__ ew,
    const int* __restrict__ offs,    // [N*8]
    float* __restrict__ hacc)        // [N][256] fp32
{
    int t = threadIdx.x;
    int slot = t >> 5;               // 0..7
    int l = t & 31;
    int n = blockIdx.x * 8 + slot;
    if (n >= NN) return;
    int e    = offs[n * 8 + 2 * P];
    int endE = (P == 3) ? ((n == NN - 1) ? EE : offs[n * 8 + 8])
                        : offs[n * 8 + 2 * P + 2];
    int c = l * 8;

    float acc[8];
    if (P == 0) {
        #pragma unroll
        for (int q = 0; q < 8; q++) acc[q] = 0.f;
    } else {
        float4 a0 = *(const float4*)&hacc[(size_t)n * DL + c];
        float4 a1 = *(const float4*)&hacc[(size_t)n * DL + c + 4];
        acc[0] = a0.x; acc[1] = a0.y; acc[2] = a0.z; acc[3] = a0.w;
        acc[4] = a1.x; acc[5] = a1.y; acc[6] = a1.z; acc[7] = a1.w;
    }

    for (; e + 4 <= endE; e += 4) {
        int i0 = eidx[e], i1 = eidx[e + 1], i2 = eidx[e + 2], i3 = eidx[e + 3];
        float w0 = ew[e], w1 = ew[e + 1], w2 = ew[e + 2], w3 = ew[e + 3];
        uint4 v0 = *(const uint4*)&hrc[(size_t)i0 + c];
        uint4 v1 = *(const uint4*)&hrc[(size_t)i1 + c];
        uint4 v2 = *(const uint4*)&hrc[(size_t)i2 + c];
        uint4 v3 = *(const uint4*)&hrc[(size_t)i3 + c];
        accw8(acc, v0, w0); accw8(acc, v1, w1);
        accw8(acc, v2, w2); accw8(acc, v3, w3);
    }
    for (; e < endE; e++) {
        uint4 v = *(const uint4*)&hrc[(size_t)eidx[e] + c];
        accw8(acc, v, ew[e]);
    }

    *(float4*)&hacc[(size_t)n * DL + c]     = make_float4(acc[0], acc[1], acc[2], acc[3]);
    *(float4*)&hacc[(size_t)n * DL + c + 4] = make_float4(acc[4], acc[5], acc[6], acc[7]);
}

// ---------------- BatchNorm stats over hg1 columns ----------------
__global__ __launch_bounds__(256) void bnstats_kernel(
    const ushort* __restrict__ hg1, float* __restrict__ colsum, float* __restrict__ colsum2)
{
    int col = threadIdx.x;            // 256 columns
    int rpb = (NN + 127) / 128;       // 391 rows per block, 128 blocks
    int row0 = blockIdx.x * rpb;
    int rend = min(row0 + rpb, NN);
    float s = 0.f, s2 = 0.f;
    for (int r = row0; r < rend; r++) {
        float v = bf2f(hg1[(size_t)r * DL + col]);
        s += v; s2 += v * v;
    }
    atomicAdd(&colsum[col], s);
    atomicAdd(&colsum2[col], s2);
}

__global__ void bnfinal_kernel(
    const float* __restrict__ colsum, const float* __restrict__ colsum2,
    const float* __restrict__ gamma, float* __restrict__ mu, float* __restrict__ aa)
{
    int c = threadIdx.x;
    if (c < DL) {
        float m = colsum[c] / (float)NN;
        float var = colsum2[c] / (float)NN - m * m;
        mu[c] = m;
        aa[c] = rsqrtf(var + 1e-5f) * gamma[c];
    }
}

// ---------------- gate = relu(BN(hg1)) @ Wg2 + bg2 ; segment max ----------------
// Each wave owns a CONTIGUOUS run of nodes; per-graph-run local max with one
// atomic per run boundary (batch is sorted) -- avoids time-correlated
// same-address atomic storms.
__global__ __launch_bounds__(256) void gate_kernel(
    const ushort* __restrict__ hg1, const float* __restrict__ mu,
    const float* __restrict__ aa, const float* __restrict__ beta,
    const float* __restrict__ Wg2, const float* __restrict__ bg2,
    const int* __restrict__ batch,
    float* __restrict__ gate, unsigned* __restrict__ gmaxu)
{
    int lane = threadIdx.x & 63;
    int wid = (blockIdx.x * blockDim.x + threadIdx.x) >> 6;
    int nw = (gridDim.x * blockDim.x) >> 6;
    int per = (NN + nw - 1) / nw;
    int n0 = wid * per;
    if (n0 >= NN) return;
    int n1 = min(n0 + per, NN);
    float bg2v = bg2[0];
    float lmax = -3.4e38f;
    int curb = batch[n0];
    for (int n = n0; n < n1; n++) {
        float s = 0.f;
        #pragma unroll
        for (int c = 0; c < 4; c++) {
            int d = c * 64 + lane;
            float v = bf2f(hg1[(size_t)n * DL + d]);
            float xn = (v - mu[d]) * aa[d] + beta[d];
            xn = fmaxf(xn, 0.f);
            s += xn * Wg2[d];
        }
        #pragma unroll
        for (int o = 32; o > 0; o >>= 1) s += __shfl_down(s, o, 64);
        if (lane == 0) {
            float g = s + bg2v;
            gate[n] = g;
            int b = batch[n];
            if (b != curb) {
                atomicMax(&gmaxu[curb], fenc(lmax));
                lmax = -3.4e38f; curb = b;
            }
            lmax = fmaxf(lmax, g);
        }
    }
    if (lane == 0) atomicMax(&gmaxu[curb], fenc(lmax));
}

// ---------------- exp + per-graph denom (contiguous 4-node runs/thread) ----
__global__ __launch_bounds__(256) void expdenom_kernel(
    const float* __restrict__ gate, const int* __restrict__ batch,
    const unsigned* __restrict__ gmaxu, float* __restrict__ ealpha, float* __restrict__ denom)
{
    int tid = blockIdx.x * 256 + threadIdx.x;
    int i0 = tid * 4;
    if (i0 >= NN) return;
    int i1 = min(i0 + 4, NN);
    int curb = batch[i0];
    float m = fdec(gmaxu[curb]);
    float lsum = 0.f;
    for (int i = i0; i < i1; i++) {
        int b = batch[i];
        if (b != curb) {
            atomicAdd(&denom[curb], lsum);
            lsum = 0.f; curb = b; m = fdec(gmaxu[b]);
        }
        float ex = expf(gate[i] - m);
        ealpha[i] = ex;
        lsum += ex;
    }
    atomicAdd(&denom[curb], lsum);
}

// ---------------- pooled[g] = sum (e/denom) * h2[n] (batch sorted) ----------------
__global__ __launch_bounds__(256) void pool_kernel(
    const ushort* __restrict__ h2, const float* __restrict__ ealpha,
    const float* __restrict__ denom, const int* __restrict__ batch,
    float* __restrict__ pooled)
{
    int col = threadIdx.x;            // 256
    int row0 = blockIdx.x * 128;
    if (row0 >= NN) return;
    int rend = min(row0 + 128, NN);
    float accv = 0.f;
    int curg = batch[row0];
    for (int r = row0; r < rend; r++) {
        int g = batch[r];
        if (g != curg) {
            atomicAdd(&pooled[curg * DL + col], accv / denom[curg]);
            accv = 0.f; curg = g;
        }
        accv += ealpha[r] * bf2f(h2[(size_t)r * DL + col]);
    }
    atomicAdd(&pooled[curg * DL + col], accv / denom[curg]);
}

__global__ void head_kernel(
    const float* __restrict__ pooled, const float* __restrict__ Wgl,
    const float* __restrict__ bgl, float* __restrict__ out)
{
    int g = blockIdx.x;
    int lane = threadIdx.x;           // 64
    float s = 0.f;
    #pragma unroll
    for (int c = 0; c < 4; c++) {
        int d = c * 64 + lane;
        s += pooled[g * DL + d] * Wgl[d];
    }
    #pragma unroll
    for (int o = 32; o > 0; o >>= 1) s += __shfl_down(s, o, 64);
    if (lane == 0) out[g] = sigmoidf_(s + bgl[0]);
}

extern "C" void kernel_launch(void* const* d_in, const int* in_sizes, int n_in,
                              void* d_out, int out_size, void* d_ws, size_t ws_size,
                              hipStream_t stream)
{
    const int* x      = (const int*)d_in[0];
    const int* ei     = (const int*)d_in[1];
    const int* etype  = (const int*)d_in[2];
    const int* batch  = (const int*)d_in[3];
    const float* e0   = (const float*)d_in[4];
    const float* e1   = (const float*)d_in[5];
    const float* e2   = (const float*)d_in[6];
    const float* e3   = (const float*)d_in[7];
    const float* e4   = (const float*)d_in[8];
    const float* e5   = (const float*)d_in[9];
    const float* W1   = (const float*)d_in[10];
    const float* root1= (const float*)d_in[11];
    const float* b1   = (const float*)d_in[12];
    const float* W2   = (const float*)d_in[13];
    const float* root2= (const float*)d_in[14];
    const float* b2   = (const float*)d_in[15];
    const float* Wg1  = (const float*)d_in[16];
    const float* bg1  = (const float*)d_in[17];
    const float* gamma= (const float*)d_in[18];
    const float* beta = (const float*)d_in[19];
    const float* Wg2  = (const float*)d_in[20];
    const float* bg2  = (const float*)d_in[21];
    const float* Wgl  = (const float*)d_in[22];
    const float* bgl  = (const float*)d_in[23];
    float* out = (float*)d_out;

    const int* esrc_in = ei;          // edge_index[0]
    const int* edst_in = ei + EE;     // edge_index[1]

    char* ws = (char*)d_ws;
    size_t off = 0;
    auto alloc = [&](size_t b) -> char* {
        char* p = ws + off;
        off += (b + 255) & ~(size_t)255;
        return p;
    };
    // Peak ws ~181 MB (R1's 188 MB fits; R4's 281 MB did not).
    ushort* hbuf   = (ushort*)alloc((size_t)NN * D0 * 2);    // 38.4 MB: h0, later h2
    ushort* h1     = (ushort*)alloc((size_t)NN * DL * 2);    // 25.6 MB
    float*  hacc   = (float*)alloc((size_t)NN * DL * 4);     // 51.2 MB fp32
    ushort* hrc    = (ushort*)alloc((size_t)NN * CHC * 2);   // 51.2 MB (later hg1)
    size_t zstart = off;                                     // ---- zeroed region ----
    int*      counts  = (int*)alloc((size_t)NN * RR * 4);
    float*    colsum  = (float*)alloc(DL * 4);
    float*    colsum2 = (float*)alloc(DL * 4);
    unsigned* gmaxu   = (unsigned*)alloc(GG * 4);
    float*    denom   = (float*)alloc(GG * 4);
    float*    pooled  = (float*)alloc((size_t)GG * DL * 4);
    size_t zbytes = off - zstart;                            // ---- end zeroed ----
    int*   offs    = (int*)alloc((size_t)NN * RR * 4);
    int*   cursors = (int*)alloc((size_t)NN * RR * 4);
    int*   eidx    = (int*)alloc((size_t)EE * 4);
    float* ew      = (float*)alloc((size_t)EE * 4);
    int*   blkSums = (int*)alloc(512);
    int*   blkOff  = (int*)alloc(512);
    float* mu      = (float*)alloc(DL * 4);
    float* aa      = (float*)alloc(DL * 4);
    float* gate    = (float*)alloc((size_t)NN * 4);
    float* ealpha  = (float*)alloc((size_t)NN * 4);
    ushort* WbT1   = (ushort*)alloc((size_t)9 * DL * D0 * 2);  // 1.77 MB
    ushort* WbT2   = (ushort*)alloc((size_t)9 * DL * DL * 2);  // 1.18 MB
    ushort* WbTg   = (ushort*)alloc((size_t)1 * DL * DL * 2);  // 131 KB

    ushort* h0  = hbuf;
    ushort* h2  = hbuf;   // h0 dead after layer1's final GEMM
    ushort* hg1 = hrc;    // hrc dead after layer2's last gather

    if (ws_size < off) return;   // fail loudly (wrong output) rather than corrupt

    hipMemsetAsync(ws + zstart, 0, zbytes, stream);

    embed_kernel<<<(NN * 48 + 255) / 256, 256, 0, stream>>>(x, e0, e1, e2, e3, e4, e5, h0);
    count_kernel<<<(EE + 255) / 256, 256, 0, stream>>>(edst_in, etype, counts);

    // weight bf16 transposes
    {
        int tot1 = 9 * DL * D0;
        cvtT_kernel<<<(tot1 + 255) / 256, 256, 0, stream>>>(W1, root1, WbT1, RR, D0);
        int tot2 = 9 * DL * DL;
        cvtT_kernel<<<(tot2 + 255) / 256, 256, 0, stream>>>(W2, root2, WbT2, RR, DL);
        int totg = 1 * DL * DL;
        cvtT_kernel<<<(totg + 255) / 256, 256, 0, stream>>>(nullptr, Wg1, WbTg, 0, DL);
    }

    const int M = NN * RR;
    const int NB = (M + SCAN_CHUNK - 1) / SCAN_CHUNK;   // 98
    scanA_kernel<<<NB, 256, 0, stream>>>(counts, M, blkSums);
    scanB_kernel<<<1, 64, 0, stream>>>(blkSums, NB, blkOff);
    scanC_kernel<<<NB, 256, 0, stream>>>(counts, M, blkOff, offs, cursors);
    scatter_kernel<<<(EE + 255) / 256, 256, 0, stream>>>(esrc_in, edst_in, etype, counts, cursors, eidx, ew);

    const int GBLK = (NN + 63) / 64;   // GEMM M-blocks
    const int ABLK = (NN + 7) / 8;     // gather blocks

    // ---- layer 1 (IN=384): 4 chunks of 2 relations, then fused root ----
    dense_gemm<D0, 2, 0><<<GBLK, 256, 0, stream>>>(h0, WbT1 + (size_t)0 * DL * D0, nullptr, nullptr, hrc, NN);
    gather_acc<0><<<ABLK, 256, 0, stream>>>(hrc, eidx, ew, offs, hacc);
    dense_gemm<D0, 2, 0><<<GBLK, 256, 0, stream>>>(h0, WbT1 + (size_t)2 * DL * D0, nullptr, nullptr, hrc, NN);
    gather_acc<1><<<ABLK, 256, 0, stream>>>(hrc, eidx, ew, offs, hacc);
    dense_gemm<D0, 2, 0><<<GBLK, 256, 0, stream>>>(h0, WbT1 + (size_t)4 * DL * D0, nullptr, nullptr, hrc, NN);
    gather_acc<2><<<ABLK, 256, 0, stream>>>(hrc, eidx, ew, offs, hacc);
    dense_gemm<D0, 2, 0><<<GBLK, 256, 0, stream>>>(h0, WbT1 + (size_t)6 * DL * D0, nullptr, nullptr, hrc, NN);
    gather_acc<3><<<ABLK, 256, 0, stream>>>(hrc, eidx, ew, offs, hacc);
    dense_gemm<D0, 1, 2><<<GBLK, 256, 0, stream>>>(h0, WbT1 + (size_t)8 * DL * D0, b1, hacc, h1, NN);

    // ---- layer 2 (IN=256) ----
    dense_gemm<DL, 2, 0><<<GBLK, 256, 0, stream>>>(h1, WbT2 + (size_t)0 * DL * DL, nullptr, nullptr, hrc, NN);
    gather_acc<0><<<ABLK, 256, 0, stream>>>(hrc, eidx, ew, offs, hacc);
    dense_gemm<DL, 2, 0><<<GBLK, 256, 0, stream>>>(h1, WbT2 + (size_t)2 * DL * DL, nullptr, nullptr, hrc, NN);
    gather_acc<1><<<ABLK, 256, 0, stream>>>(hrc, eidx, ew, offs, hacc);
    dense_gemm<DL, 2, 0><<<GBLK, 256, 0, stream>>>(h1, WbT2 + (size_t)4 * DL * DL, nullptr, nullptr, hrc, NN);
    gather_acc<2><<<ABLK, 256, 0, stream>>>(hrc, eidx, ew, offs, hacc);
    dense_gemm<DL, 2, 0><<<GBLK, 256, 0, stream>>>(h1, WbT2 + (size_t)6 * DL * DL, nullptr, nullptr, hrc, NN);
    gather_acc<3><<<ABLK, 256, 0, stream>>>(hrc, eidx, ew, offs, hacc);
    dense_gemm<DL, 1, 2><<<GBLK, 256, 0, stream>>>(h1, WbT2 + (size_t)8 * DL * DL, b2, hacc, h2, NN);

    // ---- gate linear (no act; BN follows) ----
    dense_gemm<DL, 1, 1><<<GBLK, 256, 0, stream>>>(h2, WbTg, bg1, nullptr, hg1, NN);

    bnstats_kernel<<<128, 256, 0, stream>>>(hg1, colsum, colsum2);
    bnfinal_kernel<<<1, 256, 0, stream>>>(colsum, colsum2, gamma, mu, aa);
    gate_kernel<<<512, 256, 0, stream>>>(hg1, mu, aa, beta, Wg2, bg2, batch, gate, gmaxu);
    expdenom_kernel<<<((NN + 3) / 4 + 255) / 256, 256, 0, stream>>>(gate, batch, gmaxu, ealpha, denom);
    pool_kernel<<<(NN + 127) / 128, 256, 0, stream>>>(h2, ealpha, denom, batch, pooled);
    head_kernel<<<GG, 64, 0, stream>>>(pooled, Wgl, bgl, out);
}

// Round 7
// 1065.797 us; speedup vs baseline: 2.0276x; 1.5052x over previous
//
#include <hip/hip_runtime.h>
#include <hip/hip_bf16.h>
#include <cstdint>

#define NN 50000
#define EE 800000
#define RR 8
#define GG 128
#define D0 384
#define DL 256
#define CHC 512      // hrc columns: 2 relations * 256

typedef __attribute__((ext_vector_type(8))) short bf16x8;
typedef __attribute__((ext_vector_type(4))) float f32x4;

__device__ __forceinline__ float sigmoidf_(float x) { return 1.0f / (1.0f + expf(-x)); }

__device__ __forceinline__ ushort f2bf(float f) {
    uint u = __float_as_uint(f);
    u += 0x7fffu + ((u >> 16) & 1u);
    return (ushort)(u >> 16);
}
__device__ __forceinline__ uint pack2bf(float lo, float hi) {
    return (uint)f2bf(lo) | ((uint)f2bf(hi) << 16);
}
__device__ __forceinline__ float bf2f(ushort u) {
    return __uint_as_float((uint)u << 16);
}

// acc[0..7] += w * bf16x8(v)
__device__ __forceinline__ void accw8(float* s, uint4 a, float w) {
    s[0] += w * __uint_as_float(a.x << 16);
    s[1] += w * __uint_as_float(a.x & 0xffff0000u);
    s[2] += w * __uint_as_float(a.y << 16);
    s[3] += w * __uint_as_float(a.y & 0xffff0000u);
    s[4] += w * __uint_as_float(a.z << 16);
    s[5] += w * __uint_as_float(a.z & 0xffff0000u);
    s[6] += w * __uint_as_float(a.w << 16);
    s[7] += w * __uint_as_float(a.w & 0xffff0000u);
}

// order-preserving float->uint encoding for atomicMax
__device__ __forceinline__ unsigned fenc(float x) {
    unsigned u = __float_as_uint(x);
    return (u & 0x80000000u) ? ~u : (u | 0x80000000u);
}
__device__ __forceinline__ float fdec(unsigned u) {
    unsigned b = (u & 0x80000000u) ? (u & 0x7fffffffu) : ~u;
    return __uint_as_float(b);
}

// ---------------- embedding concat: h0[n, 0:384] (bf16) ----------------
__global__ __launch_bounds__(256) void embed_kernel(
    const int* __restrict__ x,
    const float* __restrict__ e0, const float* __restrict__ e1,
    const float* __restrict__ e2, const float* __restrict__ e3,
    const float* __restrict__ e4, const float* __restrict__ e5,
    ushort* __restrict__ h0)
{
    int idx = blockIdx.x * 256 + threadIdx.x;   // over NN*48 8-elem chunks
    if (idx >= NN * 48) return;
    int n = idx / 48;
    int q = idx - n * 48;
    int d = q * 8;
    int tbl = d >> 6;
    int w = d & 63;
    int row = x[n * 6 + tbl];
    const float* src;
    switch (tbl) {
        case 0: src = e0; break; case 1: src = e1; break; case 2: src = e2; break;
        case 3: src = e3; break; case 4: src = e4; break; default: src = e5; break;
    }
    float4 f0 = *(const float4*)&src[row * 64 + w];
    float4 f1 = *(const float4*)&src[row * 64 + w + 4];
    uint4 pk;
    pk.x = pack2bf(f0.x, f0.y);
    pk.y = pack2bf(f0.z, f0.w);
    pk.z = pack2bf(f1.x, f1.y);
    pk.w = pack2bf(f1.z, f1.w);
    *(uint4*)&h0[(size_t)n * D0 + d] = pk;
}

// ---------------- weight convert + transpose: WbT[r*256+n][k] = bf16(W[r][k][n]) ----------------
__global__ __launch_bounds__(256) void cvtT_kernel(
    const float* __restrict__ W, const float* __restrict__ root,
    ushort* __restrict__ WbT, int nrel, int IN)
{
    int idx = blockIdx.x * 256 + threadIdx.x;
    int tot = (nrel + 1) * DL * IN;
    if (idx >= tot) return;
    int k = idx % IN;
    int rn = idx / IN;
    int n = rn % DL;
    int r = rn / DL;
    float v = (r < nrel) ? W[((size_t)r * IN + k) * DL + n] : root[(size_t)k * DL + n];
    WbT[idx] = f2bf(v);
}

// ---------------- CSR build ----------------
__global__ __launch_bounds__(256) void count_kernel(
    const int* __restrict__ dst, const int* __restrict__ et, int* __restrict__ counts)
{
    int i = blockIdx.x * 256 + threadIdx.x;
    if (i < EE) atomicAdd(&counts[dst[i] * RR + et[i]], 1);
}

#define SCAN_CHUNK 4096
__global__ __launch_bounds__(256) void scanA_kernel(const int* __restrict__ cnt, int M, int* __restrict__ blkSums)
{
    __shared__ int s[256];
    int b = blockIdx.x, t = threadIdx.x;
    int base = b * SCAN_CHUNK + t * 16;
    int tot = 0;
    #pragma unroll
    for (int i = 0; i < 16; i++) { int idx = base + i; if (idx < M) tot += cnt[idx]; }
    s[t] = tot; __syncthreads();
    for (int off = 128; off > 0; off >>= 1) {
        if (t < off) s[t] += s[t + off];
        __syncthreads();
    }
    if (t == 0) blkSums[b] = s[0];
}

__global__ void scanB_kernel(const int* __restrict__ blkSums, int NB, int* __restrict__ blkOff)
{
    if (threadIdx.x == 0) {
        int run = 0;
        for (int i = 0; i < NB; i++) { blkOff[i] = run; run += blkSums[i]; }
    }
}

__global__ __launch_bounds__(256) void scanC_kernel(
    const int* __restrict__ cnt, int M, const int* __restrict__ blkOff,
    int* __restrict__ offs, int* __restrict__ curs)
{
    __shared__ int s[256];
    int b = blockIdx.x, t = threadIdx.x;
    int base = b * SCAN_CHUNK + t * 16;
    int loc[16];
    int tot = 0;
    #pragma unroll
    for (int i = 0; i < 16; i++) {
        int idx = base + i;
        int v = (idx < M) ? cnt[idx] : 0;
        loc[i] = tot; tot += v;
    }
    s[t] = tot; __syncthreads();
    for (int off = 1; off < 256; off <<= 1) {
        int v = (t >= off) ? s[t - off] : 0;
        __syncthreads();
        s[t] += v;
        __syncthreads();
    }
    int texc = s[t] - tot;           // exclusive prefix of this thread
    int bb = blkOff[b];
    #pragma unroll
    for (int i = 0; i < 16; i++) {
        int idx = base + i;
        if (idx < M) { int o = bb + texc + loc[i]; offs[idx] = o; curs[idx] = o; }
    }
}

// scatter: per-edge gather index into the 2-relation chunk (src*512 + (r&1)*256)
// and weight 1/cnt. CSR order is by (dst, rel) bucket.
__global__ __launch_bounds__(256) void scatter_kernel(
    const int* __restrict__ src, const int* __restrict__ dst, const int* __restrict__ et,
    const int* __restrict__ cnts, int* __restrict__ cursors,
    int* __restrict__ eidx, float* __restrict__ ew)
{
    int i = blockIdx.x * 256 + threadIdx.x;
    if (i < EE) {
        int r = et[i];
        int b = dst[i] * RR + r;
        int pos = atomicAdd(&cursors[b], 1);
        eidx[pos] = src[i] * CHC + (r & 1) * DL;
        ew[pos] = 1.0f / (float)cnts[b];
    }
}

// ---------------- dense bf16 MFMA GEMM, both operands LDS-staged ----------------
// Tile: BM=128 x BN=128 x BK=64, 4 waves, each wave 64x64 (4x4 16x16 frags).
// grid = (N/128, ceil(M/128)); n fastest so same-A blocks co-run (L2 reuse).
// T14 split staging: issue kt+1 global loads before computing kt; LDS-write
// after the read barrier. MODE 0: plain; 1: +bias (gate); 2: +hacc+bias+sigmoid.
template<int K, int MODE>
__global__ __launch_bounds__(256) void dense_gemm(
    const ushort* __restrict__ A,    // [M][K] bf16
    const ushort* __restrict__ Bt,   // [ntiles*128][K] bf16 (rows = C cols)
    const float* __restrict__ bias,  // [NCOL] (MODE>=1)
    const float* __restrict__ haccp, // [M][256] fp32 (MODE==2)
    ushort* __restrict__ C,          // [M][NCOL] bf16
    int M, int NCOL)
{
    constexpr int NKT = K / 64;
    constexpr int LDA = 68;          // 64 + 4 pad elems -> ~4-way banks on frag reads
    __shared__ ushort Al[128 * LDA]; // 17.4 KB
    __shared__ ushort Bl[128 * LDA]; // 17.4 KB

    const int t   = threadIdx.x;
    const int m0  = blockIdx.y * 128;
    const int n0  = blockIdx.x * 128;
    const int lane = t & 63;
    const int wv  = t >> 6;
    const int wr  = (wv >> 1) * 64;  // wave row offset
    const int wc  = (wv & 1) * 64;   // wave col offset
    const int l15 = lane & 15;
    const int kg  = lane >> 4;

    // staging decomposition: thread covers rows sr+32i, elem cols sc..sc+7
    const int sr = t >> 3;
    const int sc = (t & 7) * 8;
    int arow[4], brow[4];
    #pragma unroll
    for (int i = 0; i < 4; i++) {
        int r = sr + i * 32;
        arow[i] = min(m0 + r, M - 1);
        brow[i] = n0 + r;
    }

    uint4 av[4], bv[4];
    auto SLOAD = [&](int kt) {
        const ushort* Ak = A + kt * 64 + sc;
        const ushort* Bk = Bt + kt * 64 + sc;
        #pragma unroll
        for (int i = 0; i < 4; i++) av[i] = *(const uint4*)(Ak + (size_t)arow[i] * K);
        #pragma unroll
        for (int i = 0; i < 4; i++) bv[i] = *(const uint4*)(Bk + (size_t)brow[i] * K);
    };
    auto SWRITE = [&]() {
        #pragma unroll
        for (int i = 0; i < 4; i++) {
            int base = (sr + i * 32) * LDA + sc;
            *(uint2*)&Al[base]     = make_uint2(av[i].x, av[i].y);
            *(uint2*)&Al[base + 4] = make_uint2(av[i].z, av[i].w);
            *(uint2*)&Bl[base]     = make_uint2(bv[i].x, bv[i].y);
            *(uint2*)&Bl[base + 4] = make_uint2(bv[i].z, bv[i].w);
        }
    };

    f32x4 acc[4][4];
    #pragma unroll
    for (int mt = 0; mt < 4; mt++)
        #pragma unroll
        for (int nt = 0; nt < 4; nt++) acc[mt][nt] = (f32x4){0.f, 0.f, 0.f, 0.f};

    union FR { bf16x8 v; uint u[4]; };

    SLOAD(0);
    SWRITE();
    __syncthreads();

    for (int kt = 0; kt < NKT; kt++) {
        if (kt + 1 < NKT) SLOAD(kt + 1);   // in flight under the MFMA phase
        #pragma unroll
        for (int kb = 0; kb < 2; kb++) {
            FR a[4], b[4];
            #pragma unroll
            for (int mt = 0; mt < 4; mt++) {
                const ushort* p = &Al[(wr + mt * 16 + l15) * LDA + kb * 32 + kg * 4];
                uint2 lo = *(const uint2*)p;
                uint2 hi = *(const uint2*)(p + 16);
                a[mt].u[0] = lo.x; a[mt].u[1] = lo.y; a[mt].u[2] = hi.x; a[mt].u[3] = hi.y;
            }
            #pragma unroll
            for (int nt = 0; nt < 4; nt++) {
                const ushort* p = &Bl[(wc + nt * 16 + l15) * LDA + kb * 32 + kg * 4];
                uint2 lo = *(const uint2*)p;
                uint2 hi = *(const uint2*)(p + 16);
                b[nt].u[0] = lo.x; b[nt].u[1] = lo.y; b[nt].u[2] = hi.x; b[nt].u[3] = hi.y;
            }
            #pragma unroll
            for (int nt = 0; nt < 4; nt++)
                #pragma unroll
                for (int mt = 0; mt < 4; mt++)
                    acc[mt][nt] = __builtin_amdgcn_mfma_f32_16x16x32_bf16(a[mt].v, b[nt].v, acc[mt][nt], 0, 0, 0);
        }
        if (kt + 1 < NKT) {
            __syncthreads();   // all waves done reading Al/Bl
            SWRITE();
            __syncthreads();   // new tile visible
        }
    }

    // epilogue: C/D layout col=lane&15, row=(lane>>4)*4+i
    #pragma unroll
    for (int nt = 0; nt < 4; nt++) {
        int col = n0 + wc + nt * 16 + l15;
        float bvv = (MODE >= 1) ? bias[col] : 0.f;
        #pragma unroll
        for (int mt = 0; mt < 4; mt++) {
            #pragma unroll
            for (int i = 0; i < 4; i++) {
                int row = m0 + wr + mt * 16 + kg * 4 + i;
                if (row < M) {
                    float v = acc[mt][nt][i] + bvv;
                    if (MODE == 2) {
                        v += haccp[(size_t)row * DL + col];
                        v = sigmoidf_(v);
                    }
                    C[(size_t)row * NCOL + col] = f2bf(v);
                }
            }
        }
    }
}

// ---------------- chunked flat CSR gather-accumulate ----------------
// Pass P covers relations {2P, 2P+1}: CSR buckets (n,2P),(n,2P+1) are
// contiguous. half-wave per node, 8 cols (16B) per lane, 4-deep unroll.
// P==0 initializes hacc, else accumulates.
template<int P>
__global__ __launch_bounds__(256) void gather_acc(
    const ushort* __restrict__ hrc,  // [N][512] bf16
    const int* __restrict__ eidx,
    const float* __restrict__ ew,
    const int* __restrict__ offs,    // [N*8]
    float* __restrict__ hacc)        // [N][256] fp32
{
    int t = threadIdx.x;
    int slot = t >> 5;               // 0..7
    int l = t & 31;
    int n = blockIdx.x * 8 + slot;
    if (n >= NN) return;
    int e    = offs[n * 8 + 2 * P];
    int endE = (P == 3) ? ((n == NN - 1) ? EE : offs[n * 8 + 8])
                        : offs[n * 8 + 2 * P + 2];
    int c = l * 8;

    float acc[8];
    if (P == 0) {
        #pragma unroll
        for (int q = 0; q < 8; q++) acc[q] = 0.f;
    } else {
        float4 a0 = *(const float4*)&hacc[(size_t)n * DL + c];
        float4 a1 = *(const float4*)&hacc[(size_t)n * DL + c + 4];
        acc[0] = a0.x; acc[1] = a0.y; acc[2] = a0.z; acc[3] = a0.w;
        acc[4] = a1.x; acc[5] = a1.y; acc[6] = a1.z; acc[7] = a1.w;
    }

    for (; e + 4 <= endE; e += 4) {
        int i0 = eidx[e], i1 = eidx[e + 1], i2 = eidx[e + 2], i3 = eidx[e + 3];
        float w0 = ew[e], w1 = ew[e + 1], w2 = ew[e + 2], w3 = ew[e + 3];
        uint4 v0 = *(const uint4*)&hrc[(size_t)i0 + c];
        uint4 v1 = *(const uint4*)&hrc[(size_t)i1 + c];
        uint4 v2 = *(const uint4*)&hrc[(size_t)i2 + c];
        uint4 v3 = *(const uint4*)&hrc[(size_t)i3 + c];
        accw8(acc, v0, w0); accw8(acc, v1, w1);
        accw8(acc, v2, w2); accw8(acc, v3, w3);
    }
    for (; e < endE; e++) {
        uint4 v = *(const uint4*)&hrc[(size_t)eidx[e] + c];
        accw8(acc, v, ew[e]);
    }

    *(float4*)&hacc[(size_t)n * DL + c]     = make_float4(acc[0], acc[1], acc[2], acc[3]);
    *(float4*)&hacc[(size_t)n * DL + c + 4] = make_float4(acc[4], acc[5], acc[6], acc[7]);
}

// ---------------- BatchNorm stats over hg1 columns ----------------
__global__ __launch_bounds__(256) void bnstats_kernel(
    const ushort* __restrict__ hg1, float* __restrict__ colsum, float* __restrict__ colsum2)
{
    int col = threadIdx.x;            // 256 columns
    int rpb = (NN + 127) / 128;       // 391 rows per block, 128 blocks
    int row0 = blockIdx.x * rpb;
    int rend = min(row0 + rpb, NN);
    float s = 0.f, s2 = 0.f;
    for (int r = row0; r < rend; r++) {
        float v = bf2f(hg1[(size_t)r * DL + col]);
        s += v; s2 += v * v;
    }
    atomicAdd(&colsum[col], s);
    atomicAdd(&colsum2[col], s2);
}

__global__ void bnfinal_kernel(
    const float* __restrict__ colsum, const float* __restrict__ colsum2,
    const float* __restrict__ gamma, float* __restrict__ mu, float* __restrict__ aa)
{
    int c = threadIdx.x;
    if (c < DL) {
        float m = colsum[c] / (float)NN;
        float var = colsum2[c] / (float)NN - m * m;
        mu[c] = m;
        aa[c] = rsqrtf(var + 1e-5f) * gamma[c];
    }
}

// ---------------- gate = relu(BN(hg1)) @ Wg2 + bg2 ; segment max ----------------
// Contiguous node runs per wave; one atomic per graph-run boundary.
__global__ __launch_bounds__(256) void gate_kernel(
    const ushort* __restrict__ hg1, const float* __restrict__ mu,
    const float* __restrict__ aa, const float* __restrict__ beta,
    const float* __restrict__ Wg2, const float* __restrict__ bg2,
    const int* __restrict__ batch,
    float* __restrict__ gate, unsigned* __restrict__ gmaxu)
{
    int lane = threadIdx.x & 63;
    int wid = (blockIdx.x * blockDim.x + threadIdx.x) >> 6;
    int nw = (gridDim.x * blockDim.x) >> 6;
    int per = (NN + nw - 1) / nw;
    int n0 = wid * per;
    if (n0 >= NN) return;
    int n1 = min(n0 + per, NN);
    float bg2v = bg2[0];
    float lmax = -3.4e38f;
    int curb = batch[n0];
    for (int n = n0; n < n1; n++) {
        float s = 0.f;
        #pragma unroll
        for (int c = 0; c < 4; c++) {
            int d = c * 64 + lane;
            float v = bf2f(hg1[(size_t)n * DL + d]);
            float xn = (v - mu[d]) * aa[d] + beta[d];
            xn = fmaxf(xn, 0.f);
            s += xn * Wg2[d];
        }
        #pragma unroll
        for (int o = 32; o > 0; o >>= 1) s += __shfl_down(s, o, 64);
        if (lane == 0) {
            float g = s + bg2v;
            gate[n] = g;
            int b = batch[n];
            if (b != curb) {
                atomicMax(&gmaxu[curb], fenc(lmax));
                lmax = -3.4e38f; curb = b;
            }
            lmax = fmaxf(lmax, g);
        }
    }
    if (lane == 0) atomicMax(&gmaxu[curb], fenc(lmax));
}

// ---------------- exp + per-graph denom (contiguous 4-node runs/thread) ----
__global__ __launch_bounds__(256) void expdenom_kernel(
    const float* __restrict__ gate, const int* __restrict__ batch,
    const unsigned* __restrict__ gmaxu, float* __restrict__ ealpha, float* __restrict__ denom)
{
    int tid = blockIdx.x * 256 + threadIdx.x;
    int i0 = tid * 4;
    if (i0 >= NN) return;
    int i1 = min(i0 + 4, NN);
    int curb = batch[i0];
    float m = fdec(gmaxu[curb]);
    float lsum = 0.f;
    for (int i = i0; i < i1; i++) {
        int b = batch[i];
        if (b != curb) {
            atomicAdd(&denom[curb], lsum);
            lsum = 0.f; curb = b; m = fdec(gmaxu[b]);
        }
        float ex = expf(gate[i] - m);
        ealpha[i] = ex;
        lsum += ex;
    }
    atomicAdd(&denom[curb], lsum);
}

// ---------------- pooled[g] = sum (e/denom) * h2[n] (batch sorted) ----------------
__global__ __launch_bounds__(256) void pool_kernel(
    const ushort* __restrict__ h2, const float* __restrict__ ealpha,
    const float* __restrict__ denom, const int* __restrict__ batch,
    float* __restrict__ pooled)
{
    int col = threadIdx.x;            // 256
    int row0 = blockIdx.x * 128;
    if (row0 >= NN) return;
    int rend = min(row0 + 128, NN);
    float accv = 0.f;
    int curg = batch[row0];
    for (int r = row0; r < rend; r++) {
        int g = batch[r];
        if (g != curg) {
            atomicAdd(&pooled[curg * DL + col], accv / denom[curg]);
            accv = 0.f; curg = g;
        }
        accv += ealpha[r] * bf2f(h2[(size_t)r * DL + col]);
    }
    atomicAdd(&pooled[curg * DL + col], accv / denom[curg]);
}

__global__ void head_kernel(
    const float* __restrict__ pooled, const float* __restrict__ Wgl,
    const float* __restrict__ bgl, float* __restrict__ out)
{
    int g = blockIdx.x;
    int lane = threadIdx.x;           // 64
    float s = 0.f;
    #pragma unroll
    for (int c = 0; c < 4; c++) {
        int d = c * 64 + lane;
        s += pooled[g * DL + d] * Wgl[d];
    }
    #pragma unroll
    for (int o = 32; o > 0; o >>= 1) s += __shfl_down(s, o, 64);
    if (lane == 0) out[g] = sigmoidf_(s + bgl[0]);
}

extern "C" void kernel_launch(void* const* d_in, const int* in_sizes, int n_in,
                              void* d_out, int out_size, void* d_ws, size_t ws_size,
                              hipStream_t stream)
{
    const int* x      = (const int*)d_in[0];
    const int* ei     = (const int*)d_in[1];
    const int* etype  = (const int*)d_in[2];
    const int* batch  = (const int*)d_in[3];
    const float* e0   = (const float*)d_in[4];
    const float* e1   = (const float*)d_in[5];
    const float* e2   = (const float*)d_in[6];
    const float* e3   = (const float*)d_in[7];
    const float* e4   = (const float*)d_in[8];
    const float* e5   = (const float*)d_in[9];
    const float* W1   = (const float*)d_in[10];
    const float* root1= (const float*)d_in[11];
    const float* b1   = (const float*)d_in[12];
    const float* W2   = (const float*)d_in[13];
    const float* root2= (const float*)d_in[14];
    const float* b2   = (const float*)d_in[15];
    const float* Wg1  = (const float*)d_in[16];
    const float* bg1  = (const float*)d_in[17];
    const float* gamma= (const float*)d_in[18];
    const float* beta = (const float*)d_in[19];
    const float* Wg2  = (const float*)d_in[20];
    const float* bg2  = (const float*)d_in[21];
    const float* Wgl  = (const float*)d_in[22];
    const float* bgl  = (const float*)d_in[23];
    float* out = (float*)d_out;

    const int* esrc_in = ei;          // edge_index[0]
    const int* edst_in = ei + EE;     // edge_index[1]

    char* ws = (char*)d_ws;
    size_t off = 0;
    auto alloc = [&](size_t b) -> char* {
        char* p = ws + off;
        off += (b + 255) & ~(size_t)255;
        return p;
    };
    // Peak ws ~181 MB (R1's 188 MB fits; R4's 281 MB did not).
    ushort* hbuf   = (ushort*)alloc((size_t)NN * D0 * 2);    // 38.4 MB: h0, later h2
    ushort* h1     = (ushort*)alloc((size_t)NN * DL * 2);    // 25.6 MB
    float*  hacc   = (float*)alloc((size_t)NN * DL * 4);     // 51.2 MB fp32
    ushort* hrc    = (ushort*)alloc((size_t)NN * CHC * 2);   // 51.2 MB (later hg1)
    size_t zstart = off;                                     // ---- zeroed region ----
    int*      counts  = (int*)alloc((size_t)NN * RR * 4);
    float*    colsum  = (float*)alloc(DL * 4);
    float*    colsum2 = (float*)alloc(DL * 4);
    unsigned* gmaxu   = (unsigned*)alloc(GG * 4);
    float*    denom   = (float*)alloc(GG * 4);
    float*    pooled  = (float*)alloc((size_t)GG * DL * 4);
    size_t zbytes = off - zstart;                            // ---- end zeroed ----
    int*   offs    = (int*)alloc((size_t)NN * RR * 4);
    int*   cursors = (int*)alloc((size_t)NN * RR * 4);
    int*   eidx    = (int*)alloc((size_t)EE * 4);
    float* ew      = (float*)alloc((size_t)EE * 4);
    int*   blkSums = (int*)alloc(512);
    int*   blkOff  = (int*)alloc(512);
    float* mu      = (float*)alloc(DL * 4);
    float* aa      = (float*)alloc(DL * 4);
    float* gate    = (float*)alloc((size_t)NN * 4);
    float* ealpha  = (float*)alloc((size_t)NN * 4);
    ushort* WbT1   = (ushort*)alloc((size_t)9 * DL * D0 * 2);  // 1.77 MB
    ushort* WbT2   = (ushort*)alloc((size_t)9 * DL * DL * 2);  // 1.18 MB
    ushort* WbTg   = (ushort*)alloc((size_t)1 * DL * DL * 2);  // 131 KB

    ushort* h0  = hbuf;
    ushort* h2  = hbuf;   // h0 dead after layer1's final GEMM
    ushort* hg1 = hrc;    // hrc dead after layer2's last gather

    if (ws_size < off) return;   // fail loudly (wrong output) rather than corrupt

    hipMemsetAsync(ws + zstart, 0, zbytes, stream);

    embed_kernel<<<(NN * 48 + 255) / 256, 256, 0, stream>>>(x, e0, e1, e2, e3, e4, e5, h0);
    count_kernel<<<(EE + 255) / 256, 256, 0, stream>>>(edst_in, etype, counts);

    // weight bf16 transposes
    {
        int tot1 = 9 * DL * D0;
        cvtT_kernel<<<(tot1 + 255) / 256, 256, 0, stream>>>(W1, root1, WbT1, RR, D0);
        int tot2 = 9 * DL * DL;
        cvtT_kernel<<<(tot2 + 255) / 256, 256, 0, stream>>>(W2, root2, WbT2, RR, DL);
        int totg = 1 * DL * DL;
        cvtT_kernel<<<(totg + 255) / 256, 256, 0, stream>>>(nullptr, Wg1, WbTg, 0, DL);
    }

    const int M = NN * RR;
    const int NB = (M + SCAN_CHUNK - 1) / SCAN_CHUNK;   // 98
    scanA_kernel<<<NB, 256, 0, stream>>>(counts, M, blkSums);
    scanB_kernel<<<1, 64, 0, stream>>>(blkSums, NB, blkOff);
    scanC_kernel<<<NB, 256, 0, stream>>>(counts, M, blkOff, offs, cursors);
    scatter_kernel<<<(EE + 255) / 256, 256, 0, stream>>>(esrc_in, edst_in, etype, counts, cursors, eidx, ew);

    const int MT = (NN + 127) / 128;   // 391 M-tiles
    const dim3 G2(2, MT), G4(4, MT);
    const int ABLK = (NN + 7) / 8;     // gather blocks

    // ---- layer 1 (IN=384): 4 chunks of 2 relations, then fused root ----
    dense_gemm<D0, 0><<<G4, 256, 0, stream>>>(h0, WbT1 + (size_t)0 * DL * D0, nullptr, nullptr, hrc, NN, CHC);
    gather_acc<0><<<ABLK, 256, 0, stream>>>(hrc, eidx, ew, offs, hacc);
    dense_gemm<D0, 0><<<G4, 256, 0, stream>>>(h0, WbT1 + (size_t)2 * DL * D0, nullptr, nullptr, hrc, NN, CHC);
    gather_acc<1><<<ABLK, 256, 0, stream>>>(hrc, eidx, ew, offs, hacc);
    dense_gemm<D0, 0><<<G4, 256, 0, stream>>>(h0, WbT1 + (size_t)4 * DL * D0, nullptr, nullptr, hrc, NN, CHC);
    gather_acc<2><<<ABLK, 256, 0, stream>>>(hrc, eidx, ew, offs, hacc);
    dense_gemm<D0, 0><<<G4, 256, 0, stream>>>(h0, WbT1 + (size_t)6 * DL * D0, nullptr, nullptr, hrc, NN, CHC);
    gather_acc<3><<<ABLK, 256, 0, stream>>>(hrc, eidx, ew, offs, hacc);
    dense_gemm<D0, 2><<<G2, 256, 0, stream>>>(h0, WbT1 + (size_t)8 * DL * D0, b1, hacc, h1, NN, DL);

    // ---- layer 2 (IN=256) ----
    dense_gemm<DL, 0><<<G4, 256, 0, stream>>>(h1, WbT2 + (size_t)0 * DL * DL, nullptr, nullptr, hrc, NN, CHC);
    gather_acc<0><<<ABLK, 256, 0, stream>>>(hrc, eidx, ew, offs, hacc);
    dense_gemm<DL, 0><<<G4, 256, 0, stream>>>(h1, WbT2 + (size_t)2 * DL * DL, nullptr, nullptr, hrc, NN, CHC);
    gather_acc<1><<<ABLK, 256, 0, stream>>>(hrc, eidx, ew, offs, hacc);
    dense_gemm<DL, 0><<<G4, 256, 0, stream>>>(h1, WbT2 + (size_t)4 * DL * DL, nullptr, nullptr, hrc, NN, CHC);
    gather_acc<2><<<ABLK, 256, 0, stream>>>(hrc, eidx, ew, offs, hacc);
    dense_gemm<DL, 0><<<G4, 256, 0, stream>>>(h1, WbT2 + (size_t)6 * DL * DL, nullptr, nullptr, hrc, NN, CHC);
    gather_acc<3><<<ABLK, 256, 0, stream>>>(hrc, eidx, ew, offs, hacc);
    dense_gemm<DL, 2><<<G2, 256, 0, stream>>>(h1, WbT2 + (size_t)8 * DL * DL, b2, hacc, h2, NN, DL);

    // ---- gate linear (no act; BN follows) ----
    dense_gemm<DL, 1><<<G2, 256, 0, stream>>>(h2, WbTg, bg1, nullptr, hg1, NN, DL);

    bnstats_kernel<<<128, 256, 0, stream>>>(hg1, colsum, colsum2);
    bnfinal_kernel<<<1, 256, 0, stream>>>(colsum, colsum2, gamma, mu, aa);
    gate_kernel<<<512, 256, 0, stream>>>(hg1, mu, aa, beta, Wg2, bg2, batch, gate, gmaxu);
    expdenom_kernel<<<((NN + 3) / 4 + 255) / 256, 256, 0, stream>>>(gate, batch, gmaxu, ealpha, denom);
    pool_kernel<<<(NN + 127) / 128, 256, 0, stream>>>(h2, ealpha, denom, batch, pooled);
    head_kernel<<<GG, 64, 0, stream>>>(pooled, Wgl, bgl, out);
}

// Round 8
// 976.485 us; speedup vs baseline: 2.2130x; 1.0915x over previous
//
#include <hip/hip_runtime.h>
#include <hip/hip_bf16.h>
#include <cstdint>

#define NN 50000
#define EE 800000
#define RR 8
#define GG 128
#define D0 384
#define DL 256
#define CHC 512      // hrc columns: 2 relations * 256

typedef __attribute__((ext_vector_type(8))) short bf16x8;
typedef __attribute__((ext_vector_type(4))) float f32x4;

__device__ __forceinline__ float sigmoidf_(float x) { return 1.0f / (1.0f + expf(-x)); }

__device__ __forceinline__ ushort f2bf(float f) {
    uint u = __float_as_uint(f);
    u += 0x7fffu + ((u >> 16) & 1u);
    return (ushort)(u >> 16);
}
__device__ __forceinline__ uint pack2bf(float lo, float hi) {
    return (uint)f2bf(lo) | ((uint)f2bf(hi) << 16);
}
__device__ __forceinline__ float bf2f(ushort u) {
    return __uint_as_float((uint)u << 16);
}

// acc[0..7] += w * bf16x8(v)
__device__ __forceinline__ void accw8(float* s, uint4 a, float w) {
    s[0] += w * __uint_as_float(a.x << 16);
    s[1] += w * __uint_as_float(a.x & 0xffff0000u);
    s[2] += w * __uint_as_float(a.y << 16);
    s[3] += w * __uint_as_float(a.y & 0xffff0000u);
    s[4] += w * __uint_as_float(a.z << 16);
    s[5] += w * __uint_as_float(a.z & 0xffff0000u);
    s[6] += w * __uint_as_float(a.w << 16);
    s[7] += w * __uint_as_float(a.w & 0xffff0000u);
}

// unpack 8 bf16 to fp32
__device__ __forceinline__ void unp8(float* f, uint4 a) {
    f[0] = __uint_as_float(a.x << 16);
    f[1] = __uint_as_float(a.x & 0xffff0000u);
    f[2] = __uint_as_float(a.y << 16);
    f[3] = __uint_as_float(a.y & 0xffff0000u);
    f[4] = __uint_as_float(a.z << 16);
    f[5] = __uint_as_float(a.z & 0xffff0000u);
    f[6] = __uint_as_float(a.w << 16);
    f[7] = __uint_as_float(a.w & 0xffff0000u);
}

// order-preserving float->uint encoding for atomicMax
__device__ __forceinline__ unsigned fenc(float x) {
    unsigned u = __float_as_uint(x);
    return (u & 0x80000000u) ? ~u : (u | 0x80000000u);
}
__device__ __forceinline__ float fdec(unsigned u) {
    unsigned b = (u & 0x80000000u) ? (u & 0x7fffffffu) : ~u;
    return __uint_as_float(b);
}

// ---------------- embedding concat: h0[n, 0:384] (bf16) ----------------
__global__ __launch_bounds__(256) void embed_kernel(
    const int* __restrict__ x,
    const float* __restrict__ e0, const float* __restrict__ e1,
    const float* __restrict__ e2, const float* __restrict__ e3,
    const float* __restrict__ e4, const float* __restrict__ e5,
    ushort* __restrict__ h0)
{
    int idx = blockIdx.x * 256 + threadIdx.x;   // over NN*48 8-elem chunks
    if (idx >= NN * 48) return;
    int n = idx / 48;
    int q = idx - n * 48;
    int d = q * 8;
    int tbl = d >> 6;
    int w = d & 63;
    int row = x[n * 6 + tbl];
    const float* src;
    switch (tbl) {
        case 0: src = e0; break; case 1: src = e1; break; case 2: src = e2; break;
        case 3: src = e3; break; case 4: src = e4; break; default: src = e5; break;
    }
    float4 f0 = *(const float4*)&src[row * 64 + w];
    float4 f1 = *(const float4*)&src[row * 64 + w + 4];
    uint4 pk;
    pk.x = pack2bf(f0.x, f0.y);
    pk.y = pack2bf(f0.z, f0.w);
    pk.z = pack2bf(f1.x, f1.y);
    pk.w = pack2bf(f1.z, f1.w);
    *(uint4*)&h0[(size_t)n * D0 + d] = pk;
}

// ---------------- weight convert + transpose: WbT[r*256+n][k] = bf16(W[r][k][n]) ----------------
__global__ __launch_bounds__(256) void cvtT_kernel(
    const float* __restrict__ W, const float* __restrict__ root,
    ushort* __restrict__ WbT, int nrel, int IN)
{
    int idx = blockIdx.x * 256 + threadIdx.x;
    int tot = (nrel + 1) * DL * IN;
    if (idx >= tot) return;
    int k = idx % IN;
    int rn = idx / IN;
    int n = rn % DL;
    int r = rn / DL;
    float v = (r < nrel) ? W[((size_t)r * IN + k) * DL + n] : root[(size_t)k * DL + n];
    WbT[idx] = f2bf(v);
}

// ---------------- CSR build ----------------
__global__ __launch_bounds__(256) void count_kernel(
    const int* __restrict__ dst, const int* __restrict__ et, int* __restrict__ counts)
{
    int i = blockIdx.x * 256 + threadIdx.x;
    if (i < EE) atomicAdd(&counts[dst[i] * RR + et[i]], 1);
}

#define SCAN_CHUNK 4096
__global__ __launch_bounds__(256) void scanA_kernel(const int* __restrict__ cnt, int M, int* __restrict__ blkSums)
{
    __shared__ int s[256];
    int b = blockIdx.x, t = threadIdx.x;
    int base = b * SCAN_CHUNK + t * 16;
    int tot = 0;
    #pragma unroll
    for (int i = 0; i < 16; i++) { int idx = base + i; if (idx < M) tot += cnt[idx]; }
    s[t] = tot; __syncthreads();
    for (int off = 128; off > 0; off >>= 1) {
        if (t < off) s[t] += s[t + off];
        __syncthreads();
    }
    if (t == 0) blkSums[b] = s[0];
}

__global__ void scanB_kernel(const int* __restrict__ blkSums, int NB, int* __restrict__ blkOff)
{
    if (threadIdx.x == 0) {
        int run = 0;
        for (int i = 0; i < NB; i++) { blkOff[i] = run; run += blkSums[i]; }
    }
}

__global__ __launch_bounds__(256) void scanC_kernel(
    const int* __restrict__ cnt, int M, const int* __restrict__ blkOff,
    int* __restrict__ offs, int* __restrict__ curs)
{
    __shared__ int s[256];
    int b = blockIdx.x, t = threadIdx.x;
    int base = b * SCAN_CHUNK + t * 16;
    int loc[16];
    int tot = 0;
    #pragma unroll
    for (int i = 0; i < 16; i++) {
        int idx = base + i;
        int v = (idx < M) ? cnt[idx] : 0;
        loc[i] = tot; tot += v;
    }
    s[t] = tot; __syncthreads();
    for (int off = 1; off < 256; off <<= 1) {
        int v = (t >= off) ? s[t - off] : 0;
        __syncthreads();
        s[t] += v;
        __syncthreads();
    }
    int texc = s[t] - tot;           // exclusive prefix of this thread
    int bb = blkOff[b];
    #pragma unroll
    for (int i = 0; i < 16; i++) {
        int idx = base + i;
        if (idx < M) { int o = bb + texc + loc[i]; offs[idx] = o; curs[idx] = o; }
    }
}

// scatter: per-edge gather index into the 2-relation chunk (src*512 + (r&1)*256)
// and weight 1/cnt. CSR order is by (dst, rel) bucket.
__global__ __launch_bounds__(256) void scatter_kernel(
    const int* __restrict__ src, const int* __restrict__ dst, const int* __restrict__ et,
    const int* __restrict__ cnts, int* __restrict__ cursors,
    int* __restrict__ eidx, float* __restrict__ ew)
{
    int i = blockIdx.x * 256 + threadIdx.x;
    if (i < EE) {
        int r = et[i];
        int b = dst[i] * RR + r;
        int pos = atomicAdd(&cursors[b], 1);
        eidx[pos] = src[i] * CHC + (r & 1) * DL;
        ew[pos] = 1.0f / (float)cnts[b];
    }
}

// ---------------- dense bf16 MFMA GEMM, both operands LDS-staged ----------------
// Tile: BM=128 x BN=128 x BK=64, 4 waves, each wave 64x64 (4x4 16x16 frags).
// grid = (N/128, ceil(M/128)); n fastest so same-A blocks co-run (L2 reuse).
// T14 split staging: issue kt+1 global loads before computing kt; LDS-write
// after the read barrier. MODE 0: plain; 1: +bias (gate); 2: +hacc+bias+sigmoid.
template<int K, int MODE>
__global__ __launch_bounds__(256) void dense_gemm(
    const ushort* __restrict__ A,    // [M][K] bf16
    const ushort* __restrict__ Bt,   // [ntiles*128][K] bf16 (rows = C cols)
    const float* __restrict__ bias,  // [NCOL] (MODE>=1)
    const float* __restrict__ haccp, // [M][256] fp32 (MODE==2)
    ushort* __restrict__ C,          // [M][NCOL] bf16
    int M, int NCOL)
{
    constexpr int NKT = K / 64;
    constexpr int LDA = 68;          // 64 + 4 pad elems -> ~4-way banks on frag reads
    __shared__ ushort Al[128 * LDA]; // 17.4 KB
    __shared__ ushort Bl[128 * LDA]; // 17.4 KB

    const int t   = threadIdx.x;
    const int m0  = blockIdx.y * 128;
    const int n0  = blockIdx.x * 128;
    const int lane = t & 63;
    const int wv  = t >> 6;
    const int wr  = (wv >> 1) * 64;  // wave row offset
    const int wc  = (wv & 1) * 64;   // wave col offset
    const int l15 = lane & 15;
    const int kg  = lane >> 4;

    // staging decomposition: thread covers rows sr+32i, elem cols sc..sc+7
    const int sr = t >> 3;
    const int sc = (t & 7) * 8;
    int arow[4], brow[4];
    #pragma unroll
    for (int i = 0; i < 4; i++) {
        int r = sr + i * 32;
        arow[i] = min(m0 + r, M - 1);
        brow[i] = n0 + r;
    }

    uint4 av[4], bv[4];
    auto SLOAD = [&](int kt) {
        const ushort* Ak = A + kt * 64 + sc;
        const ushort* Bk = Bt + kt * 64 + sc;
        #pragma unroll
        for (int i = 0; i < 4; i++) av[i] = *(const uint4*)(Ak + (size_t)arow[i] * K);
        #pragma unroll
        for (int i = 0; i < 4; i++) bv[i] = *(const uint4*)(Bk + (size_t)brow[i] * K);
    };
    auto SWRITE = [&]() {
        #pragma unroll
        for (int i = 0; i < 4; i++) {
            int base = (sr + i * 32) * LDA + sc;
            *(uint2*)&Al[base]     = make_uint2(av[i].x, av[i].y);
            *(uint2*)&Al[base + 4] = make_uint2(av[i].z, av[i].w);
            *(uint2*)&Bl[base]     = make_uint2(bv[i].x, bv[i].y);
            *(uint2*)&Bl[base + 4] = make_uint2(bv[i].z, bv[i].w);
        }
    };

    f32x4 acc[4][4];
    #pragma unroll
    for (int mt = 0; mt < 4; mt++)
        #pragma unroll
        for (int nt = 0; nt < 4; nt++) acc[mt][nt] = (f32x4){0.f, 0.f, 0.f, 0.f};

    union FR { bf16x8 v; uint u[4]; };

    SLOAD(0);
    SWRITE();
    __syncthreads();

    for (int kt = 0; kt < NKT; kt++) {
        if (kt + 1 < NKT) SLOAD(kt + 1);   // in flight under the MFMA phase
        #pragma unroll
        for (int kb = 0; kb < 2; kb++) {
            FR a[4], b[4];
            #pragma unroll
            for (int mt = 0; mt < 4; mt++) {
                const ushort* p = &Al[(wr + mt * 16 + l15) * LDA + kb * 32 + kg * 4];
                uint2 lo = *(const uint2*)p;
                uint2 hi = *(const uint2*)(p + 16);
                a[mt].u[0] = lo.x; a[mt].u[1] = lo.y; a[mt].u[2] = hi.x; a[mt].u[3] = hi.y;
            }
            #pragma unroll
            for (int nt = 0; nt < 4; nt++) {
                const ushort* p = &Bl[(wc + nt * 16 + l15) * LDA + kb * 32 + kg * 4];
                uint2 lo = *(const uint2*)p;
                uint2 hi = *(const uint2*)(p + 16);
                b[nt].u[0] = lo.x; b[nt].u[1] = lo.y; b[nt].u[2] = hi.x; b[nt].u[3] = hi.y;
            }
            #pragma unroll
            for (int nt = 0; nt < 4; nt++)
                #pragma unroll
                for (int mt = 0; mt < 4; mt++)
                    acc[mt][nt] = __builtin_amdgcn_mfma_f32_16x16x32_bf16(a[mt].v, b[nt].v, acc[mt][nt], 0, 0, 0);
        }
        if (kt + 1 < NKT) {
            __syncthreads();   // all waves done reading Al/Bl
            SWRITE();
            __syncthreads();   // new tile visible
        }
    }

    // epilogue: C/D layout col=lane&15, row=(lane>>4)*4+i
    #pragma unroll
    for (int nt = 0; nt < 4; nt++) {
        int col = n0 + wc + nt * 16 + l15;
        float bvv = (MODE >= 1) ? bias[col] : 0.f;
        #pragma unroll
        for (int mt = 0; mt < 4; mt++) {
            #pragma unroll
            for (int i = 0; i < 4; i++) {
                int row = m0 + wr + mt * 16 + kg * 4 + i;
                if (row < M) {
                    float v = acc[mt][nt][i] + bvv;
                    if (MODE == 2) {
                        v += haccp[(size_t)row * DL + col];
                        v = sigmoidf_(v);
                    }
                    C[(size_t)row * NCOL + col] = f2bf(v);
                }
            }
        }
    }
}

// ---------------- chunked flat CSR gather-accumulate ----------------
// Pass P covers relations {2P, 2P+1}: CSR buckets (n,2P),(n,2P+1) are
// contiguous. half-wave per node, 8 cols (16B) per lane; edges always
// processed in 4-wide batches (clamped index + zero weight padding) so
// all loads stay 4-deep in flight. P==0 initializes hacc.
template<int P>
__global__ __launch_bounds__(256) void gather_acc(
    const ushort* __restrict__ hrc,  // [N][512] bf16
    const int* __restrict__ eidx,
    const float* __restrict__ ew,
    const int* __restrict__ offs,    // [N*8]
    float* __restrict__ hacc)        // [N][256] fp32
{
    int t = threadIdx.x;
    int slot = t >> 5;               // 0..7
    int l = t & 31;
    int n = blockIdx.x * 8 + slot;
    if (n >= NN) return;
    int e    = offs[n * 8 + 2 * P];
    int endE = (P == 3) ? ((n == NN - 1) ? EE : offs[n * 8 + 8])
                        : offs[n * 8 + 2 * P + 2];
    int c = l * 8;

    float acc[8];
    if (P == 0) {
        #pragma unroll
        for (int q = 0; q < 8; q++) acc[q] = 0.f;
    } else {
        float4 a0 = *(const float4*)&hacc[(size_t)n * DL + c];
        float4 a1 = *(const float4*)&hacc[(size_t)n * DL + c + 4];
        acc[0] = a0.x; acc[1] = a0.y; acc[2] = a0.z; acc[3] = a0.w;
        acc[4] = a1.x; acc[5] = a1.y; acc[6] = a1.z; acc[7] = a1.w;
    }

    for (; e < endE; e += 4) {
        int e1 = min(e + 1, endE - 1);
        int e2 = min(e + 2, endE - 1);
        int e3 = min(e + 3, endE - 1);
        int i0 = eidx[e], i1 = eidx[e1], i2 = eidx[e2], i3 = eidx[e3];
        float w0 = ew[e];
        float w1 = (e + 1 < endE) ? ew[e1] : 0.f;
        float w2 = (e + 2 < endE) ? ew[e2] : 0.f;
        float w3 = (e + 3 < endE) ? ew[e3] : 0.f;
        uint4 v0 = *(const uint4*)&hrc[(size_t)i0 + c];
        uint4 v1 = *(const uint4*)&hrc[(size_t)i1 + c];
        uint4 v2 = *(const uint4*)&hrc[(size_t)i2 + c];
        uint4 v3 = *(const uint4*)&hrc[(size_t)i3 + c];
        accw8(acc, v0, w0); accw8(acc, v1, w1);
        accw8(acc, v2, w2); accw8(acc, v3, w3);
    }

    *(float4*)&hacc[(size_t)n * DL + c]     = make_float4(acc[0], acc[1], acc[2], acc[3]);
    *(float4*)&hacc[(size_t)n * DL + c + 4] = make_float4(acc[4], acc[5], acc[6], acc[7]);
}

// ---------------- BatchNorm stats over hg1 columns (vectorized) ----------------
// 256 blocks; thread (g,l): rows row0+g step 8, cols l*8..l*8+7 via uint4.
// LDS cross-group reduce -> 2 atomics per column per block.
__global__ __launch_bounds__(256) void bnstats_kernel(
    const ushort* __restrict__ hg1, float* __restrict__ colsum, float* __restrict__ colsum2)
{
    __shared__ float ss[8][256], ss2[8][256];
    int t = threadIdx.x;
    int g = t >> 5, l = t & 31;
    int c = l * 8;
    constexpr int RPB = (NN + 255) / 256;   // 196
    int row0 = blockIdx.x * RPB;
    int rend = min(row0 + RPB, NN);
    float s[8], s2[8];
    #pragma unroll
    for (int q = 0; q < 8; q++) { s[q] = 0.f; s2[q] = 0.f; }
    for (int r = row0 + g; r < rend; r += 8) {
        uint4 v = *(const uint4*)&hg1[(size_t)r * DL + c];
        float f[8]; unp8(f, v);
        #pragma unroll
        for (int q = 0; q < 8; q++) { s[q] += f[q]; s2[q] += f[q] * f[q]; }
    }
    #pragma unroll
    for (int q = 0; q < 8; q++) { ss[g][c + q] = s[q]; ss2[g][c + q] = s2[q]; }
    __syncthreads();
    float ts = 0.f, ts2 = 0.f;
    #pragma unroll
    for (int gg = 0; gg < 8; gg++) { ts += ss[gg][t]; ts2 += ss2[gg][t]; }
    atomicAdd(&colsum[t], ts);
    atomicAdd(&colsum2[t], ts2);
}

__global__ void bnfinal_kernel(
    const float* __restrict__ colsum, const float* __restrict__ colsum2,
    const float* __restrict__ gamma, float* __restrict__ mu, float* __restrict__ aa)
{
    int c = threadIdx.x;
    if (c < DL) {
        float m = colsum[c] / (float)NN;
        float var = colsum2[c] / (float)NN - m * m;
        mu[c] = m;
        aa[c] = rsqrtf(var + 1e-5f) * gamma[c];
    }
}

// ---------------- gate = relu(BN(hg1)) @ Wg2 + bg2 ; segment max ----------------
// Contiguous node runs per wave; one atomic per graph-run boundary.
__global__ __launch_bounds__(256) void gate_kernel(
    const ushort* __restrict__ hg1, const float* __restrict__ mu,
    const float* __restrict__ aa, const float* __restrict__ beta,
    const float* __restrict__ Wg2, const float* __restrict__ bg2,
    const int* __restrict__ batch,
    float* __restrict__ gate, unsigned* __restrict__ gmaxu)
{
    int lane = threadIdx.x & 63;
    int wid = (blockIdx.x * blockDim.x + threadIdx.x) >> 6;
    int nw = (gridDim.x * blockDim.x) >> 6;
    int per = (NN + nw - 1) / nw;
    int n0 = wid * per;
    if (n0 >= NN) return;
    int n1 = min(n0 + per, NN);
    float bg2v = bg2[0];
    float lmax = -3.4e38f;
    int curb = batch[n0];
    for (int n = n0; n < n1; n++) {
        float s = 0.f;
        #pragma unroll
        for (int c = 0; c < 4; c++) {
            int d = c * 64 + lane;
            float v = bf2f(hg1[(size_t)n * DL + d]);
            float xn = (v - mu[d]) * aa[d] + beta[d];
            xn = fmaxf(xn, 0.f);
            s += xn * Wg2[d];
        }
        #pragma unroll
        for (int o = 32; o > 0; o >>= 1) s += __shfl_down(s, o, 64);
        if (lane == 0) {
            float g = s + bg2v;
            gate[n] = g;
            int b = batch[n];
            if (b != curb) {
                atomicMax(&gmaxu[curb], fenc(lmax));
                lmax = -3.4e38f; curb = b;
            }
            lmax = fmaxf(lmax, g);
        }
    }
    if (lane == 0) atomicMax(&gmaxu[curb], fenc(lmax));
}

// ---------------- exp + per-graph denom (contiguous 4-node runs/thread) ----
__global__ __launch_bounds__(256) void expdenom_kernel(
    const float* __restrict__ gate, const int* __restrict__ batch,
    const unsigned* __restrict__ gmaxu, float* __restrict__ ealpha, float* __restrict__ denom)
{
    int tid = blockIdx.x * 256 + threadIdx.x;
    int i0 = tid * 4;
    if (i0 >= NN) return;
    int i1 = min(i0 + 4, NN);
    int curb = batch[i0];
    float m = fdec(gmaxu[curb]);
    float lsum = 0.f;
    for (int i = i0; i < i1; i++) {
        int b = batch[i];
        if (b != curb) {
            atomicAdd(&denom[curb], lsum);
            lsum = 0.f; curb = b; m = fdec(gmaxu[b]);
        }
        float ex = expf(gate[i] - m);
        ealpha[i] = ex;
        lsum += ex;
    }
    atomicAdd(&denom[curb], lsum);
}

// ---------------- pooled[g] = sum (e/denom) * h2[n] (batch sorted, vectorized) ----
// Block covers 128 rows; sub-group g (32 lanes) covers 16 contiguous rows,
// lane handles 8 cols via uint4. Flush 8 atomics per lane per graph-run.
__global__ __launch_bounds__(256) void pool_kernel(
    const ushort* __restrict__ h2, const float* __restrict__ ealpha,
    const float* __restrict__ denom, const int* __restrict__ batch,
    float* __restrict__ pooled)
{
    int t = threadIdx.x;
    int g = t >> 5, l = t & 31;
    int c = l * 8;
    int row0 = blockIdx.x * 128 + g * 16;
    if (row0 >= NN) return;
    int rend = min(row0 + 16, NN);
    float acc[8];
    #pragma unroll
    for (int q = 0; q < 8; q++) acc[q] = 0.f;
    int curg = batch[row0];
    for (int r = row0; r < rend; r++) {
        int gb = batch[r];
        if (gb != curg) {
            float inv = 1.0f / denom[curg];
            #pragma unroll
            for (int q = 0; q < 8; q++) atomicAdd(&pooled[curg * DL + c + q], acc[q] * inv);
            #pragma unroll
            for (int q = 0; q < 8; q++) acc[q] = 0.f;
            curg = gb;
        }
        float w = ealpha[r];
        uint4 v = *(const uint4*)&h2[(size_t)r * DL + c];
        accw8(acc, v, w);
    }
    float inv = 1.0f / denom[curg];
    #pragma unroll
    for (int q = 0; q < 8; q++) atomicAdd(&pooled[curg * DL + c + q], acc[q] * inv);
}

__global__ void head_kernel(
    const float* __restrict__ pooled, const float* __restrict__ Wgl,
    const float* __restrict__ bgl, float* __restrict__ out)
{
    int g = blockIdx.x;
    int lane = threadIdx.x;           // 64
    float s = 0.f;
    #pragma unroll
    for (int c = 0; c < 4; c++) {
        int d = c * 64 + lane;
        s += pooled[g * DL + d] * Wgl[d];
    }
    #pragma unroll
    for (int o = 32; o > 0; o >>= 1) s += __shfl_down(s, o, 64);
    if (lane == 0) out[g] = sigmoidf_(s + bgl[0]);
}

extern "C" void kernel_launch(void* const* d_in, const int* in_sizes, int n_in,
                              void* d_out, int out_size, void* d_ws, size_t ws_size,
                              hipStream_t stream)
{
    const int* x      = (const int*)d_in[0];
    const int* ei     = (const int*)d_in[1];
    const int* etype  = (const int*)d_in[2];
    const int* batch  = (const int*)d_in[3];
    const float* e0   = (const float*)d_in[4];
    const float* e1   = (const float*)d_in[5];
    const float* e2   = (const float*)d_in[6];
    const float* e3   = (const float*)d_in[7];
    const float* e4   = (const float*)d_in[8];
    const float* e5   = (const float*)d_in[9];
    const float* W1   = (const float*)d_in[10];
    const float* root1= (const float*)d_in[11];
    const float* b1   = (const float*)d_in[12];
    const float* W2   = (const float*)d_in[13];
    const float* root2= (const float*)d_in[14];
    const float* b2   = (const float*)d_in[15];
    const float* Wg1  = (const float*)d_in[16];
    const float* bg1  = (const float*)d_in[17];
    const float* gamma= (const float*)d_in[18];
    const float* beta = (const float*)d_in[19];
    const float* Wg2  = (const float*)d_in[20];
    const float* bg2  = (const float*)d_in[21];
    const float* Wgl  = (const float*)d_in[22];
    const float* bgl  = (const float*)d_in[23];
    float* out = (float*)d_out;

    const int* esrc_in = ei;          // edge_index[0]
    const int* edst_in = ei + EE;     // edge_index[1]

    char* ws = (char*)d_ws;
    size_t off = 0;
    auto alloc = [&](size_t b) -> char* {
        char* p = ws + off;
        off += (b + 255) & ~(size_t)255;
        return p;
    };
    // Peak ws ~181 MB (R1's 188 MB fits; R4's 281 MB did not).
    ushort* hbuf   = (ushort*)alloc((size_t)NN * D0 * 2);    // 38.4 MB: h0, later h2
    ushort* h1     = (ushort*)alloc((size_t)NN * DL * 2);    // 25.6 MB
    float*  hacc   = (float*)alloc((size_t)NN * DL * 4);     // 51.2 MB fp32
    ushort* hrc    = (ushort*)alloc((size_t)NN * CHC * 2);   // 51.2 MB (later hg1)
    size_t zstart = off;                                     // ---- zeroed region ----
    int*      counts  = (int*)alloc((size_t)NN * RR * 4);
    float*    colsum  = (float*)alloc(DL * 4);
    float*    colsum2 = (float*)alloc(DL * 4);
    unsigned* gmaxu   = (unsigned*)alloc(GG * 4);
    float*    denom   = (float*)alloc(GG * 4);
    float*    pooled  = (float*)alloc((size_t)GG * DL * 4);
    size_t zbytes = off - zstart;                            // ---- end zeroed ----
    int*   offs    = (int*)alloc((size_t)NN * RR * 4);
    int*   cursors = (int*)alloc((size_t)NN * RR * 4);
    int*   eidx    = (int*)alloc((size_t)EE * 4);
    float* ew      = (float*)alloc((size_t)EE * 4);
    int*   blkSums = (int*)alloc(512);
    int*   blkOff  = (int*)alloc(512);
    float* mu      = (float*)alloc(DL * 4);
    float* aa      = (float*)alloc(DL * 4);
    float* gate    = (float*)alloc((size_t)NN * 4);
    float* ealpha  = (float*)alloc((size_t)NN * 4);
    ushort* WbT1   = (ushort*)alloc((size_t)9 * DL * D0 * 2);  // 1.77 MB
    ushort* WbT2   = (ushort*)alloc((size_t)9 * DL * DL * 2);  // 1.18 MB
    ushort* WbTg   = (ushort*)alloc((size_t)1 * DL * DL * 2);  // 131 KB

    ushort* h0  = hbuf;
    ushort* h2  = hbuf;   // h0 dead after layer1's final GEMM
    ushort* hg1 = hrc;    // hrc dead after layer2's last gather

    if (ws_size < off) return;   // fail loudly (wrong output) rather than corrupt

    hipMemsetAsync(ws + zstart, 0, zbytes, stream);

    embed_kernel<<<(NN * 48 + 255) / 256, 256, 0, stream>>>(x, e0, e1, e2, e3, e4, e5, h0);
    count_kernel<<<(EE + 255) / 256, 256, 0, stream>>>(edst_in, etype, counts);

    // weight bf16 transposes
    {
        int tot1 = 9 * DL * D0;
        cvtT_kernel<<<(tot1 + 255) / 256, 256, 0, stream>>>(W1, root1, WbT1, RR, D0);
        int tot2 = 9 * DL * DL;
        cvtT_kernel<<<(tot2 + 255) / 256, 256, 0, stream>>>(W2, root2, WbT2, RR, DL);
        int totg = 1 * DL * DL;
        cvtT_kernel<<<(totg + 255) / 256, 256, 0, stream>>>(nullptr, Wg1, WbTg, 0, DL);
    }

    const int M = NN * RR;
    const int NB = (M + SCAN_CHUNK - 1) / SCAN_CHUNK;   // 98
    scanA_kernel<<<NB, 256, 0, stream>>>(counts, M, blkSums);
    scanB_kernel<<<1, 64, 0, stream>>>(blkSums, NB, blkOff);
    scanC_kernel<<<NB, 256, 0, stream>>>(counts, M, blkOff, offs, cursors);
    scatter_kernel<<<(EE + 255) / 256, 256, 0, stream>>>(esrc_in, edst_in, etype, counts, cursors, eidx, ew);

    const int MT = (NN + 127) / 128;   // 391 M-tiles
    const dim3 G2(2, MT), G4(4, MT);
    const int ABLK = (NN + 7) / 8;     // gather blocks

    // ---- layer 1 (IN=384): 4 chunks of 2 relations, then fused root ----
    dense_gemm<D0, 0><<<G4, 256, 0, stream>>>(h0, WbT1 + (size_t)0 * DL * D0, nullptr, nullptr, hrc, NN, CHC);
    gather_acc<0><<<ABLK, 256, 0, stream>>>(hrc, eidx, ew, offs, hacc);
    dense_gemm<D0, 0><<<G4, 256, 0, stream>>>(h0, WbT1 + (size_t)2 * DL * D0, nullptr, nullptr, hrc, NN, CHC);
    gather_acc<1><<<ABLK, 256, 0, stream>>>(hrc, eidx, ew, offs, hacc);
    dense_gemm<D0, 0><<<G4, 256, 0, stream>>>(h0, WbT1 + (size_t)4 * DL * D0, nullptr, nullptr, hrc, NN, CHC);
    gather_acc<2><<<ABLK, 256, 0, stream>>>(hrc, eidx, ew, offs, hacc);
    dense_gemm<D0, 0><<<G4, 256, 0, stream>>>(h0, WbT1 + (size_t)6 * DL * D0, nullptr, nullptr, hrc, NN, CHC);
    gather_acc<3><<<ABLK, 256, 0, stream>>>(hrc, eidx, ew, offs, hacc);
    dense_gemm<D0, 2><<<G2, 256, 0, stream>>>(h0, WbT1 + (size_t)8 * DL * D0, b1, hacc, h1, NN, DL);

    // ---- layer 2 (IN=256) ----
    dense_gemm<DL, 0><<<G4, 256, 0, stream>>>(h1, WbT2 + (size_t)0 * DL * DL, nullptr, nullptr, hrc, NN, CHC);
    gather_acc<0><<<ABLK, 256, 0, stream>>>(hrc, eidx, ew, offs, hacc);
    dense_gemm<DL, 0><<<G4, 256, 0, stream>>>(h1, WbT2 + (size_t)2 * DL * DL, nullptr, nullptr, hrc, NN, CHC);
    gather_acc<1><<<ABLK, 256, 0, stream>>>(hrc, eidx, ew, offs, hacc);
    dense_gemm<DL, 0><<<G4, 256, 0, stream>>>(h1, WbT2 + (size_t)4 * DL * DL, nullptr, nullptr, hrc, NN, CHC);
    gather_acc<2><<<ABLK, 256, 0, stream>>>(hrc, eidx, ew, offs, hacc);
    dense_gemm<DL, 0><<<G4, 256, 0, stream>>>(h1, WbT2 + (size_t)6 * DL * DL, nullptr, nullptr, hrc, NN, CHC);
    gather_acc<3><<<ABLK, 256, 0, stream>>>(hrc, eidx, ew, offs, hacc);
    dense_gemm<DL, 2><<<G2, 256, 0, stream>>>(h1, WbT2 + (size_t)8 * DL * DL, b2, hacc, h2, NN, DL);

    // ---- gate linear (no act; BN follows) ----
    dense_gemm<DL, 1><<<G2, 256, 0, stream>>>(h2, WbTg, bg1, nullptr, hg1, NN, DL);

    bnstats_kernel<<<256, 256, 0, stream>>>(hg1, colsum, colsum2);
    bnfinal_kernel<<<1, 256, 0, stream>>>(colsum, colsum2, gamma, mu, aa);
    gate_kernel<<<512, 256, 0, stream>>>(hg1, mu, aa, beta, Wg2, bg2, batch, gate, gmaxu);
    expdenom_kernel<<<((NN + 3) / 4 + 255) / 256, 256, 0, stream>>>(gate, batch, gmaxu, ealpha, denom);
    pool_kernel<<<(NN + 127) / 128, 256, 0, stream>>>(h2, ealpha, denom, batch, pooled);
    head_kernel<<<GG, 64, 0, stream>>>(pooled, Wgl, bgl, out);
}

// Round 9
// 909.324 us; speedup vs baseline: 2.3765x; 1.0739x over previous
//
#include <hip/hip_runtime.h>
#include <hip/hip_bf16.h>
#include <cstdint>

#define NN 50000
#define EE 800000
#define RR 8
#define GG 128
#define D0 384
#define DL 256

typedef __attribute__((ext_vector_type(8))) short bf16x8;
typedef __attribute__((ext_vector_type(4))) float f32x4;

__device__ __forceinline__ float sigmoidf_(float x) { return 1.0f / (1.0f + expf(-x)); }

__device__ __forceinline__ ushort f2bf(float f) {
    uint u = __float_as_uint(f);
    u += 0x7fffu + ((u >> 16) & 1u);
    return (ushort)(u >> 16);
}
__device__ __forceinline__ uint pack2bf(float lo, float hi) {
    return (uint)f2bf(lo) | ((uint)f2bf(hi) << 16);
}
__device__ __forceinline__ float bf2f(ushort u) {
    return __uint_as_float((uint)u << 16);
}

// async global->LDS 16B per lane (dest = wave-uniform base + lane*16)
__device__ __forceinline__ void g2lds16(ushort* lds, const ushort* g) {
    __builtin_amdgcn_global_load_lds(
        (__attribute__((address_space(1))) void*)g,
        (__attribute__((address_space(3))) void*)lds,
        16, 0, 0);
}

// acc[0..7] += w * bf16x8(v)
__device__ __forceinline__ void accw8(float* s, uint4 a, float w) {
    s[0] += w * __uint_as_float(a.x << 16);
    s[1] += w * __uint_as_float(a.x & 0xffff0000u);
    s[2] += w * __uint_as_float(a.y << 16);
    s[3] += w * __uint_as_float(a.y & 0xffff0000u);
    s[4] += w * __uint_as_float(a.z << 16);
    s[5] += w * __uint_as_float(a.z & 0xffff0000u);
    s[6] += w * __uint_as_float(a.w << 16);
    s[7] += w * __uint_as_float(a.w & 0xffff0000u);
}

// unpack 8 bf16 to fp32
__device__ __forceinline__ void unp8(float* f, uint4 a) {
    f[0] = __uint_as_float(a.x << 16);
    f[1] = __uint_as_float(a.x & 0xffff0000u);
    f[2] = __uint_as_float(a.y << 16);
    f[3] = __uint_as_float(a.y & 0xffff0000u);
    f[4] = __uint_as_float(a.z << 16);
    f[5] = __uint_as_float(a.z & 0xffff0000u);
    f[6] = __uint_as_float(a.w << 16);
    f[7] = __uint_as_float(a.w & 0xffff0000u);
}

// order-preserving float->uint encoding for atomicMax
__device__ __forceinline__ unsigned fenc(float x) {
    unsigned u = __float_as_uint(x);
    return (u & 0x80000000u) ? ~u : (u | 0x80000000u);
}
__device__ __forceinline__ float fdec(unsigned u) {
    unsigned b = (u & 0x80000000u) ? (u & 0x7fffffffu) : ~u;
    return __uint_as_float(b);
}

// ---------------- embedding concat: h0[n, 0:384] (bf16) ----------------
__global__ __launch_bounds__(256) void embed_kernel(
    const int* __restrict__ x,
    const float* __restrict__ e0, const float* __restrict__ e1,
    const float* __restrict__ e2, const float* __restrict__ e3,
    const float* __restrict__ e4, const float* __restrict__ e5,
    ushort* __restrict__ h0)
{
    int idx = blockIdx.x * 256 + threadIdx.x;   // over NN*48 8-elem chunks
    if (idx >= NN * 48) return;
    int n = idx / 48;
    int q = idx - n * 48;
    int d = q * 8;
    int tbl = d >> 6;
    int w = d & 63;
    int row = x[n * 6 + tbl];
    const float* src;
    switch (tbl) {
        case 0: src = e0; break; case 1: src = e1; break; case 2: src = e2; break;
        case 3: src = e3; break; case 4: src = e4; break; default: src = e5; break;
    }
    float4 f0 = *(const float4*)&src[row * 64 + w];
    float4 f1 = *(const float4*)&src[row * 64 + w + 4];
    uint4 pk;
    pk.x = pack2bf(f0.x, f0.y);
    pk.y = pack2bf(f0.z, f0.w);
    pk.z = pack2bf(f1.x, f1.y);
    pk.w = pack2bf(f1.z, f1.w);
    *(uint4*)&h0[(size_t)n * D0 + d] = pk;
}

// ---------------- weight convert + transpose: WbT[r*256+n][k] = bf16(W[r][k][n]) ----------------
__global__ __launch_bounds__(256) void cvtT_kernel(
    const float* __restrict__ W, const float* __restrict__ root,
    ushort* __restrict__ WbT, int nrel, int IN)
{
    int idx = blockIdx.x * 256 + threadIdx.x;
    int tot = (nrel + 1) * DL * IN;
    if (idx >= tot) return;
    int k = idx % IN;
    int rn = idx / IN;
    int n = rn % DL;
    int r = rn / DL;
    float v = (r < nrel) ? W[((size_t)r * IN + k) * DL + n] : root[(size_t)k * DL + n];
    WbT[idx] = f2bf(v);
}

// ---------------- CSR build ----------------
__global__ __launch_bounds__(256) void count_kernel(
    const int* __restrict__ dst, const int* __restrict__ et, int* __restrict__ counts)
{
    int i = blockIdx.x * 256 + threadIdx.x;
    if (i < EE) atomicAdd(&counts[dst[i] * RR + et[i]], 1);
}

#define SCAN_CHUNK 4096
__global__ __launch_bounds__(256) void scanA_kernel(const int* __restrict__ cnt, int M, int* __restrict__ blkSums)
{
    __shared__ int s[256];
    int b = blockIdx.x, t = threadIdx.x;
    int base = b * SCAN_CHUNK + t * 16;
    int tot = 0;
    #pragma unroll
    for (int i = 0; i < 16; i++) { int idx = base + i; if (idx < M) tot += cnt[idx]; }
    s[t] = tot; __syncthreads();
    for (int off = 128; off > 0; off >>= 1) {
        if (t < off) s[t] += s[t + off];
        __syncthreads();
    }
    if (t == 0) blkSums[b] = s[0];
}

__global__ void scanB_kernel(const int* __restrict__ blkSums, int NB, int* __restrict__ blkOff)
{
    if (threadIdx.x == 0) {
        int run = 0;
        for (int i = 0; i < NB; i++) { blkOff[i] = run; run += blkSums[i]; }
    }
}

__global__ __launch_bounds__(256) void scanC_kernel(
    const int* __restrict__ cnt, int M, const int* __restrict__ blkOff,
    int* __restrict__ offs, int* __restrict__ curs)
{
    __shared__ int s[256];
    int b = blockIdx.x, t = threadIdx.x;
    int base = b * SCAN_CHUNK + t * 16;
    int loc[16];
    int tot = 0;
    #pragma unroll
    for (int i = 0; i < 16; i++) {
        int idx = base + i;
        int v = (idx < M) ? cnt[idx] : 0;
        loc[i] = tot; tot += v;
    }
    s[t] = tot; __syncthreads();
    for (int off = 1; off < 256; off <<= 1) {
        int v = (t >= off) ? s[t - off] : 0;
        __syncthreads();
        s[t] += v;
        __syncthreads();
    }
    int texc = s[t] - tot;           // exclusive prefix of this thread
    int bb = blkOff[b];
    #pragma unroll
    for (int i = 0; i < 16; i++) {
        int idx = base + i;
        if (idx < M) { int o = bb + texc + loc[i]; offs[idx] = o; curs[idx] = o; }
    }
}

// scatter: per-edge gather index into the npc-relation chunk
// eidx = src*chc + (r & (npc-1))*256 ; weight 1/cnt.
__global__ __launch_bounds__(256) void scatter_kernel(
    const int* __restrict__ src, const int* __restrict__ dst, const int* __restrict__ et,
    const int* __restrict__ cnts, int* __restrict__ cursors,
    int* __restrict__ eidx, float* __restrict__ ew, int chc, int mask)
{
    int i = blockIdx.x * 256 + threadIdx.x;
    if (i < EE) {
        int r = et[i];
        int b = dst[i] * RR + r;
        int pos = atomicAdd(&cursors[b], 1);
        eidx[pos] = src[i] * chc + (r & mask) * DL;
        ew[pos] = 1.0f / (float)cnts[b];
    }
}

// ---------------- dense bf16 MFMA GEMM: global_load_lds + dbuf (m97 structure) ----
// Tile BM=128 x BN=128 x BK=64, 4 waves, wave = 64x64. LDS linear with
// XOR swizzle (T2, both-sides): stored slot = global slot ^ (row&7);
// source col = ((lane&7)^(row&7))*8 so gload_lds's linear dest lands swizzled.
// MODE 0: plain; 1: +bias (gate); 2: +hacc+bias+sigmoid (root finalize).
template<int K, int MODE>
__global__ __launch_bounds__(256) void dense_gemm(
    const ushort* __restrict__ A,    // [M][K] bf16
    const ushort* __restrict__ Bt,   // [NCOL][K] bf16 (rows = C cols)
    const float* __restrict__ bias,  // [NCOL] (MODE>=1)
    const float* __restrict__ haccp, // [M][256] fp32 (MODE==2)
    ushort* __restrict__ C,          // [M][NCOL] bf16
    int M, int NCOL)
{
    constexpr int NKT = K / 64;
    __shared__ ushort Al[2][8192];   // [buf][128 rows x 64 elems] 16 KB each
    __shared__ ushort Bl[2][8192];

    const int t    = threadIdx.x;
    const int m0   = blockIdx.y * 128;
    const int n0   = blockIdx.x * 128;
    const int lane = t & 63;
    const int wv   = t >> 6;
    const int wr   = (wv >> 1) * 64;
    const int wc   = (wv & 1) * 64;
    const int l15  = lane & 15;
    const int kg   = lane >> 4;
    const int sw   = l15 & 7;        // read-side swizzle key (row&7)

    // staging: wave wv covers tile rows [wv*32, wv*32+32); call i covers 8 rows.
    const int lr   = lane >> 3;      // 0..7 row within call ( = row&7 )
    const int cs   = ((lane & 7) ^ lr) * 8;    // swizzled source col (elems)
    int agrow[4], bgrow[4];
    #pragma unroll
    for (int i = 0; i < 4; i++) {
        int r = wv * 32 + i * 8 + lr;
        agrow[i] = min(m0 + r, M - 1);
        bgrow[i] = n0 + r;
    }

    auto STAGE = [&](int kt, int buf) {
        #pragma unroll
        for (int i = 0; i < 4; i++) {
            g2lds16(&Al[buf][wv * 2048 + i * 512], A  + (size_t)agrow[i] * K + kt * 64 + cs);
            g2lds16(&Bl[buf][wv * 2048 + i * 512], Bt + (size_t)bgrow[i] * K + kt * 64 + cs);
        }
    };

    f32x4 acc[4][4];
    #pragma unroll
    for (int mt = 0; mt < 4; mt++)
        #pragma unroll
        for (int nt = 0; nt < 4; nt++) acc[mt][nt] = (f32x4){0.f, 0.f, 0.f, 0.f};

    union FR { bf16x8 v; uint u[4]; };

    STAGE(0, 0);

    for (int kt = 0; kt < NKT; kt++) {
        int cur = kt & 1;
        __syncthreads();                       // vmcnt drain: buf `cur` ready
        if (kt + 1 < NKT) STAGE(kt + 1, cur ^ 1);
        const ushort* Ap = Al[cur];
        const ushort* Bp = Bl[cur];
        #pragma unroll
        for (int kb = 0; kb < 2; kb++) {
            const int e0 = kb * 32 + kg * 4;
            const int o0 = (e0)      ^ (sw * 8);
            const int o1 = (e0 + 16) ^ (sw * 8);
            FR a[4], b[4];
            #pragma unroll
            for (int mt = 0; mt < 4; mt++) {
                int r = (wr + mt * 16 + l15) * 64;
                uint2 lo = *(const uint2*)&Ap[r + o0];
                uint2 hi = *(const uint2*)&Ap[r + o1];
                a[mt].u[0] = lo.x; a[mt].u[1] = lo.y; a[mt].u[2] = hi.x; a[mt].u[3] = hi.y;
            }
            #pragma unroll
            for (int nt = 0; nt < 4; nt++) {
                int r = (wc + nt * 16 + l15) * 64;
                uint2 lo = *(const uint2*)&Bp[r + o0];
                uint2 hi = *(const uint2*)&Bp[r + o1];
                b[nt].u[0] = lo.x; b[nt].u[1] = lo.y; b[nt].u[2] = hi.x; b[nt].u[3] = hi.y;
            }
            #pragma unroll
            for (int nt = 0; nt < 4; nt++)
                #pragma unroll
                for (int mt = 0; mt < 4; mt++)
                    acc[mt][nt] = __builtin_amdgcn_mfma_f32_16x16x32_bf16(a[mt].v, b[nt].v, acc[mt][nt], 0, 0, 0);
        }
    }

    // epilogue: C/D layout col=lane&15, row=(lane>>4)*4+i
    #pragma unroll
    for (int nt = 0; nt < 4; nt++) {
        int col = n0 + wc + nt * 16 + l15;
        float bvv = (MODE >= 1) ? bias[col] : 0.f;
        #pragma unroll
        for (int mt = 0; mt < 4; mt++) {
            #pragma unroll
            for (int i = 0; i < 4; i++) {
                int row = m0 + wr + mt * 16 + kg * 4 + i;
                if (row < M) {
                    float v = acc[mt][nt][i] + bvv;
                    if (MODE == 2) {
                        v += haccp[(size_t)row * DL + col];
                        v = sigmoidf_(v);
                    }
                    C[(size_t)row * NCOL + col] = f2bf(v);
                }
            }
        }
    }
}

// ---------------- flat CSR gather-accumulate over relations [relStart, relEnd) ----
// Buckets (n, relStart..relEnd) are contiguous in the CSR. Half-wave per node,
// 8 cols (16B) per lane; edges in 4-wide batches (clamped idx + zero weight).
__global__ __launch_bounds__(256) void gather_acc(
    const ushort* __restrict__ hrc,  // [N][chc] bf16
    const int* __restrict__ eidx,
    const float* __restrict__ ew,
    const int* __restrict__ offs,    // [N*8]
    float* __restrict__ hacc,        // [N][256] fp32
    int relStart, int relEnd, int first)
{
    int t = threadIdx.x;
    int slot = t >> 5;               // 0..7
    int l = t & 31;
    int n = blockIdx.x * 8 + slot;
    if (n >= NN) return;
    int e    = offs[n * 8 + relStart];
    int endE = (relEnd == 8 && n == NN - 1) ? EE : offs[n * 8 + relEnd];
    int c = l * 8;

    float acc[8];
    if (first) {
        #pragma unroll
        for (int q = 0; q < 8; q++) acc[q] = 0.f;
    } else {
        float4 a0 = *(const float4*)&hacc[(size_t)n * DL + c];
        float4 a1 = *(const float4*)&hacc[(size_t)n * DL + c + 4];
        acc[0] = a0.x; acc[1] = a0.y; acc[2] = a0.z; acc[3] = a0.w;
        acc[4] = a1.x; acc[5] = a1.y; acc[6] = a1.z; acc[7] = a1.w;
    }

    for (; e < endE; e += 4) {
        int e1 = min(e + 1, endE - 1);
        int e2 = min(e + 2, endE - 1);
        int e3 = min(e + 3, endE - 1);
        int i0 = eidx[e], i1 = eidx[e1], i2 = eidx[e2], i3 = eidx[e3];
        float w0 = ew[e];
        float w1 = (e + 1 < endE) ? ew[e1] : 0.f;
        float w2 = (e + 2 < endE) ? ew[e2] : 0.f;
        float w3 = (e + 3 < endE) ? ew[e3] : 0.f;
        uint4 v0 = *(const uint4*)&hrc[(size_t)i0 + c];
        uint4 v1 = *(const uint4*)&hrc[(size_t)i1 + c];
        uint4 v2 = *(const uint4*)&hrc[(size_t)i2 + c];
        uint4 v3 = *(const uint4*)&hrc[(size_t)i3 + c];
        accw8(acc, v0, w0); accw8(acc, v1, w1);
        accw8(acc, v2, w2); accw8(acc, v3, w3);
    }

    *(float4*)&hacc[(size_t)n * DL + c]     = make_float4(acc[0], acc[1], acc[2], acc[3]);
    *(float4*)&hacc[(size_t)n * DL + c + 4] = make_float4(acc[4], acc[5], acc[6], acc[7]);
}

// ---------------- BatchNorm stats over hg1 columns (vectorized) ----------------
__global__ __launch_bounds__(256) void bnstats_kernel(
    const ushort* __restrict__ hg1, float* __restrict__ colsum, float* __restrict__ colsum2)
{
    __shared__ float ss[8][256], ss2[8][256];
    int t = threadIdx.x;
    int g = t >> 5, l = t & 31;
    int c = l * 8;
    constexpr int RPB = (NN + 255) / 256;   // 196
    int row0 = blockIdx.x * RPB;
    int rend = min(row0 + RPB, NN);
    float s[8], s2[8];
    #pragma unroll
    for (int q = 0; q < 8; q++) { s[q] = 0.f; s2[q] = 0.f; }
    for (int r = row0 + g; r < rend; r += 8) {
        uint4 v = *(const uint4*)&hg1[(size_t)r * DL + c];
        float f[8]; unp8(f, v);
        #pragma unroll
        for (int q = 0; q < 8; q++) { s[q] += f[q]; s2[q] += f[q] * f[q]; }
    }
    #pragma unroll
    for (int q = 0; q < 8; q++) { ss[g][c + q] = s[q]; ss2[g][c + q] = s2[q]; }
    __syncthreads();
    float ts = 0.f, ts2 = 0.f;
    #pragma unroll
    for (int gg = 0; gg < 8; gg++) { ts += ss[gg][t]; ts2 += ss2[gg][t]; }
    atomicAdd(&colsum[t], ts);
    atomicAdd(&colsum2[t], ts2);
}

__global__ void bnfinal_kernel(
    const float* __restrict__ colsum, const float* __restrict__ colsum2,
    const float* __restrict__ gamma, float* __restrict__ mu, float* __restrict__ aa)
{
    int c = threadIdx.x;
    if (c < DL) {
        float m = colsum[c] / (float)NN;
        float var = colsum2[c] / (float)NN - m * m;
        mu[c] = m;
        aa[c] = rsqrtf(var + 1e-5f) * gamma[c];
    }
}

// ---------------- gate = relu(BN(hg1)) @ Wg2 + bg2 ; segment max ----------------
__global__ __launch_bounds__(256) void gate_kernel(
    const ushort* __restrict__ hg1, const float* __restrict__ mu,
    const float* __restrict__ aa, const float* __restrict__ beta,
    const float* __restrict__ Wg2, const float* __restrict__ bg2,
    const int* __restrict__ batch,
    float* __restrict__ gate, unsigned* __restrict__ gmaxu)
{
    int lane = threadIdx.x & 63;
    int wid = (blockIdx.x * blockDim.x + threadIdx.x) >> 6;
    int nw = (gridDim.x * blockDim.x) >> 6;
    int per = (NN + nw - 1) / nw;
    int n0 = wid * per;
    if (n0 >= NN) return;
    int n1 = min(n0 + per, NN);
    float bg2v = bg2[0];
    float lmax = -3.4e38f;
    int curb = batch[n0];
    for (int n = n0; n < n1; n++) {
        float s = 0.f;
        #pragma unroll
        for (int c = 0; c < 4; c++) {
            int d = c * 64 + lane;
            float v = bf2f(hg1[(size_t)n * DL + d]);
            float xn = (v - mu[d]) * aa[d] + beta[d];
            xn = fmaxf(xn, 0.f);
            s += xn * Wg2[d];
        }
        #pragma unroll
        for (int o = 32; o > 0; o >>= 1) s += __shfl_down(s, o, 64);
        if (lane == 0) {
            float g = s + bg2v;
            gate[n] = g;
            int b = batch[n];
            if (b != curb) {
                atomicMax(&gmaxu[curb], fenc(lmax));
                lmax = -3.4e38f; curb = b;
            }
            lmax = fmaxf(lmax, g);
        }
    }
    if (lane == 0) atomicMax(&gmaxu[curb], fenc(lmax));
}

// ---------------- exp + per-graph denom (contiguous 4-node runs/thread) ----
__global__ __launch_bounds__(256) void expdenom_kernel(
    const float* __restrict__ gate, const int* __restrict__ batch,
    const unsigned* __restrict__ gmaxu, float* __restrict__ ealpha, float* __restrict__ denom)
{
    int tid = blockIdx.x * 256 + threadIdx.x;
    int i0 = tid * 4;
    if (i0 >= NN) return;
    int i1 = min(i0 + 4, NN);
    int curb = batch[i0];
    float m = fdec(gmaxu[curb]);
    float lsum = 0.f;
    for (int i = i0; i < i1; i++) {
        int b = batch[i];
        if (b != curb) {
            atomicAdd(&denom[curb], lsum);
            lsum = 0.f; curb = b; m = fdec(gmaxu[b]);
        }
        float ex = expf(gate[i] - m);
        ealpha[i] = ex;
        lsum += ex;
    }
    atomicAdd(&denom[curb], lsum);
}

// ---------------- pooled[g] = sum (e/denom) * h2[n] (batch sorted, vectorized) ----
__global__ __launch_bounds__(256) void pool_kernel(
    const ushort* __restrict__ h2, const float* __restrict__ ealpha,
    const float* __restrict__ denom, const int* __restrict__ batch,
    float* __restrict__ pooled)
{
    int t = threadIdx.x;
    int g = t >> 5, l = t & 31;
    int c = l * 8;
    int row0 = blockIdx.x * 128 + g * 16;
    if (row0 >= NN) return;
    int rend = min(row0 + 16, NN);
    float acc[8];
    #pragma unroll
    for (int q = 0; q < 8; q++) acc[q] = 0.f;
    int curg = batch[row0];
    for (int r = row0; r < rend; r++) {
        int gb = batch[r];
        if (gb != curg) {
            float inv = 1.0f / denom[curg];
            #pragma unroll
            for (int q = 0; q < 8; q++) atomicAdd(&pooled[curg * DL + c + q], acc[q] * inv);
            #pragma unroll
            for (int q = 0; q < 8; q++) acc[q] = 0.f;
            curg = gb;
        }
        float w = ealpha[r];
        uint4 v = *(const uint4*)&h2[(size_t)r * DL + c];
        accw8(acc, v, w);
    }
    float inv = 1.0f / denom[curg];
    #pragma unroll
    for (int q = 0; q < 8; q++) atomicAdd(&pooled[curg * DL + c + q], acc[q] * inv);
}

__global__ void head_kernel(
    const float* __restrict__ pooled, const float* __restrict__ Wgl,
    const float* __restrict__ bgl, float* __restrict__ out)
{
    int g = blockIdx.x;
    int lane = threadIdx.x;           // 64
    float s = 0.f;
    #pragma unroll
    for (int c = 0; c < 4; c++) {
        int d = c * 64 + lane;
        s += pooled[g * DL + d] * Wgl[d];
    }
    #pragma unroll
    for (int o = 32; o > 0; o >>= 1) s += __shfl_down(s, o, 64);
    if (lane == 0) out[g] = sigmoidf_(s + bgl[0]);
}

extern "C" void kernel_launch(void* const* d_in, const int* in_sizes, int n_in,
                              void* d_out, int out_size, void* d_ws, size_t ws_size,
                              hipStream_t stream)
{
    const int* x      = (const int*)d_in[0];
    const int* ei     = (const int*)d_in[1];
    const int* etype  = (const int*)d_in[2];
    const int* batch  = (const int*)d_in[3];
    const float* e0   = (const float*)d_in[4];
    const float* e1   = (const float*)d_in[5];
    const float* e2   = (const float*)d_in[6];
    const float* e3   = (const float*)d_in[7];
    const float* e4   = (const float*)d_in[8];
    const float* e5   = (const float*)d_in[9];
    const float* W1   = (const float*)d_in[10];
    const float* root1= (const float*)d_in[11];
    const float* b1   = (const float*)d_in[12];
    const float* W2   = (const float*)d_in[13];
    const float* root2= (const float*)d_in[14];
    const float* b2   = (const float*)d_in[15];
    const float* Wg1  = (const float*)d_in[16];
    const float* bg1  = (const float*)d_in[17];
    const float* gamma= (const float*)d_in[18];
    const float* beta = (const float*)d_in[19];
    const float* Wg2  = (const float*)d_in[20];
    const float* bg2  = (const float*)d_in[21];
    const float* Wgl  = (const float*)d_in[22];
    const float* bgl  = (const float*)d_in[23];
    float* out = (float*)d_out;

    const int* esrc_in = ei;          // edge_index[0]
    const int* edst_in = ei + EE;     // edge_index[1]

    char* ws = (char*)d_ws;
    size_t off = 0;
    auto alloc = [&](size_t b) -> char* {
        char* p = ws + off;
        off += (b + 255) & ~(size_t)255;
        return p;
    };
    ushort* hbuf   = (ushort*)alloc((size_t)NN * D0 * 2);    // 38.4 MB: h0, later h2
    ushort* h1     = (ushort*)alloc((size_t)NN * DL * 2);    // 25.6 MB
    float*  hacc   = (float*)alloc((size_t)NN * DL * 4);     // 51.2 MB fp32
    size_t zstart = off;                                     // ---- zeroed region ----
    int*      counts  = (int*)alloc((size_t)NN * RR * 4);
    float*    colsum  = (float*)alloc(DL * 4);
    float*    colsum2 = (float*)alloc(DL * 4);
    unsigned* gmaxu   = (unsigned*)alloc(GG * 4);
    float*    denom   = (float*)alloc(GG * 4);
    float*    pooled  = (float*)alloc((size_t)GG * DL * 4);
    size_t zbytes = off - zstart;                            // ---- end zeroed ----
    int*   offs    = (int*)alloc((size_t)NN * RR * 4);
    int*   cursors = (int*)alloc((size_t)NN * RR * 4);
    int*   eidx    = (int*)alloc((size_t)EE * 4);
    float* ew      = (float*)alloc((size_t)EE * 4);
    int*   blkSums = (int*)alloc(512);
    int*   blkOff  = (int*)alloc(512);
    float* mu      = (float*)alloc(DL * 4);
    float* aa      = (float*)alloc(DL * 4);
    float* gate    = (float*)alloc((size_t)NN * 4);
    float* ealpha  = (float*)alloc((size_t)NN * 4);
    ushort* WbT1   = (ushort*)alloc((size_t)9 * DL * D0 * 2);  // 1.77 MB
    ushort* WbT2   = (ushort*)alloc((size_t)9 * DL * DL * 2);  // 1.18 MB
    ushort* WbTg   = (ushort*)alloc((size_t)1 * DL * DL * 2);  // 131 KB

    // hrc LAST: pick 4-relation chunks (102.4 MB) if workspace allows, else 2.
    int npc;
    ushort* hrc;
    {
        size_t need4 = ((size_t)NN * 4 * DL * 2 + 255) & ~(size_t)255;
        size_t need2 = ((size_t)NN * 2 * DL * 2 + 255) & ~(size_t)255;
        if (off + need4 <= ws_size)      { npc = 4; hrc = (ushort*)alloc((size_t)NN * 4 * DL * 2); }
        else if (off + need2 <= ws_size) { npc = 2; hrc = (ushort*)alloc((size_t)NN * 2 * DL * 2); }
        else return;   // fail loudly (wrong output) rather than corrupt
    }
    const int chc = npc * DL;

    ushort* h0  = hbuf;
    ushort* h2  = hbuf;   // h0 dead after layer1's final GEMM
    ushort* hg1 = hrc;    // hrc dead after layer2's last gather

    hipMemsetAsync(ws + zstart, 0, zbytes, stream);

    embed_kernel<<<(NN * 48 + 255) / 256, 256, 0, stream>>>(x, e0, e1, e2, e3, e4, e5, h0);
    count_kernel<<<(EE + 255) / 256, 256, 0, stream>>>(edst_in, etype, counts);

    // weight bf16 transposes
    {
        int tot1 = 9 * DL * D0;
        cvtT_kernel<<<(tot1 + 255) / 256, 256, 0, stream>>>(W1, root1, WbT1, RR, D0);
        int tot2 = 9 * DL * DL;
        cvtT_kernel<<<(tot2 + 255) / 256, 256, 0, stream>>>(W2, root2, WbT2, RR, DL);
        int totg = 1 * DL * DL;
        cvtT_kernel<<<(totg + 255) / 256, 256, 0, stream>>>(nullptr, Wg1, WbTg, 0, DL);
    }

    const int M = NN * RR;
    const int NB = (M + SCAN_CHUNK - 1) / SCAN_CHUNK;   // 98
    scanA_kernel<<<NB, 256, 0, stream>>>(counts, M, blkSums);
    scanB_kernel<<<1, 64, 0, stream>>>(blkSums, NB, blkOff);
    scanC_kernel<<<NB, 256, 0, stream>>>(counts, M, blkOff, offs, cursors);
    scatter_kernel<<<(EE + 255) / 256, 256, 0, stream>>>(esrc_in, edst_in, etype, counts, cursors,
                                                          eidx, ew, chc, npc - 1);

    const int MT = (NN + 127) / 128;   // 391 M-tiles
    const dim3 GC(npc * 2, MT), G2(2, MT);
    const int ABLK = (NN + 7) / 8;

    // ---- layer 1 (IN=384): 8/npc chunks, then fused root+aggregate finalize ----
    for (int c0 = 0; c0 < RR; c0 += npc) {
        dense_gemm<D0, 0><<<GC, 256, 0, stream>>>(h0, WbT1 + (size_t)c0 * DL * D0, nullptr, nullptr, hrc, NN, chc);
        gather_acc<<<ABLK, 256, 0, stream>>>(hrc, eidx, ew, offs, hacc, c0, c0 + npc, c0 == 0);
    }
    dense_gemm<D0, 2><<<G2, 256, 0, stream>>>(h0, WbT1 + (size_t)8 * DL * D0, b1, hacc, h1, NN, DL);

    // ---- layer 2 (IN=256) ----
    for (int c0 = 0; c0 < RR; c0 += npc) {
        dense_gemm<DL, 0><<<GC, 256, 0, stream>>>(h1, WbT2 + (size_t)c0 * DL * DL, nullptr, nullptr, hrc, NN, chc);
        gather_acc<<<ABLK, 256, 0, stream>>>(hrc, eidx, ew, offs, hacc, c0, c0 + npc, c0 == 0);
    }
    dense_gemm<DL, 2><<<G2, 256, 0, stream>>>(h1, WbT2 + (size_t)8 * DL * DL, b2, hacc, h2, NN, DL);

    // ---- gate linear (no act; BN follows) ----
    dense_gemm<DL, 1><<<G2, 256, 0, stream>>>(h2, WbTg, bg1, nullptr, hg1, NN, DL);

    bnstats_kernel<<<256, 256, 0, stream>>>(hg1, colsum, colsum2);
    bnfinal_kernel<<<1, 256, 0, stream>>>(colsum, colsum2, gamma, mu, aa);
    gate_kernel<<<512, 256, 0, stream>>>(hg1, mu, aa, beta, Wg2, bg2, batch, gate, gmaxu);
    expdenom_kernel<<<((NN + 3) / 4 + 255) / 256, 256, 0, stream>>>(gate, batch, gmaxu, ealpha, denom);
    pool_kernel<<<(NN + 127) / 128, 256, 0, stream>>>(h2, ealpha, denom, batch, pooled);
    head_kernel<<<GG, 64, 0, stream>>>(pooled, Wgl, bgl, out);
}

// Round 10
// 851.211 us; speedup vs baseline: 2.5387x; 1.0683x over previous
//
#include <hip/hip_runtime.h>
#include <hip/hip_bf16.h>
#include <cstdint>

#define NN 50000
#define EE 800000
#define RR 8
#define GG 128
#define D0 384
#define DL 256

typedef __attribute__((ext_vector_type(8))) short bf16x8;
typedef __attribute__((ext_vector_type(4))) float f32x4;

__device__ __forceinline__ float sigmoidf_(float x) { return 1.0f / (1.0f + expf(-x)); }

__device__ __forceinline__ ushort f2bf(float f) {
    uint u = __float_as_uint(f);
    u += 0x7fffu + ((u >> 16) & 1u);
    return (ushort)(u >> 16);
}
__device__ __forceinline__ uint pack2bf(float lo, float hi) {
    return (uint)f2bf(lo) | ((uint)f2bf(hi) << 16);
}
__device__ __forceinline__ float bf2f(ushort u) {
    return __uint_as_float((uint)u << 16);
}

// async global->LDS 16B per lane (dest = wave-uniform base + lane*16)
__device__ __forceinline__ void g2lds16(ushort* lds, const ushort* g) {
    __builtin_amdgcn_global_load_lds(
        (__attribute__((address_space(1))) void*)g,
        (__attribute__((address_space(3))) void*)lds,
        16, 0, 0);
}

// acc[0..7] += w * bf16x8(v)
__device__ __forceinline__ void accw8(float* s, uint4 a, float w) {
    s[0] += w * __uint_as_float(a.x << 16);
    s[1] += w * __uint_as_float(a.x & 0xffff0000u);
    s[2] += w * __uint_as_float(a.y << 16);
    s[3] += w * __uint_as_float(a.y & 0xffff0000u);
    s[4] += w * __uint_as_float(a.z << 16);
    s[5] += w * __uint_as_float(a.z & 0xffff0000u);
    s[6] += w * __uint_as_float(a.w << 16);
    s[7] += w * __uint_as_float(a.w & 0xffff0000u);
}

// unpack 8 bf16 to fp32
__device__ __forceinline__ void unp8(float* f, uint4 a) {
    f[0] = __uint_as_float(a.x << 16);
    f[1] = __uint_as_float(a.x & 0xffff0000u);
    f[2] = __uint_as_float(a.y << 16);
    f[3] = __uint_as_float(a.y & 0xffff0000u);
    f[4] = __uint_as_float(a.z << 16);
    f[5] = __uint_as_float(a.z & 0xffff0000u);
    f[6] = __uint_as_float(a.w << 16);
    f[7] = __uint_as_float(a.w & 0xffff0000u);
}

// order-preserving float->uint encoding for atomicMax
__device__ __forceinline__ unsigned fenc(float x) {
    unsigned u = __float_as_uint(x);
    return (u & 0x80000000u) ? ~u : (u | 0x80000000u);
}
__device__ __forceinline__ float fdec(unsigned u) {
    unsigned b = (u & 0x80000000u) ? (u & 0x7fffffffu) : ~u;
    return __uint_as_float(b);
}

// ---------------- embedding concat: h0[n, 0:384] (bf16) ----------------
__global__ __launch_bounds__(256) void embed_kernel(
    const int* __restrict__ x,
    const float* __restrict__ e0, const float* __restrict__ e1,
    const float* __restrict__ e2, const float* __restrict__ e3,
    const float* __restrict__ e4, const float* __restrict__ e5,
    ushort* __restrict__ h0)
{
    int idx = blockIdx.x * 256 + threadIdx.x;   // over NN*48 8-elem chunks
    if (idx >= NN * 48) return;
    int n = idx / 48;
    int q = idx - n * 48;
    int d = q * 8;
    int tbl = d >> 6;
    int w = d & 63;
    int row = x[n * 6 + tbl];
    const float* src;
    switch (tbl) {
        case 0: src = e0; break; case 1: src = e1; break; case 2: src = e2; break;
        case 3: src = e3; break; case 4: src = e4; break; default: src = e5; break;
    }
    float4 f0 = *(const float4*)&src[row * 64 + w];
    float4 f1 = *(const float4*)&src[row * 64 + w + 4];
    uint4 pk;
    pk.x = pack2bf(f0.x, f0.y);
    pk.y = pack2bf(f0.z, f0.w);
    pk.z = pack2bf(f1.x, f1.y);
    pk.w = pack2bf(f1.z, f1.w);
    *(uint4*)&h0[(size_t)n * D0 + d] = pk;
}

// ---------------- weight convert + transpose: WbT[r*256+n][k] = bf16(W[r][k][n]) ----------------
__global__ __launch_bounds__(256) void cvtT_kernel(
    const float* __restrict__ W, const float* __restrict__ root,
    ushort* __restrict__ WbT, int nrel, int IN)
{
    int idx = blockIdx.x * 256 + threadIdx.x;
    int tot = (nrel + 1) * DL * IN;
    if (idx >= tot) return;
    int k = idx % IN;
    int rn = idx / IN;
    int n = rn % DL;
    int r = rn / DL;
    float v = (r < nrel) ? W[((size_t)r * IN + k) * DL + n] : root[(size_t)k * DL + n];
    WbT[idx] = f2bf(v);
}

// ---------------- CSR build ----------------
__global__ __launch_bounds__(256) void count_kernel(
    const int* __restrict__ dst, const int* __restrict__ et, int* __restrict__ counts)
{
    int i = blockIdx.x * 256 + threadIdx.x;
    if (i < EE) atomicAdd(&counts[dst[i] * RR + et[i]], 1);
}

#define SCAN_CHUNK 4096
__global__ __launch_bounds__(256) void scanA_kernel(const int* __restrict__ cnt, int M, int* __restrict__ blkSums)
{
    __shared__ int s[256];
    int b = blockIdx.x, t = threadIdx.x;
    int base = b * SCAN_CHUNK + t * 16;
    int tot = 0;
    #pragma unroll
    for (int i = 0; i < 16; i++) { int idx = base + i; if (idx < M) tot += cnt[idx]; }
    s[t] = tot; __syncthreads();
    for (int off = 128; off > 0; off >>= 1) {
        if (t < off) s[t] += s[t + off];
        __syncthreads();
    }
    if (t == 0) blkSums[b] = s[0];
}

__global__ void scanB_kernel(const int* __restrict__ blkSums, int NB, int* __restrict__ blkOff)
{
    if (threadIdx.x == 0) {
        int run = 0;
        for (int i = 0; i < NB; i++) { blkOff[i] = run; run += blkSums[i]; }
    }
}

__global__ __launch_bounds__(256) void scanC_kernel(
    const int* __restrict__ cnt, int M, const int* __restrict__ blkOff,
    int* __restrict__ offs, int* __restrict__ curs)
{
    __shared__ int s[256];
    int b = blockIdx.x, t = threadIdx.x;
    int base = b * SCAN_CHUNK + t * 16;
    int loc[16];
    int tot = 0;
    #pragma unroll
    for (int i = 0; i < 16; i++) {
        int idx = base + i;
        int v = (idx < M) ? cnt[idx] : 0;
        loc[i] = tot; tot += v;
    }
    s[t] = tot; __syncthreads();
    for (int off = 1; off < 256; off <<= 1) {
        int v = (t >= off) ? s[t - off] : 0;
        __syncthreads();
        s[t] += v;
        __syncthreads();
    }
    int texc = s[t] - tot;           // exclusive prefix of this thread
    int bb = blkOff[b];
    #pragma unroll
    for (int i = 0; i < 16; i++) {
        int idx = base + i;
        if (idx < M) { int o = bb + texc + loc[i]; offs[idx] = o; curs[idx] = o; }
    }
}

// scatter: per-edge gather index into the npc-relation chunk
// eidx = src*chc + (r & (npc-1))*256 ; weight 1/cnt.
__global__ __launch_bounds__(256) void scatter_kernel(
    const int* __restrict__ src, const int* __restrict__ dst, const int* __restrict__ et,
    const int* __restrict__ cnts, int* __restrict__ cursors,
    int* __restrict__ eidx, float* __restrict__ ew, int chc, int mask)
{
    int i = blockIdx.x * 256 + threadIdx.x;
    if (i < EE) {
        int r = et[i];
        int b = dst[i] * RR + r;
        int pos = atomicAdd(&cursors[b], 1);
        eidx[pos] = src[i] * chc + (r & mask) * DL;
        ew[pos] = 1.0f / (float)cnts[b];
    }
}

// ---------------- dense bf16 MFMA GEMM: global_load_lds + dbuf + XCD-chunked remap ----
// Tile BM=128 x BN=128 x BK=64, 4 waves, wave = 64x64. LDS linear with XOR
// swizzle (T2, both-sides). T1: bijective XCD-chunked blockId remap so the
// blocks sharing an A m-tile co-run on ONE XCD (A fetched once per XCD L2).
// MODE 0: plain; 1: +bias (gate); 2: +hacc+bias+sigmoid (root finalize).
template<int K, int MODE>
__global__ __launch_bounds__(256) void dense_gemm(
    const ushort* __restrict__ A,    // [M][K] bf16
    const ushort* __restrict__ Bt,   // [NCOL][K] bf16 (rows = C cols)
    const float* __restrict__ bias,  // [NCOL] (MODE>=1)
    const float* __restrict__ haccp, // [M][256] fp32 (MODE==2)
    ushort* __restrict__ C,          // [M][NCOL] bf16
    int M, int NCOL)
{
    constexpr int NKT = K / 64;
    __shared__ ushort Al[2][8192];   // [buf][128 rows x 64 elems] 16 KB each
    __shared__ ushort Bl[2][8192];

    // ---- T1: bijective XCD-chunked remap (m204) ----
    const int nwg  = gridDim.x * gridDim.y;
    const int flat = blockIdx.y * gridDim.x + blockIdx.x;
    const int q8 = nwg >> 3, r8 = nwg & 7;
    const int xcd = flat & 7, pos = flat >> 3;
    const int vid = ((xcd < r8) ? xcd * (q8 + 1) : r8 * (q8 + 1) + (xcd - r8) * q8) + pos;
    const int m0  = (vid / gridDim.x) * 128;
    const int n0  = (vid % gridDim.x) * 128;

    const int t    = threadIdx.x;
    const int lane = t & 63;
    const int wv   = t >> 6;
    const int wr   = (wv >> 1) * 64;
    const int wc   = (wv & 1) * 64;
    const int l15  = lane & 15;
    const int kg   = lane >> 4;
    const int sw   = l15 & 7;        // read-side swizzle key (row&7)

    // staging: wave wv covers tile rows [wv*32, wv*32+32); call i covers 8 rows.
    const int lr   = lane >> 3;      // 0..7 row within call ( = row&7 )
    const int cs   = ((lane & 7) ^ lr) * 8;    // swizzled source col (elems)
    int agrow[4], bgrow[4];
    #pragma unroll
    for (int i = 0; i < 4; i++) {
        int r = wv * 32 + i * 8 + lr;
        agrow[i] = min(m0 + r, M - 1);
        bgrow[i] = n0 + r;
    }

    auto STAGE = [&](int kt, int buf) {
        #pragma unroll
        for (int i = 0; i < 4; i++) {
            g2lds16(&Al[buf][wv * 2048 + i * 512], A  + (size_t)agrow[i] * K + kt * 64 + cs);
            g2lds16(&Bl[buf][wv * 2048 + i * 512], Bt + (size_t)bgrow[i] * K + kt * 64 + cs);
        }
    };

    f32x4 acc[4][4];
    #pragma unroll
    for (int mt = 0; mt < 4; mt++)
        #pragma unroll
        for (int nt = 0; nt < 4; nt++) acc[mt][nt] = (f32x4){0.f, 0.f, 0.f, 0.f};

    union FR { bf16x8 v; uint u[4]; };

    STAGE(0, 0);

    for (int kt = 0; kt < NKT; kt++) {
        int cur = kt & 1;
        __syncthreads();                       // vmcnt drain: buf `cur` ready
        if (kt + 1 < NKT) STAGE(kt + 1, cur ^ 1);
        const ushort* Ap = Al[cur];
        const ushort* Bp = Bl[cur];
        #pragma unroll
        for (int kb = 0; kb < 2; kb++) {
            const int e0 = kb * 32 + kg * 4;
            const int o0 = (e0)      ^ (sw * 8);
            const int o1 = (e0 + 16) ^ (sw * 8);
            FR a[4], b[4];
            #pragma unroll
            for (int mt = 0; mt < 4; mt++) {
                int r = (wr + mt * 16 + l15) * 64;
                uint2 lo = *(const uint2*)&Ap[r + o0];
                uint2 hi = *(const uint2*)&Ap[r + o1];
                a[mt].u[0] = lo.x; a[mt].u[1] = lo.y; a[mt].u[2] = hi.x; a[mt].u[3] = hi.y;
            }
            #pragma unroll
            for (int nt = 0; nt < 4; nt++) {
                int r = (wc + nt * 16 + l15) * 64;
                uint2 lo = *(const uint2*)&Bp[r + o0];
                uint2 hi = *(const uint2*)&Bp[r + o1];
                b[nt].u[0] = lo.x; b[nt].u[1] = lo.y; b[nt].u[2] = hi.x; b[nt].u[3] = hi.y;
            }
            #pragma unroll
            for (int nt = 0; nt < 4; nt++)
                #pragma unroll
                for (int mt = 0; mt < 4; mt++)
                    acc[mt][nt] = __builtin_amdgcn_mfma_f32_16x16x32_bf16(a[mt].v, b[nt].v, acc[mt][nt], 0, 0, 0);
        }
    }

    // epilogue: C/D layout col=lane&15, row=(lane>>4)*4+i
    #pragma unroll
    for (int nt = 0; nt < 4; nt++) {
        int col = n0 + wc + nt * 16 + l15;
        float bvv = (MODE >= 1) ? bias[col] : 0.f;
        #pragma unroll
        for (int mt = 0; mt < 4; mt++) {
            #pragma unroll
            for (int i = 0; i < 4; i++) {
                int row = m0 + wr + mt * 16 + kg * 4 + i;
                if (row < M) {
                    float v = acc[mt][nt][i] + bvv;
                    if (MODE == 2) {
                        v += haccp[(size_t)row * DL + col];
                        v = sigmoidf_(v);
                    }
                    C[(size_t)row * NCOL + col] = f2bf(v);
                }
            }
        }
    }
}

// ---------------- flat CSR gather-accumulate over relations [relStart, relEnd) ----
__global__ __launch_bounds__(256) void gather_acc(
    const ushort* __restrict__ hrc,  // [N][chc] bf16
    const int* __restrict__ eidx,
    const float* __restrict__ ew,
    const int* __restrict__ offs,    // [N*8]
    float* __restrict__ hacc,        // [N][256] fp32
    int relStart, int relEnd, int first)
{
    int t = threadIdx.x;
    int slot = t >> 5;               // 0..7
    int l = t & 31;
    int n = blockIdx.x * 8 + slot;
    if (n >= NN) return;
    int e    = offs[n * 8 + relStart];
    int endE = (relEnd == 8 && n == NN - 1) ? EE : offs[n * 8 + relEnd];
    int c = l * 8;

    float acc[8];
    if (first) {
        #pragma unroll
        for (int q = 0; q < 8; q++) acc[q] = 0.f;
    } else {
        float4 a0 = *(const float4*)&hacc[(size_t)n * DL + c];
        float4 a1 = *(const float4*)&hacc[(size_t)n * DL + c + 4];
        acc[0] = a0.x; acc[1] = a0.y; acc[2] = a0.z; acc[3] = a0.w;
        acc[4] = a1.x; acc[5] = a1.y; acc[6] = a1.z; acc[7] = a1.w;
    }

    for (; e < endE; e += 4) {
        int e1 = min(e + 1, endE - 1);
        int e2 = min(e + 2, endE - 1);
        int e3 = min(e + 3, endE - 1);
        int i0 = eidx[e], i1 = eidx[e1], i2 = eidx[e2], i3 = eidx[e3];
        float w0 = ew[e];
        float w1 = (e + 1 < endE) ? ew[e1] : 0.f;
        float w2 = (e + 2 < endE) ? ew[e2] : 0.f;
        float w3 = (e + 3 < endE) ? ew[e3] : 0.f;
        uint4 v0 = *(const uint4*)&hrc[(size_t)i0 + c];
        uint4 v1 = *(const uint4*)&hrc[(size_t)i1 + c];
        uint4 v2 = *(const uint4*)&hrc[(size_t)i2 + c];
        uint4 v3 = *(const uint4*)&hrc[(size_t)i3 + c];
        accw8(acc, v0, w0); accw8(acc, v1, w1);
        accw8(acc, v2, w2); accw8(acc, v3, w3);
    }

    *(float4*)&hacc[(size_t)n * DL + c]     = make_float4(acc[0], acc[1], acc[2], acc[3]);
    *(float4*)&hacc[(size_t)n * DL + c + 4] = make_float4(acc[4], acc[5], acc[6], acc[7]);
}

// ---------------- BatchNorm stats over hg1 columns (vectorized) ----------------
__global__ __launch_bounds__(256) void bnstats_kernel(
    const ushort* __restrict__ hg1, float* __restrict__ colsum, float* __restrict__ colsum2)
{
    __shared__ float ss[8][256], ss2[8][256];
    int t = threadIdx.x;
    int g = t >> 5, l = t & 31;
    int c = l * 8;
    constexpr int RPB = (NN + 255) / 256;   // 196
    int row0 = blockIdx.x * RPB;
    int rend = min(row0 + RPB, NN);
    float s[8], s2[8];
    #pragma unroll
    for (int q = 0; q < 8; q++) { s[q] = 0.f; s2[q] = 0.f; }
    for (int r = row0 + g; r < rend; r += 8) {
        uint4 v = *(const uint4*)&hg1[(size_t)r * DL + c];
        float f[8]; unp8(f, v);
        #pragma unroll
        for (int q = 0; q < 8; q++) { s[q] += f[q]; s2[q] += f[q] * f[q]; }
    }
    #pragma unroll
    for (int q = 0; q < 8; q++) { ss[g][c + q] = s[q]; ss2[g][c + q] = s2[q]; }
    __syncthreads();
    float ts = 0.f, ts2 = 0.f;
    #pragma unroll
    for (int gg = 0; gg < 8; gg++) { ts += ss[gg][t]; ts2 += ss2[gg][t]; }
    atomicAdd(&colsum[t], ts);
    atomicAdd(&colsum2[t], ts2);
}

__global__ void bnfinal_kernel(
    const float* __restrict__ colsum, const float* __restrict__ colsum2,
    const float* __restrict__ gamma, float* __restrict__ mu, float* __restrict__ aa)
{
    int c = threadIdx.x;
    if (c < DL) {
        float m = colsum[c] / (float)NN;
        float var = colsum2[c] / (float)NN - m * m;
        mu[c] = m;
        aa[c] = rsqrtf(var + 1e-5f) * gamma[c];
    }
}

// ---------------- gate = relu(BN(hg1)) @ Wg2 + bg2 ; segment max ----------------
__global__ __launch_bounds__(256) void gate_kernel(
    const ushort* __restrict__ hg1, const float* __restrict__ mu,
    const float* __restrict__ aa, const float* __restrict__ beta,
    const float* __restrict__ Wg2, const float* __restrict__ bg2,
    const int* __restrict__ batch,
    float* __restrict__ gate, unsigned* __restrict__ gmaxu)
{
    int lane = threadIdx.x & 63;
    int wid = (blockIdx.x * blockDim.x + threadIdx.x) >> 6;
    int nw = (gridDim.x * blockDim.x) >> 6;
    int per = (NN + nw - 1) / nw;
    int n0 = wid * per;
    if (n0 >= NN) return;
    int n1 = min(n0 + per, NN);
    float bg2v = bg2[0];
    float lmax = -3.4e38f;
    int curb = batch[n0];
    for (int n = n0; n < n1; n++) {
        float s = 0.f;
        #pragma unroll
        for (int c = 0; c < 4; c++) {
            int d = c * 64 + lane;
            float v = bf2f(hg1[(size_t)n * DL + d]);
            float xn = (v - mu[d]) * aa[d] + beta[d];
            xn = fmaxf(xn, 0.f);
            s += xn * Wg2[d];
        }
        #pragma unroll
        for (int o = 32; o > 0; o >>= 1) s += __shfl_down(s, o, 64);
        if (lane == 0) {
            float g = s + bg2v;
            gate[n] = g;
            int b = batch[n];
            if (b != curb) {
                atomicMax(&gmaxu[curb], fenc(lmax));
                lmax = -3.4e38f; curb = b;
            }
            lmax = fmaxf(lmax, g);
        }
    }
    if (lane == 0) atomicMax(&gmaxu[curb], fenc(lmax));
}

// ---------------- exp + per-graph denom (contiguous 4-node runs/thread) ----
__global__ __launch_bounds__(256) void expdenom_kernel(
    const float* __restrict__ gate, const int* __restrict__ batch,
    const unsigned* __restrict__ gmaxu, float* __restrict__ ealpha, float* __restrict__ denom)
{
    int tid = blockIdx.x * 256 + threadIdx.x;
    int i0 = tid * 4;
    if (i0 >= NN) return;
    int i1 = min(i0 + 4, NN);
    int curb = batch[i0];
    float m = fdec(gmaxu[curb]);
    float lsum = 0.f;
    for (int i = i0; i < i1; i++) {
        int b = batch[i];
        if (b != curb) {
            atomicAdd(&denom[curb], lsum);
            lsum = 0.f; curb = b; m = fdec(gmaxu[b]);
        }
        float ex = expf(gate[i] - m);
        ealpha[i] = ex;
        lsum += ex;
    }
    atomicAdd(&denom[curb], lsum);
}

// ---------------- pooled[g] = sum (e/denom) * h2[n] (batch sorted, vectorized) ----
__global__ __launch_bounds__(256) void pool_kernel(
    const ushort* __restrict__ h2, const float* __restrict__ ealpha,
    const float* __restrict__ denom, const int* __restrict__ batch,
    float* __restrict__ pooled)
{
    int t = threadIdx.x;
    int g = t >> 5, l = t & 31;
    int c = l * 8;
    int row0 = blockIdx.x * 128 + g * 16;
    if (row0 >= NN) return;
    int rend = min(row0 + 16, NN);
    float acc[8];
    #pragma unroll
    for (int q = 0; q < 8; q++) acc[q] = 0.f;
    int curg = batch[row0];
    for (int r = row0; r < rend; r++) {
        int gb = batch[r];
        if (gb != curg) {
            float inv = 1.0f / denom[curg];
            #pragma unroll
            for (int q = 0; q < 8; q++) atomicAdd(&pooled[curg * DL + c + q], acc[q] * inv);
            #pragma unroll
            for (int q = 0; q < 8; q++) acc[q] = 0.f;
            curg = gb;
        }
        float w = ealpha[r];
        uint4 v = *(const uint4*)&h2[(size_t)r * DL + c];
        accw8(acc, v, w);
    }
    float inv = 1.0f / denom[curg];
    #pragma unroll
    for (int q = 0; q < 8; q++) atomicAdd(&pooled[curg * DL + c + q], acc[q] * inv);
}

__global__ void head_kernel(
    const float* __restrict__ pooled, const float* __restrict__ Wgl,
    const float* __restrict__ bgl, float* __restrict__ out)
{
    int g = blockIdx.x;
    int lane = threadIdx.x;           // 64
    float s = 0.f;
    #pragma unroll
    for (int c = 0; c < 4; c++) {
        int d = c * 64 + lane;
        s += pooled[g * DL + d] * Wgl[d];
    }
    #pragma unroll
    for (int o = 32; o > 0; o >>= 1) s += __shfl_down(s, o, 64);
    if (lane == 0) out[g] = sigmoidf_(s + bgl[0]);
}

extern "C" void kernel_launch(void* const* d_in, const int* in_sizes, int n_in,
                              void* d_out, int out_size, void* d_ws, size_t ws_size,
                              hipStream_t stream)
{
    const int* x      = (const int*)d_in[0];
    const int* ei     = (const int*)d_in[1];
    const int* etype  = (const int*)d_in[2];
    const int* batch  = (const int*)d_in[3];
    const float* e0   = (const float*)d_in[4];
    const float* e1   = (const float*)d_in[5];
    const float* e2   = (const float*)d_in[6];
    const float* e3   = (const float*)d_in[7];
    const float* e4   = (const float*)d_in[8];
    const float* e5   = (const float*)d_in[9];
    const float* W1   = (const float*)d_in[10];
    const float* root1= (const float*)d_in[11];
    const float* b1   = (const float*)d_in[12];
    const float* W2   = (const float*)d_in[13];
    const float* root2= (const float*)d_in[14];
    const float* b2   = (const float*)d_in[15];
    const float* Wg1  = (const float*)d_in[16];
    const float* bg1  = (const float*)d_in[17];
    const float* gamma= (const float*)d_in[18];
    const float* beta = (const float*)d_in[19];
    const float* Wg2  = (const float*)d_in[20];
    const float* bg2  = (const float*)d_in[21];
    const float* Wgl  = (const float*)d_in[22];
    const float* bgl  = (const float*)d_in[23];
    float* out = (float*)d_out;

    const int* esrc_in = ei;          // edge_index[0]
    const int* edst_in = ei + EE;     // edge_index[1]

    char* ws = (char*)d_ws;
    size_t off = 0;
    auto alloc = [&](size_t b) -> char* {
        char* p = ws + off;
        off += (b + 255) & ~(size_t)255;
        return p;
    };
    ushort* hbuf   = (ushort*)alloc((size_t)NN * D0 * 2);    // 38.4 MB: h0, later h2
    ushort* h1     = (ushort*)alloc((size_t)NN * DL * 2);    // 25.6 MB
    float*  hacc   = (float*)alloc((size_t)NN * DL * 4);     // 51.2 MB fp32
    size_t zstart = off;                                     // ---- zeroed region ----
    int*      counts  = (int*)alloc((size_t)NN * RR * 4);
    float*    colsum  = (float*)alloc(DL * 4);
    float*    colsum2 = (float*)alloc(DL * 4);
    unsigned* gmaxu   = (unsigned*)alloc(GG * 4);
    float*    denom   = (float*)alloc(GG * 4);
    float*    pooled  = (float*)alloc((size_t)GG * DL * 4);
    size_t zbytes = off - zstart;                            // ---- end zeroed ----
    int*   offs    = (int*)alloc((size_t)NN * RR * 4);
    int*   cursors = (int*)alloc((size_t)NN * RR * 4);
    int*   eidx    = (int*)alloc((size_t)EE * 4);
    float* ew      = (float*)alloc((size_t)EE * 4);
    int*   blkSums = (int*)alloc(512);
    int*   blkOff  = (int*)alloc(512);
    float* mu      = (float*)alloc(DL * 4);
    float* aa      = (float*)alloc(DL * 4);
    float* gate    = (float*)alloc((size_t)NN * 4);
    float* ealpha  = (float*)alloc((size_t)NN * 4);
    ushort* WbT1   = (ushort*)alloc((size_t)9 * DL * D0 * 2);  // 1.77 MB
    ushort* WbT2   = (ushort*)alloc((size_t)9 * DL * DL * 2);  // 1.18 MB
    ushort* WbTg   = (ushort*)alloc((size_t)1 * DL * DL * 2);  // 131 KB

    // hrc LAST: pick 4-relation chunks (102.4 MB) if workspace allows, else 2.
    int npc;
    ushort* hrc;
    {
        size_t need4 = ((size_t)NN * 4 * DL * 2 + 255) & ~(size_t)255;
        size_t need2 = ((size_t)NN * 2 * DL * 2 + 255) & ~(size_t)255;
        if (off + need4 <= ws_size)      { npc = 4; hrc = (ushort*)alloc((size_t)NN * 4 * DL * 2); }
        else if (off + need2 <= ws_size) { npc = 2; hrc = (ushort*)alloc((size_t)NN * 2 * DL * 2); }
        else return;   // fail loudly (wrong output) rather than corrupt
    }
    const int chc = npc * DL;

    ushort* h0  = hbuf;
    ushort* h2  = hbuf;   // h0 dead after layer1's final GEMM
    ushort* hg1 = hrc;    // hrc dead after layer2's last gather

    hipMemsetAsync(ws + zstart, 0, zbytes, stream);

    embed_kernel<<<(NN * 48 + 255) / 256, 256, 0, stream>>>(x, e0, e1, e2, e3, e4, e5, h0);
    count_kernel<<<(EE + 255) / 256, 256, 0, stream>>>(edst_in, etype, counts);

    // weight bf16 transposes
    {
        int tot1 = 9 * DL * D0;
        cvtT_kernel<<<(tot1 + 255) / 256, 256, 0, stream>>>(W1, root1, WbT1, RR, D0);
        int tot2 = 9 * DL * DL;
        cvtT_kernel<<<(tot2 + 255) / 256, 256, 0, stream>>>(W2, root2, WbT2, RR, DL);
        int totg = 1 * DL * DL;
        cvtT_kernel<<<(totg + 255) / 256, 256, 0, stream>>>(nullptr, Wg1, WbTg, 0, DL);
    }

    const int M = NN * RR;
    const int NB = (M + SCAN_CHUNK - 1) / SCAN_CHUNK;   // 98
    scanA_kernel<<<NB, 256, 0, stream>>>(counts, M, blkSums);
    scanB_kernel<<<1, 64, 0, stream>>>(blkSums, NB, blkOff);
    scanC_kernel<<<NB, 256, 0, stream>>>(counts, M, blkOff, offs, cursors);
    scatter_kernel<<<(EE + 255) / 256, 256, 0, stream>>>(esrc_in, edst_in, etype, counts, cursors,
                                                          eidx, ew, chc, npc - 1);

    const int MT = (NN + 127) / 128;   // 391 M-tiles
    const dim3 GC(npc * 2, MT), G2(2, MT);
    const int ABLK = (NN + 7) / 8;

    // ---- layer 1 (IN=384): 8/npc chunks, then fused root+aggregate finalize ----
    for (int c0 = 0; c0 < RR; c0 += npc) {
        dense_gemm<D0, 0><<<GC, 256, 0, stream>>>(h0, WbT1 + (size_t)c0 * DL * D0, nullptr, nullptr, hrc, NN, chc);
        gather_acc<<<ABLK, 256, 0, stream>>>(hrc, eidx, ew, offs, hacc, c0, c0 + npc, c0 == 0);
    }
    dense_gemm<D0, 2><<<G2, 256, 0, stream>>>(h0, WbT1 + (size_t)8 * DL * D0, b1, hacc, h1, NN, DL);

    // ---- layer 2 (IN=256) ----
    for (int c0 = 0; c0 < RR; c0 += npc) {
        dense_gemm<DL, 0><<<GC, 256, 0, stream>>>(h1, WbT2 + (size_t)c0 * DL * DL, nullptr, nullptr, hrc, NN, chc);
        gather_acc<<<ABLK, 256, 0, stream>>>(hrc, eidx, ew, offs, hacc, c0, c0 + npc, c0 == 0);
    }
    dense_gemm<DL, 2><<<G2, 256, 0, stream>>>(h1, WbT2 + (size_t)8 * DL * DL, b2, hacc, h2, NN, DL);

    // ---- gate linear (no act; BN follows) ----
    dense_gemm<DL, 1><<<G2, 256, 0, stream>>>(h2, WbTg, bg1, nullptr, hg1, NN, DL);

    bnstats_kernel<<<256, 256, 0, stream>>>(hg1, colsum, colsum2);
    bnfinal_kernel<<<1, 256, 0, stream>>>(colsum, colsum2, gamma, mu, aa);
    gate_kernel<<<512, 256, 0, stream>>>(hg1, mu, aa, beta, Wg2, bg2, batch, gate, gmaxu);
    expdenom_kernel<<<((NN + 3) / 4 + 255) / 256, 256, 0, stream>>>(gate, batch, gmaxu, ealpha, denom);
    pool_kernel<<<(NN + 127) / 128, 256, 0, stream>>>(h2, ealpha, denom, batch, pooled);
    head_kernel<<<GG, 64, 0, stream>>>(pooled, Wgl, bgl, out);
}

// Round 11
// 819.916 us; speedup vs baseline: 2.6356x; 1.0382x over previous
//
#include <hip/hip_runtime.h>
#include <hip/hip_bf16.h>
#include <cstdint>

#define NN 50000
#define EE 800000
#define RR 8
#define GG 128
#define D0 384
#define DL 256

typedef __attribute__((ext_vector_type(8))) short bf16x8;
typedef __attribute__((ext_vector_type(4))) float f32x4;

__device__ __forceinline__ float sigmoidf_(float x) { return 1.0f / (1.0f + expf(-x)); }

__device__ __forceinline__ ushort f2bf(float f) {
    uint u = __float_as_uint(f);
    u += 0x7fffu + ((u >> 16) & 1u);
    return (ushort)(u >> 16);
}
__device__ __forceinline__ uint pack2bf(float lo, float hi) {
    return (uint)f2bf(lo) | ((uint)f2bf(hi) << 16);
}
__device__ __forceinline__ float bf2f(ushort u) {
    return __uint_as_float((uint)u << 16);
}

// acc[0..7] += w * bf16x8(v)
__device__ __forceinline__ void accw8(float* s, uint4 a, float w) {
    s[0] += w * __uint_as_float(a.x << 16);
    s[1] += w * __uint_as_float(a.x & 0xffff0000u);
    s[2] += w * __uint_as_float(a.y << 16);
    s[3] += w * __uint_as_float(a.y & 0xffff0000u);
    s[4] += w * __uint_as_float(a.z << 16);
    s[5] += w * __uint_as_float(a.z & 0xffff0000u);
    s[6] += w * __uint_as_float(a.w << 16);
    s[7] += w * __uint_as_float(a.w & 0xffff0000u);
}

// unpack 8 bf16 to fp32
__device__ __forceinline__ void unp8(float* f, uint4 a) {
    f[0] = __uint_as_float(a.x << 16);
    f[1] = __uint_as_float(a.x & 0xffff0000u);
    f[2] = __uint_as_float(a.y << 16);
    f[3] = __uint_as_float(a.y & 0xffff0000u);
    f[4] = __uint_as_float(a.z << 16);
    f[5] = __uint_as_float(a.z & 0xffff0000u);
    f[6] = __uint_as_float(a.w << 16);
    f[7] = __uint_as_float(a.w & 0xffff0000u);
}

// order-preserving float->uint encoding for atomicMax
__device__ __forceinline__ unsigned fenc(float x) {
    unsigned u = __float_as_uint(x);
    return (u & 0x80000000u) ? ~u : (u | 0x80000000u);
}
__device__ __forceinline__ float fdec(unsigned u) {
    unsigned b = (u & 0x80000000u) ? (u & 0x7fffffffu) : ~u;
    return __uint_as_float(b);
}

// ---------------- embedding concat: h0[n, 0:384] (bf16) ----------------
__global__ __launch_bounds__(256) void embed_kernel(
    const int* __restrict__ x,
    const float* __restrict__ e0, const float* __restrict__ e1,
    const float* __restrict__ e2, const float* __restrict__ e3,
    const float* __restrict__ e4, const float* __restrict__ e5,
    ushort* __restrict__ h0)
{
    int idx = blockIdx.x * 256 + threadIdx.x;   // over NN*48 8-elem chunks
    if (idx >= NN * 48) return;
    int n = idx / 48;
    int q = idx - n * 48;
    int d = q * 8;
    int tbl = d >> 6;
    int w = d & 63;
    int row = x[n * 6 + tbl];
    const float* src;
    switch (tbl) {
        case 0: src = e0; break; case 1: src = e1; break; case 2: src = e2; break;
        case 3: src = e3; break; case 4: src = e4; break; default: src = e5; break;
    }
    float4 f0 = *(const float4*)&src[row * 64 + w];
    float4 f1 = *(const float4*)&src[row * 64 + w + 4];
    uint4 pk;
    pk.x = pack2bf(f0.x, f0.y);
    pk.y = pack2bf(f0.z, f0.w);
    pk.z = pack2bf(f1.x, f1.y);
    pk.w = pack2bf(f1.z, f1.w);
    *(uint4*)&h0[(size_t)n * D0 + d] = pk;
}

// ---------------- weight convert + transpose: WbT[r*256+n][k] = bf16(W[r][k][n]) ----------------
__global__ __launch_bounds__(256) void cvtT_kernel(
    const float* __restrict__ W, const float* __restrict__ root,
    ushort* __restrict__ WbT, int nrel, int IN)
{
    int idx = blockIdx.x * 256 + threadIdx.x;
    int tot = (nrel + 1) * DL * IN;
    if (idx >= tot) return;
    int k = idx % IN;
    int rn = idx / IN;
    int n = rn % DL;
    int r = rn / DL;
    float v = (r < nrel) ? W[((size_t)r * IN + k) * DL + n] : root[(size_t)k * DL + n];
    WbT[idx] = f2bf(v);
}

// ---------------- CSR build ----------------
__global__ __launch_bounds__(256) void count_kernel(
    const int* __restrict__ dst, const int* __restrict__ et, int* __restrict__ counts)
{
    int i = blockIdx.x * 256 + threadIdx.x;
    if (i < EE) atomicAdd(&counts[dst[i] * RR + et[i]], 1);
}

#define SCAN_CHUNK 4096
__global__ __launch_bounds__(256) void scanA_kernel(const int* __restrict__ cnt, int M, int* __restrict__ blkSums)
{
    __shared__ int s[256];
    int b = blockIdx.x, t = threadIdx.x;
    int base = b * SCAN_CHUNK + t * 16;
    int tot = 0;
    #pragma unroll
    for (int i = 0; i < 16; i++) { int idx = base + i; if (idx < M) tot += cnt[idx]; }
    s[t] = tot; __syncthreads();
    for (int off = 128; off > 0; off >>= 1) {
        if (t < off) s[t] += s[t + off];
        __syncthreads();
    }
    if (t == 0) blkSums[b] = s[0];
}

__global__ void scanB_kernel(const int* __restrict__ blkSums, int NB, int* __restrict__ blkOff)
{
    if (threadIdx.x == 0) {
        int run = 0;
        for (int i = 0; i < NB; i++) { blkOff[i] = run; run += blkSums[i]; }
    }
}

__global__ __launch_bounds__(256) void scanC_kernel(
    const int* __restrict__ cnt, int M, const int* __restrict__ blkOff,
    int* __restrict__ offs, int* __restrict__ curs)
{
    __shared__ int s[256];
    int b = blockIdx.x, t = threadIdx.x;
    int base = b * SCAN_CHUNK + t * 16;
    int loc[16];
    int tot = 0;
    #pragma unroll
    for (int i = 0; i < 16; i++) {
        int idx = base + i;
        int v = (idx < M) ? cnt[idx] : 0;
        loc[i] = tot; tot += v;
    }
    s[t] = tot; __syncthreads();
    for (int off = 1; off < 256; off <<= 1) {
        int v = (t >= off) ? s[t - off] : 0;
        __syncthreads();
        s[t] += v;
        __syncthreads();
    }
    int texc = s[t] - tot;           // exclusive prefix of this thread
    int bb = blkOff[b];
    #pragma unroll
    for (int i = 0; i < 16; i++) {
        int idx = base + i;
        if (idx < M) { int o = bb + texc + loc[i]; offs[idx] = o; curs[idx] = o; }
    }
}

// scatter: per-edge gather index into the npc-relation chunk
// eidx = src*chc + (r & (npc-1))*256 ; weight 1/cnt.
__global__ __launch_bounds__(256) void scatter_kernel(
    const int* __restrict__ src, const int* __restrict__ dst, const int* __restrict__ et,
    const int* __restrict__ cnts, int* __restrict__ cursors,
    int* __restrict__ eidx, float* __restrict__ ew, int chc, int mask)
{
    int i = blockIdx.x * 256 + threadIdx.x;
    if (i < EE) {
        int r = et[i];
        int b = dst[i] * RR + r;
        int pos = atomicAdd(&cursors[b], 1);
        eidx[pos] = src[i] * chc + (r & mask) * DL;
        ew[pos] = 1.0f / (float)cnts[b];
    }
}

// ---------------- dense bf16 MFMA GEMM: padded LDS + pinned reg-prefetch + XCD remap ----
// Tile BM=128 x BN=128 x BK=64, 4 waves, wave = 64x64. LDS padded LDA=68
// (rows spread 2r over banks -> 0 conflicts, R8-measured). T14 prefetch:
// SLOAD(kt+1) issued then sched_barrier(0) pins the loads BEFORE the MFMA
// phase (R8's loads were sunk by the compiler -> latency-serialized).
// T1: bijective XCD-chunked blockId remap (FETCH 152->23MB, R10-measured).
// MODE 0: plain; 1: +bias (gate); 2: +hacc+bias+sigmoid (root finalize).
template<int K, int MODE>
__global__ __launch_bounds__(256) void dense_gemm(
    const ushort* __restrict__ A,    // [M][K] bf16
    const ushort* __restrict__ Bt,   // [NCOL][K] bf16 (rows = C cols)
    const float* __restrict__ bias,  // [NCOL] (MODE>=1)
    const float* __restrict__ haccp, // [M][256] fp32 (MODE==2)
    ushort* __restrict__ C,          // [M][NCOL] bf16
    int M, int NCOL)
{
    constexpr int NKT = K / 64;
    constexpr int LDA = 68;          // 64 + 4 pad -> row stride 34 dwords, banks spread 2r
    __shared__ ushort Al[128 * LDA]; // 17.4 KB
    __shared__ ushort Bl[128 * LDA]; // 17.4 KB

    // ---- T1: bijective XCD-chunked remap (m204) ----
    const int nwg  = gridDim.x * gridDim.y;
    const int flat = blockIdx.y * gridDim.x + blockIdx.x;
    const int q8 = nwg >> 3, r8 = nwg & 7;
    const int xcd = flat & 7, pos = flat >> 3;
    const int vid = ((xcd < r8) ? xcd * (q8 + 1) : r8 * (q8 + 1) + (xcd - r8) * q8) + pos;
    const int m0  = (vid / gridDim.x) * 128;
    const int n0  = (vid % gridDim.x) * 128;

    const int t    = threadIdx.x;
    const int lane = t & 63;
    const int wv   = t >> 6;
    const int wr   = (wv >> 1) * 64;  // wave row offset
    const int wc   = (wv & 1) * 64;   // wave col offset
    const int l15  = lane & 15;
    const int kg   = lane >> 4;

    // staging decomposition: thread covers rows sr+32i, elem cols sc..sc+7
    const int sr = t >> 3;
    const int sc = (t & 7) * 8;
    int arow[4], brow[4];
    #pragma unroll
    for (int i = 0; i < 4; i++) {
        int r = sr + i * 32;
        arow[i] = min(m0 + r, M - 1);
        brow[i] = n0 + r;
    }

    uint4 av[4], bv[4];
    auto SLOAD = [&](int kt) {
        const ushort* Ak = A + kt * 64 + sc;
        const ushort* Bk = Bt + kt * 64 + sc;
        #pragma unroll
        for (int i = 0; i < 4; i++) av[i] = *(const uint4*)(Ak + (size_t)arow[i] * K);
        #pragma unroll
        for (int i = 0; i < 4; i++) bv[i] = *(const uint4*)(Bk + (size_t)brow[i] * K);
    };
    auto SWRITE = [&]() {
        #pragma unroll
        for (int i = 0; i < 4; i++) {
            int base = (sr + i * 32) * LDA + sc;
            *(uint2*)&Al[base]     = make_uint2(av[i].x, av[i].y);
            *(uint2*)&Al[base + 4] = make_uint2(av[i].z, av[i].w);
            *(uint2*)&Bl[base]     = make_uint2(bv[i].x, bv[i].y);
            *(uint2*)&Bl[base + 4] = make_uint2(bv[i].z, bv[i].w);
        }
    };

    f32x4 acc[4][4];
    #pragma unroll
    for (int mt = 0; mt < 4; mt++)
        #pragma unroll
        for (int nt = 0; nt < 4; nt++) acc[mt][nt] = (f32x4){0.f, 0.f, 0.f, 0.f};

    union FR { bf16x8 v; uint u[4]; };

    SLOAD(0);
    SWRITE();
    __syncthreads();

    for (int kt = 0; kt < NKT; kt++) {
        if (kt + 1 < NKT) {
            SLOAD(kt + 1);                       // issue prefetch...
            __builtin_amdgcn_sched_barrier(0);   // ...and PIN it before the MFMA phase
        }
        #pragma unroll
        for (int kb = 0; kb < 2; kb++) {
            FR a[4], b[4];
            #pragma unroll
            for (int mt = 0; mt < 4; mt++) {
                const ushort* p = &Al[(wr + mt * 16 + l15) * LDA + kb * 32 + kg * 4];
                uint2 lo = *(const uint2*)p;
                uint2 hi = *(const uint2*)(p + 16);
                a[mt].u[0] = lo.x; a[mt].u[1] = lo.y; a[mt].u[2] = hi.x; a[mt].u[3] = hi.y;
            }
            #pragma unroll
            for (int nt = 0; nt < 4; nt++) {
                const ushort* p = &Bl[(wc + nt * 16 + l15) * LDA + kb * 32 + kg * 4];
                uint2 lo = *(const uint2*)p;
                uint2 hi = *(const uint2*)(p + 16);
                b[nt].u[0] = lo.x; b[nt].u[1] = lo.y; b[nt].u[2] = hi.x; b[nt].u[3] = hi.y;
            }
            #pragma unroll
            for (int nt = 0; nt < 4; nt++)
                #pragma unroll
                for (int mt = 0; mt < 4; mt++)
                    acc[mt][nt] = __builtin_amdgcn_mfma_f32_16x16x32_bf16(a[mt].v, b[nt].v, acc[mt][nt], 0, 0, 0);
        }
        if (kt + 1 < NKT) {
            __syncthreads();   // all waves done reading Al/Bl
            SWRITE();
            __syncthreads();   // new tile visible
        }
    }

    // epilogue: C/D layout col=lane&15, row=(lane>>4)*4+i
    #pragma unroll
    for (int nt = 0; nt < 4; nt++) {
        int col = n0 + wc + nt * 16 + l15;
        float bvv = (MODE >= 1) ? bias[col] : 0.f;
        #pragma unroll
        for (int mt = 0; mt < 4; mt++) {
            #pragma unroll
            for (int i = 0; i < 4; i++) {
                int row = m0 + wr + mt * 16 + kg * 4 + i;
                if (row < M) {
                    float v = acc[mt][nt][i] + bvv;
                    if (MODE == 2) {
                        v += haccp[(size_t)row * DL + col];
                        v = sigmoidf_(v);
                    }
                    C[(size_t)row * NCOL + col] = f2bf(v);
                }
            }
        }
    }
}

// ---------------- flat CSR gather-accumulate over relations [relStart, relEnd) ----
__global__ __launch_bounds__(256) void gather_acc(
    const ushort* __restrict__ hrc,  // [N][chc] bf16
    const int* __restrict__ eidx,
    const float* __restrict__ ew,
    const int* __restrict__ offs,    // [N*8]
    float* __restrict__ hacc,        // [N][256] fp32
    int relStart, int relEnd, int first)
{
    int t = threadIdx.x;
    int slot = t >> 5;               // 0..7
    int l = t & 31;
    int n = blockIdx.x * 8 + slot;
    if (n >= NN) return;
    int e    = offs[n * 8 + relStart];
    int endE = (relEnd == 8 && n == NN - 1) ? EE : offs[n * 8 + relEnd];
    int c = l * 8;

    float acc[8];
    if (first) {
        #pragma unroll
        for (int q = 0; q < 8; q++) acc[q] = 0.f;
    } else {
        float4 a0 = *(const float4*)&hacc[(size_t)n * DL + c];
        float4 a1 = *(const float4*)&hacc[(size_t)n * DL + c + 4];
        acc[0] = a0.x; acc[1] = a0.y; acc[2] = a0.z; acc[3] = a0.w;
        acc[4] = a1.x; acc[5] = a1.y; acc[6] = a1.z; acc[7] = a1.w;
    }

    for (; e < endE; e += 4) {
        int e1 = min(e + 1, endE - 1);
        int e2 = min(e + 2, endE - 1);
        int e3 = min(e + 3, endE - 1);
        int i0 = eidx[e], i1 = eidx[e1], i2 = eidx[e2], i3 = eidx[e3];
        float w0 = ew[e];
        float w1 = (e + 1 < endE) ? ew[e1] : 0.f;
        float w2 = (e + 2 < endE) ? ew[e2] : 0.f;
        float w3 = (e + 3 < endE) ? ew[e3] : 0.f;
        uint4 v0 = *(const uint4*)&hrc[(size_t)i0 + c];
        uint4 v1 = *(const uint4*)&hrc[(size_t)i1 + c];
        uint4 v2 = *(const uint4*)&hrc[(size_t)i2 + c];
        uint4 v3 = *(const uint4*)&hrc[(size_t)i3 + c];
        accw8(acc, v0, w0); accw8(acc, v1, w1);
        accw8(acc, v2, w2); accw8(acc, v3, w3);
    }

    *(float4*)&hacc[(size_t)n * DL + c]     = make_float4(acc[0], acc[1], acc[2], acc[3]);
    *(float4*)&hacc[(size_t)n * DL + c + 4] = make_float4(acc[4], acc[5], acc[6], acc[7]);
}

// ---------------- BatchNorm stats over hg1 columns (vectorized) ----------------
__global__ __launch_bounds__(256) void bnstats_kernel(
    const ushort* __restrict__ hg1, float* __restrict__ colsum, float* __restrict__ colsum2)
{
    __shared__ float ss[8][256], ss2[8][256];
    int t = threadIdx.x;
    int g = t >> 5, l = t & 31;
    int c = l * 8;
    constexpr int RPB = (NN + 255) / 256;   // 196
    int row0 = blockIdx.x * RPB;
    int rend = min(row0 + RPB, NN);
    float s[8], s2[8];
    #pragma unroll
    for (int q = 0; q < 8; q++) { s[q] = 0.f; s2[q] = 0.f; }
    for (int r = row0 + g; r < rend; r += 8) {
        uint4 v = *(const uint4*)&hg1[(size_t)r * DL + c];
        float f[8]; unp8(f, v);
        #pragma unroll
        for (int q = 0; q < 8; q++) { s[q] += f[q]; s2[q] += f[q] * f[q]; }
    }
    #pragma unroll
    for (int q = 0; q < 8; q++) { ss[g][c + q] = s[q]; ss2[g][c + q] = s2[q]; }
    __syncthreads();
    float ts = 0.f, ts2 = 0.f;
    #pragma unroll
    for (int gg = 0; gg < 8; gg++) { ts += ss[gg][t]; ts2 += ss2[gg][t]; }
    atomicAdd(&colsum[t], ts);
    atomicAdd(&colsum2[t], ts2);
}

__global__ void bnfinal_kernel(
    const float* __restrict__ colsum, const float* __restrict__ colsum2,
    const float* __restrict__ gamma, float* __restrict__ mu, float* __restrict__ aa)
{
    int c = threadIdx.x;
    if (c < DL) {
        float m = colsum[c] / (float)NN;
        float var = colsum2[c] / (float)NN - m * m;
        mu[c] = m;
        aa[c] = rsqrtf(var + 1e-5f) * gamma[c];
    }
}

// ---------------- gate = relu(BN(hg1)) @ Wg2 + bg2 ; segment max ----------------
__global__ __launch_bounds__(256) void gate_kernel(
    const ushort* __restrict__ hg1, const float* __restrict__ mu,
    const float* __restrict__ aa, const float* __restrict__ beta,
    const float* __restrict__ Wg2, const float* __restrict__ bg2,
    const int* __restrict__ batch,
    float* __restrict__ gate, unsigned* __restrict__ gmaxu)
{
    int lane = threadIdx.x & 63;
    int wid = (blockIdx.x * blockDim.x + threadIdx.x) >> 6;
    int nw = (gridDim.x * blockDim.x) >> 6;
    int per = (NN + nw - 1) / nw;
    int n0 = wid * per;
    if (n0 >= NN) return;
    int n1 = min(n0 + per, NN);
    float bg2v = bg2[0];
    float lmax = -3.4e38f;
    int curb = batch[n0];
    for (int n = n0; n < n1; n++) {
        float s = 0.f;
        #pragma unroll
        for (int c = 0; c < 4; c++) {
            int d = c * 64 + lane;
            float v = bf2f(hg1[(size_t)n * DL + d]);
            float xn = (v - mu[d]) * aa[d] + beta[d];
            xn = fmaxf(xn, 0.f);
            s += xn * Wg2[d];
        }
        #pragma unroll
        for (int o = 32; o > 0; o >>= 1) s += __shfl_down(s, o, 64);
        if (lane == 0) {
            float g = s + bg2v;
            gate[n] = g;
            int b = batch[n];
            if (b != curb) {
                atomicMax(&gmaxu[curb], fenc(lmax));
                lmax = -3.4e38f; curb = b;
            }
            lmax = fmaxf(lmax, g);
        }
    }
    if (lane == 0) atomicMax(&gmaxu[curb], fenc(lmax));
}

// ---------------- exp + per-graph denom (contiguous 4-node runs/thread) ----
__global__ __launch_bounds__(256) void expdenom_kernel(
    const float* __restrict__ gate, const int* __restrict__ batch,
    const unsigned* __restrict__ gmaxu, float* __restrict__ ealpha, float* __restrict__ denom)
{
    int tid = blockIdx.x * 256 + threadIdx.x;
    int i0 = tid * 4;
    if (i0 >= NN) return;
    int i1 = min(i0 + 4, NN);
    int curb = batch[i0];
    float m = fdec(gmaxu[curb]);
    float lsum = 0.f;
    for (int i = i0; i < i1; i++) {
        int b = batch[i];
        if (b != curb) {
            atomicAdd(&denom[curb], lsum);
            lsum = 0.f; curb = b; m = fdec(gmaxu[b]);
        }
        float ex = expf(gate[i] - m);
        ealpha[i] = ex;
        lsum += ex;
    }
    atomicAdd(&denom[curb], lsum);
}

// ---------------- pooled[g] = sum (e/denom) * h2[n] (batch sorted, vectorized) ----
__global__ __launch_bounds__(256) void pool_kernel(
    const ushort* __restrict__ h2, const float* __restrict__ ealpha,
    const float* __restrict__ denom, const int* __restrict__ batch,
    float* __restrict__ pooled)
{
    int t = threadIdx.x;
    int g = t >> 5, l = t & 31;
    int c = l * 8;
    int row0 = blockIdx.x * 128 + g * 16;
    if (row0 >= NN) return;
    int rend = min(row0 + 16, NN);
    float acc[8];
    #pragma unroll
    for (int q = 0; q < 8; q++) acc[q] = 0.f;
    int curg = batch[row0];
    for (int r = row0; r < rend; r++) {
        int gb = batch[r];
        if (gb != curg) {
            float inv = 1.0f / denom[curg];
            #pragma unroll
            for (int q = 0; q < 8; q++) atomicAdd(&pooled[curg * DL + c + q], acc[q] * inv);
            #pragma unroll
            for (int q = 0; q < 8; q++) acc[q] = 0.f;
            curg = gb;
        }
        float w = ealpha[r];
        uint4 v = *(const uint4*)&h2[(size_t)r * DL + c];
        accw8(acc, v, w);
    }
    float inv = 1.0f / denom[curg];
    #pragma unroll
    for (int q = 0; q < 8; q++) atomicAdd(&pooled[curg * DL + c + q], acc[q] * inv);
}

__global__ void head_kernel(
    const float* __restrict__ pooled, const float* __restrict__ Wgl,
    const float* __restrict__ bgl, float* __restrict__ out)
{
    int g = blockIdx.x;
    int lane = threadIdx.x;           // 64
    float s = 0.f;
    #pragma unroll
    for (int c = 0; c < 4; c++) {
        int d = c * 64 + lane;
        s += pooled[g * DL + d] * Wgl[d];
    }
    #pragma unroll
    for (int o = 32; o > 0; o >>= 1) s += __shfl_down(s, o, 64);
    if (lane == 0) out[g] = sigmoidf_(s + bgl[0]);
}

extern "C" void kernel_launch(void* const* d_in, const int* in_sizes, int n_in,
                              void* d_out, int out_size, void* d_ws, size_t ws_size,
                              hipStream_t stream)
{
    const int* x      = (const int*)d_in[0];
    const int* ei     = (const int*)d_in[1];
    const int* etype  = (const int*)d_in[2];
    const int* batch  = (const int*)d_in[3];
    const float* e0   = (const float*)d_in[4];
    const float* e1   = (const float*)d_in[5];
    const float* e2   = (const float*)d_in[6];
    const float* e3   = (const float*)d_in[7];
    const float* e4   = (const float*)d_in[8];
    const float* e5   = (const float*)d_in[9];
    const float* W1   = (const float*)d_in[10];
    const float* root1= (const float*)d_in[11];
    const float* b1   = (const float*)d_in[12];
    const float* W2   = (const float*)d_in[13];
    const float* root2= (const float*)d_in[14];
    const float* b2   = (const float*)d_in[15];
    const float* Wg1  = (const float*)d_in[16];
    const float* bg1  = (const float*)d_in[17];
    const float* gamma= (const float*)d_in[18];
    const float* beta = (const float*)d_in[19];
    const float* Wg2  = (const float*)d_in[20];
    const float* bg2  = (const float*)d_in[21];
    const float* Wgl  = (const float*)d_in[22];
    const float* bgl  = (const float*)d_in[23];
    float* out = (float*)d_out;

    const int* esrc_in = ei;          // edge_index[0]
    const int* edst_in = ei + EE;     // edge_index[1]

    char* ws = (char*)d_ws;
    size_t off = 0;
    auto alloc = [&](size_t b) -> char* {
        char* p = ws + off;
        off += (b + 255) & ~(size_t)255;
        return p;
    };
    ushort* hbuf   = (ushort*)alloc((size_t)NN * D0 * 2);    // 38.4 MB: h0, later h2
    ushort* h1     = (ushort*)alloc((size_t)NN * DL * 2);    // 25.6 MB
    float*  hacc   = (float*)alloc((size_t)NN * DL * 4);     // 51.2 MB fp32
    size_t zstart = off;                                     // ---- zeroed region ----
    int*      counts  = (int*)alloc((size_t)NN * RR * 4);
    float*    colsum  = (float*)alloc(DL * 4);
    float*    colsum2 = (float*)alloc(DL * 4);
    unsigned* gmaxu   = (unsigned*)alloc(GG * 4);
    float*    denom   = (float*)alloc(GG * 4);
    float*    pooled  = (float*)alloc((size_t)GG * DL * 4);
    size_t zbytes = off - zstart;                            // ---- end zeroed ----
    int*   offs    = (int*)alloc((size_t)NN * RR * 4);
    int*   cursors = (int*)alloc((size_t)NN * RR * 4);
    int*   eidx    = (int*)alloc((size_t)EE * 4);
    float* ew      = (float*)alloc((size_t)EE * 4);
    int*   blkSums = (int*)alloc(512);
    int*   blkOff  = (int*)alloc(512);
    float* mu      = (float*)alloc(DL * 4);
    float* aa      = (float*)alloc(DL * 4);
    float* gate    = (float*)alloc((size_t)NN * 4);
    float* ealpha  = (float*)alloc((size_t)NN * 4);
    ushort* WbT1   = (ushort*)alloc((size_t)9 * DL * D0 * 2);  // 1.77 MB
    ushort* WbT2   = (ushort*)alloc((size_t)9 * DL * DL * 2);  // 1.18 MB
    ushort* WbTg   = (ushort*)alloc((size_t)1 * DL * DL * 2);  // 131 KB

    // hrc LAST: pick 4-relation chunks (102.4 MB) if workspace allows, else 2.
    int npc;
    ushort* hrc;
    {
        size_t need4 = ((size_t)NN * 4 * DL * 2 + 255) & ~(size_t)255;
        size_t need2 = ((size_t)NN * 2 * DL * 2 + 255) & ~(size_t)255;
        if (off + need4 <= ws_size)      { npc = 4; hrc = (ushort*)alloc((size_t)NN * 4 * DL * 2); }
        else if (off + need2 <= ws_size) { npc = 2; hrc = (ushort*)alloc((size_t)NN * 2 * DL * 2); }
        else return;   // fail loudly (wrong output) rather than corrupt
    }
    const int chc = npc * DL;

    ushort* h0  = hbuf;
    ushort* h2  = hbuf;   // h0 dead after layer1's final GEMM
    ushort* hg1 = hrc;    // hrc dead after layer2's last gather

    hipMemsetAsync(ws + zstart, 0, zbytes, stream);

    embed_kernel<<<(NN * 48 + 255) / 256, 256, 0, stream>>>(x, e0, e1, e2, e3, e4, e5, h0);
    count_kernel<<<(EE + 255) / 256, 256, 0, stream>>>(edst_in, etype, counts);

    // weight bf16 transposes
    {
        int tot1 = 9 * DL * D0;
        cvtT_kernel<<<(tot1 + 255) / 256, 256, 0, stream>>>(W1, root1, WbT1, RR, D0);
        int tot2 = 9 * DL * DL;
        cvtT_kernel<<<(tot2 + 255) / 256, 256, 0, stream>>>(W2, root2, WbT2, RR, DL);
        int totg = 1 * DL * DL;
        cvtT_kernel<<<(totg + 255) / 256, 256, 0, stream>>>(nullptr, Wg1, WbTg, 0, DL);
    }

    const int M = NN * RR;
    const int NB = (M + SCAN_CHUNK - 1) / SCAN_CHUNK;   // 98
    scanA_kernel<<<NB, 256, 0, stream>>>(counts, M, blkSums);
    scanB_kernel<<<1, 64, 0, stream>>>(blkSums, NB, blkOff);
    scanC_kernel<<<NB, 256, 0, stream>>>(counts, M, blkOff, offs, cursors);
    scatter_kernel<<<(EE + 255) / 256, 256, 0, stream>>>(esrc_in, edst_in, etype, counts, cursors,
                                                          eidx, ew, chc, npc - 1);

    const int MT = (NN + 127) / 128;   // 391 M-tiles
    const dim3 GC(npc * 2, MT), G2(2, MT);
    const int ABLK = (NN + 7) / 8;

    // ---- layer 1 (IN=384): 8/npc chunks, then fused root+aggregate finalize ----
    for (int c0 = 0; c0 < RR; c0 += npc) {
        dense_gemm<D0, 0><<<GC, 256, 0, stream>>>(h0, WbT1 + (size_t)c0 * DL * D0, nullptr, nullptr, hrc, NN, chc);
        gather_acc<<<ABLK, 256, 0, stream>>>(hrc, eidx, ew, offs, hacc, c0, c0 + npc, c0 == 0);
    }
    dense_gemm<D0, 2><<<G2, 256, 0, stream>>>(h0, WbT1 + (size_t)8 * DL * D0, b1, hacc, h1, NN, DL);

    // ---- layer 2 (IN=256) ----
    for (int c0 = 0; c0 < RR; c0 += npc) {
        dense_gemm<DL, 0><<<GC, 256, 0, stream>>>(h1, WbT2 + (size_t)c0 * DL * DL, nullptr, nullptr, hrc, NN, chc);
        gather_acc<<<ABLK, 256, 0, stream>>>(hrc, eidx, ew, offs, hacc, c0, c0 + npc, c0 == 0);
    }
    dense_gemm<DL, 2><<<G2, 256, 0, stream>>>(h1, WbT2 + (size_t)8 * DL * DL, b2, hacc, h2, NN, DL);

    // ---- gate linear (no act; BN follows) ----
    dense_gemm<DL, 1><<<G2, 256, 0, stream>>>(h2, WbTg, bg1, nullptr, hg1, NN, DL);

    bnstats_kernel<<<256, 256, 0, stream>>>(hg1, colsum, colsum2);
    bnfinal_kernel<<<1, 256, 0, stream>>>(colsum, colsum2, gamma, mu, aa);
    gate_kernel<<<512, 256, 0, stream>>>(hg1, mu, aa, beta, Wg2, bg2, batch, gate, gmaxu);
    expdenom_kernel<<<((NN + 3) / 4 + 255) / 256, 256, 0, stream>>>(gate, batch, gmaxu, ealpha, denom);
    pool_kernel<<<(NN + 127) / 128, 256, 0, stream>>>(h2, ealpha, denom, batch, pooled);
    head_kernel<<<GG, 64, 0, stream>>>(pooled, Wgl, bgl, out);
}